// Round 11
// baseline (710.891 us; speedup 1.0000x reference)
//
#include <hip/hip_runtime.h>
#include <math.h>

// ---------------------------------------------------------------------------
// Round 10: factor the qk GEMM. qk[n,h,:] = rstd*A_h - rstd*mu*u_h + v_h with
// u_h=Wk_h^T g, v_h=Wk_h^T b, A_h=Wk_h^T(qf_h.g). Heads 1/2: qf depends only
// on j (resp. i) -> A_1/A_2 are 64-row tables per plane (tiny GEMM). Only
// head 0 needs the full 4096-row GEMM (1/3 of old flops). qkb heads 1/2
// filled by a cheap combine kernel. All 3 split terms kept (precision class
// of r6, absmax 0.0156). attn + out-GEMM unchanged.
// ---------------------------------------------------------------------------

constexpr int kG = 64, kS = 4, kC = 771, kNV = 4;
constexpr int kQD = 2313;
constexpr int kNPIX = 4096;
constexpr int kL = 16;
constexpr int kImgMStride = kC * kG * kG;
constexpr int kKP = 800;
constexpr int kLDA = 2400;
constexpr int kBROWS = 896;
constexpr int kCP = 776;
constexpr int kNG = kCP / 4;
constexpr int kLDQ = 3 * kCP;
constexpr int kIMS2 = kNPIX * kCP;

constexpr size_t kQKB_FLOATS = (size_t)kNPIX * kLDQ;
constexpr size_t kW_ELEMS = (size_t)3 * kBROWS * kKP;
constexpr size_t kA0_ELEMS = (size_t)kNPIX * kKP;   // per-slot a0 split
constexpr size_t kWH_ELEMS = (size_t)kNPIX * kLDA;  // per-slot whi
constexpr size_t kQN_FLOATS = (size_t)kNPIX * kQD;
constexpr size_t kTAB_FLOATS = (size_t)6 * 64 * kC;

using bf16x8 = __attribute__((ext_vector_type(8))) short;
using f32x4 = __attribute__((ext_vector_type(4))) float;

__device__ __forceinline__ unsigned short f2bf(float x) {
  unsigned int u = __float_as_uint(x);
  u = (u + 0x7FFFu + ((u >> 16) & 1u)) >> 16;
  return (unsigned short)u;
}
__device__ __forceinline__ float bf2f(unsigned short h) {
  return __uint_as_float(((unsigned int)h) << 16);
}
__device__ __forceinline__ void gload16(const unsigned short* g,
                                        unsigned short* l) {
  __builtin_amdgcn_global_load_lds(
      (const __attribute__((address_space(1))) void*)g,
      (__attribute__((address_space(3))) void*)l, 16, 0, 0);
}

// ---- tiny 4x4 batched inverse --------------------------------------------
__global__ void invert4_kernel(const float* __restrict__ c2w,
                               float* __restrict__ w2c) {
  const int m = threadIdx.x;
  if (m >= kNV) return;
  float a[4][8];
  for (int r = 0; r < 4; ++r)
    for (int c = 0; c < 4; ++c) {
      a[r][c] = c2w[m * 16 + r * 4 + c];
      a[r][4 + c] = (r == c) ? 1.f : 0.f;
    }
  for (int col = 0; col < 4; ++col) {
    int piv = col;
    float best = fabsf(a[col][col]);
    for (int r = col + 1; r < 4; ++r) {
      float t = fabsf(a[r][col]);
      if (t > best) { best = t; piv = r; }
    }
    if (piv != col)
      for (int c = 0; c < 8; ++c) {
        float t = a[col][c]; a[col][c] = a[piv][c]; a[piv][c] = t;
      }
    const float inv = 1.f / a[col][col];
    for (int c = 0; c < 8; ++c) a[col][c] *= inv;
    for (int r = 0; r < 4; ++r)
      if (r != col) {
        const float f = a[r][col];
        for (int c = 0; c < 8; ++c) a[r][c] -= f * a[col][c];
      }
  }
  for (int r = 0; r < 4; ++r)
    for (int c = 0; c < 4; ++c) w2c[m * 16 + r * 4 + c] = a[r][4 + c];
}

// ---- image transpose [NV,C,H,W] -> [NV,H,W,776] f32 ----------------------
__global__ void __launch_bounds__(256) transpose_img_kernel(
    const float* __restrict__ img, float* __restrict__ out) {
  __shared__ float t[64][65];
  const int y = blockIdx.x, m = blockIdx.y, tid = threadIdx.x;
  const size_t obase = ((size_t)m * kNPIX + (size_t)y * 64) * kCP;
  for (int c0 = 0; c0 < kC; c0 += 64) {
    const int cw = (kC - c0) < 64 ? (kC - c0) : 64;
    for (int idx = tid; idx < cw * 64; idx += 256) {
      const int cl = idx >> 6, x = idx & 63;
      t[cl][x] = img[(((size_t)m * kC + c0 + cl) * 64 + y) * 64 + x];
    }
    __syncthreads();
    for (int idx = tid; idx < 64 * 64; idx += 256) {
      const int x = idx >> 6, cl = idx & 63;
      if (cl < cw) out[obase + (size_t)x * kCP + c0 + cl] = t[cl][x];
    }
    __syncthreads();
  }
  for (int idx = tid; idx < 64 * 8; idx += 256) {
    const int x = idx >> 3, c = 768 + (idx & 7);
    if (c >= kC && c < kCP) out[obase + (size_t)x * kCP + c] = 0.f;
  }
}

// ---- weight prep ----------------------------------------------------------
__global__ void __launch_bounds__(256) prep_wk_kernel(
    const float* __restrict__ Wk, unsigned short* __restrict__ hi,
    unsigned short* __restrict__ lo) {
  const int c = blockIdx.x, h = blockIdx.y;
  const size_t base = ((size_t)h * kBROWS + c) * kKP;
  for (int k = threadIdx.x; k < kKP; k += 256) {
    float v = (c < kC && k < kC) ? Wk[(size_t)c * kQD + h * kC + k] : 0.f;
    const unsigned short a = f2bf(v);
    hi[base + k] = a;
    lo[base + k] = f2bf(v - bf2f(a));
  }
}

__global__ void __launch_bounds__(256) prep_wvt_kernel(
    const float* __restrict__ Wv, unsigned short* __restrict__ hi,
    unsigned short* __restrict__ lo) {
  __shared__ float t[64][65];
  const int k0 = blockIdx.x * 64, j0 = blockIdx.y * 64, h = blockIdx.z;
  const int tx = threadIdx.x & 63, ty4 = threadIdx.x >> 6;
  for (int ty = ty4; ty < 64; ty += 4) {
    const int k = k0 + ty, j = j0 + tx;
    t[ty][tx] = (k < kC && j < kC) ? Wv[(size_t)k * kQD + h * kC + j] : 0.f;
  }
  __syncthreads();
  for (int ty = ty4; ty < 64; ty += 4) {
    const int j = j0 + ty, k = k0 + tx;
    if (j < kBROWS && k < kKP) {
      const float v = t[tx][ty];
      const unsigned short a = f2bf(v);
      const size_t p = ((size_t)h * kBROWS + j) * kKP + k;
      hi[p] = a;
      lo[p] = f2bf(v - bf2f(a));
    }
  }
}

// ---- other-plane mean table (bit-exact, r9) -------------------------------
__global__ void __launch_bounds__(256) prep_meantab_kernel(
    const float* __restrict__ q_xy, const float* __restrict__ q_xz,
    const float* __restrict__ q_yz, float* __restrict__ tab) {
  const int v = blockIdx.x;  // 0..63
  const int t = blockIdx.y;  // plane*2+part
  const int plane = t >> 1, part = t & 1;
  const float* src;
  if (plane == 0) src = part ? q_yz : q_xz;
  else if (plane == 1) src = part ? q_yz : q_xy;
  else src = part ? q_xz : q_xy;
  __shared__ int sIdx[4][4];
  __shared__ float sW[4][4];
  if (threadIdx.x < 4) {
    const int s = threadIdx.x;
    const float Xv = -1.f + 2.f * v / 63.f;
    const float Ts = -1.f + 2.f * s / 3.f;
    float a, b;
    if (plane == 0) { a = Xv; b = Ts; }
    else if (plane == 1) {
      if (part == 0) { a = Xv; b = Ts; } else { a = Ts; b = Xv; }
    } else { a = Ts; b = Xv; }
    const float ga = fminf(fmaxf((a * 0.5f + 0.5f) * 63.f, 0.f), 63.f);
    const float gb = fminf(fmaxf((b * 0.5f + 0.5f) * 63.f, 0.f), 63.f);
    const float ix = fminf(fmaxf((ga + 1.f) * 0.5f * 63.f, 0.f), 63.f);
    const float iy = fminf(fmaxf((gb + 1.f) * 0.5f * 63.f, 0.f), 63.f);
    const float x0 = floorf(ix), y0 = floorf(iy);
    const float wx = ix - x0, wy = iy - y0;
    const int x0i = (int)x0, y0i = (int)y0;
    const int x1i = (x0i + 1 > 63) ? 63 : x0i + 1;
    const int y1i = (y0i + 1 > 63) ? 63 : y0i + 1;
    sIdx[s][0] = (y0i * 64 + x0i) * kC;
    sIdx[s][1] = (y0i * 64 + x1i) * kC;
    sIdx[s][2] = (y1i * 64 + x0i) * kC;
    sIdx[s][3] = (y1i * 64 + x1i) * kC;
    sW[s][0] = (1.f - wx) * (1.f - wy);
    sW[s][1] = wx * (1.f - wy);
    sW[s][2] = (1.f - wx) * wy;
    sW[s][3] = wx * wy;
  }
  __syncthreads();
  for (int c = threadIdx.x; c < kC; c += 256) {
    float a1 = 0.f;
#pragma unroll
    for (int s = 0; s < 4; ++s) {
      a1 += src[sIdx[s][0] + c] * sW[s][0] + src[sIdx[s][1] + c] * sW[s][1]
          + src[sIdx[s][2] + c] * sW[s][2] + src[sIdx[s][3] + c] * sW[s][3];
    }
    tab[((size_t)t * 64 + v) * kC + c] = a1 * 0.25f;
  }
}

// ---- bf16 split of meantab*g (A-operand for table GEMMs, M padded 128) ----
__global__ void __launch_bounds__(256) prep_tabsplit_kernel(
    const float* __restrict__ tab, const float* __restrict__ ln_g,
    unsigned short* __restrict__ hi, unsigned short* __restrict__ lo) {
  const int v = blockIdx.x;  // 0..127
  const int t = blockIdx.y;  // 0..5
  const int h = 1 + (t & 1);
  const size_t base = ((size_t)t * 128 + v) * kKP;
  for (int k = threadIdx.x; k < kKP; k += 256) {
    float val = 0.f;
    if (v < 64 && k < kC)
      val = tab[((size_t)t * 64 + v) * kC + k] * ln_g[h * kC + k];
    const unsigned short a = f2bf(val);
    hi[base + k] = a;
    lo[base + k] = f2bf(val - bf2f(a));
  }
}

// ---- u_h = Wk_h^T g, v_h = Wk_h^T b (f32 exact) ---------------------------
__global__ void __launch_bounds__(256) prep_uv_kernel(
    const float* __restrict__ Wk, const float* __restrict__ ln_g,
    const float* __restrict__ ln_b, float* __restrict__ u,
    float* __restrict__ v) {
  const int c = blockIdx.x * 256 + threadIdx.x;
  const int h = blockIdx.y;
  if (c >= kCP) return;
  float su = 0.f, sv = 0.f;
  if (c < kC) {
    const float* wr = Wk + (size_t)c * kQD + h * kC;
    const float* g = ln_g + h * kC;
    const float* b = ln_b + h * kC;
    for (int k = 0; k < kC; ++k) {
      su = fmaf(wr[k], g[k], su);
      sv = fmaf(wr[k], b[k], sv);
    }
  }
  u[h * kCP + c] = su;
  v[h * kCP + c] = sv;
}

// ---- build_a0: stats + qbk + head-0 split (y0 = qp*g) + (mu,rstd) ---------
__global__ void __launch_bounds__(256) build_a0_kernel(
    const float* __restrict__ q_xy, const float* __restrict__ q_xz,
    const float* __restrict__ q_yz, const float* __restrict__ tab,
    const float* __restrict__ ln_g, const float* __restrict__ ln_b,
    const float* __restrict__ bk, unsigned short* __restrict__ a0hi,
    unsigned short* __restrict__ a0lo, float* __restrict__ murs,
    float* __restrict__ qbk) {
  const int slot = blockIdx.y, plane = slot;
  const float* qp = (plane == 0) ? q_xy : (plane == 1) ? q_xz : q_yz;
  const int n = blockIdx.x, i = n >> 6, j = n & 63, tid = threadIdx.x;
  __shared__ float qf[kQD];
  __shared__ float red[16];

  const float* t0 = tab + ((size_t)(plane * 2 + 0) * 64 + j) * kC;
  const float* t1 = tab + ((size_t)(plane * 2 + 1) * 64 + i) * kC;
  for (int c = tid; c < kC; c += 256) {
    qf[c] = qp[(size_t)n * kC + c];
    qf[kC + c] = t0[c];
    qf[2 * kC + c] = t1[c];
  }
  __syncthreads();

  float sm = 0.f;
  for (int idx = tid; idx < kQD; idx += 256) sm += qf[idx];
#pragma unroll
  for (int off = 32; off; off >>= 1) sm += __shfl_down(sm, off);
  if ((tid & 63) == 0) red[tid >> 6] = sm;
  __syncthreads();
  const float mu = (red[0] + red[1] + red[2] + red[3]) * (1.f / kQD);
  __syncthreads();
  float sq = 0.f;
  for (int idx = tid; idx < kQD; idx += 256) {
    const float d = qf[idx] - mu;
    sq += d * d;
  }
#pragma unroll
  for (int off = 32; off; off >>= 1) sq += __shfl_down(sq, off);
  if ((tid & 63) == 0) red[tid >> 6] = sq;
  __syncthreads();
  const float var = (red[0] + red[1] + red[2] + red[3]) * (1.f / kQD);
  const float rstd = 1.f / sqrtf(var + 1e-5f);
  if (tid == 0) {
    murs[2 * ((size_t)slot * kNPIX + n)] = mu;
    murs[2 * ((size_t)slot * kNPIX + n) + 1] = rstd;
  }
  __syncthreads();

  float h0 = 0.f, h1 = 0.f, h2 = 0.f;
  unsigned short* ah = a0hi + (size_t)slot * kA0_ELEMS + (size_t)n * kKP;
  unsigned short* al = a0lo + (size_t)slot * kA0_ELEMS + (size_t)n * kKP;
  for (int idx = tid; idx < 3 * kKP; idx += 256) {
    int h, k;
    if (idx < kKP) { h = 0; k = idx; }
    else if (idx < 2 * kKP) { h = 1; k = idx - kKP; }
    else { h = 2; k = idx - 2 * kKP; }
    if (k < kC) {
      const int li = h * kC + k;
      const float v = (qf[li] - mu) * rstd * ln_g[li] + ln_b[li];
      const float pb = v * bk[li];
      if (h == 0) h0 += pb; else if (h == 1) h1 += pb; else h2 += pb;
    }
    if (idx < kKP) {  // head-0 split operand y0 = qf0 * g (NO mu/b)
      const float y = (idx < kC) ? qf[idx] * ln_g[idx] : 0.f;
      const unsigned short hv = f2bf(y);
      ah[idx] = hv;
      al[idx] = f2bf(y - bf2f(hv));
    }
  }
#pragma unroll
  for (int off = 32; off; off >>= 1) {
    h0 += __shfl_down(h0, off);
    h1 += __shfl_down(h1, off);
    h2 += __shfl_down(h2, off);
  }
  if ((tid & 63) == 0) {
    red[(tid >> 6) * 4 + 0] = h0;
    red[(tid >> 6) * 4 + 1] = h1;
    red[(tid >> 6) * 4 + 2] = h2;
  }
  __syncthreads();
  if (tid < 3)
    qbk[((size_t)slot * kNPIX + n) * 3 + tid] =
        red[tid] + red[4 + tid] + red[8 + tid] + red[12 + tid];
}

// ---- head-0 GEMM: A0(=y0 split) x Wk_0 split, 3-term; uv epilogue ---------
__global__ void __launch_bounds__(256) gemm_a0_kernel(
    const unsigned short* __restrict__ A0hi,
    const unsigned short* __restrict__ A0lo,
    const unsigned short* __restrict__ Bhi,
    const unsigned short* __restrict__ Blo, const float* __restrict__ murs,
    const float* __restrict__ uvec, const float* __restrict__ vvec,
    float* __restrict__ qkb) {
  __shared__ unsigned short smA[2][128 * 32];
  __shared__ unsigned short smB[2][128 * 32];
  const int slot = blockIdx.z;
  const int t = blockIdx.y * 7 + blockIdx.x;
  const int xcd = t & 7, idx = t >> 3;
  const int nb = idx % 7, mb = (xcd << 2) + idx / 7;
  const int m0 = mb * 128, n0 = nb * 128;
  const unsigned short* Ah = A0hi + (size_t)slot * kA0_ELEMS;
  const unsigned short* Al = A0lo + (size_t)slot * kA0_ELEMS;
  const int tid = threadIdx.x;
  const int lane = tid & 63, w = tid >> 6;
  const int wm = w >> 1, wn = w & 1;

  const int sr0 = w * 16 + (lane >> 2);
  const int ss = lane & 3;
  size_t aoff[2], boff[2];
  int ldsb[2];
#pragma unroll
  for (int p = 0; p < 2; ++p) {
    const int r = p * 64 + sr0;
    const int kl = (ss ^ ((r >> 1) & 3)) * 8;
    aoff[p] = (size_t)(m0 + r) * kKP + kl;
    boff[p] = (size_t)(n0 + r) * kKP + kl;
    ldsb[p] = (p * 64 + w * 16) * 32;
  }
  int offA[4], offB[4];
#pragma unroll
  for (int i = 0; i < 4; ++i) {
    const int ra = wm * 64 + i * 16 + (lane & 15);
    offA[i] = ra * 32 + (((lane >> 4) ^ ((ra >> 1) & 3)) << 3);
    const int rb = wn * 64 + i * 16 + (lane & 15);
    offB[i] = rb * 32 + (((lane >> 4) ^ ((rb >> 1) & 3)) << 3);
  }
  f32x4 acc[4][4];
#pragma unroll
  for (int i = 0; i < 4; ++i)
#pragma unroll
    for (int j = 0; j < 4; ++j) acc[i][j] = f32x4{0.f, 0.f, 0.f, 0.f};

  for (int k0 = 0; k0 < kKP; k0 += 32) {
#pragma unroll
    for (int p = 0; p < 2; ++p) {
      gload16(Ah + aoff[p] + k0, &smA[0][ldsb[p]]);
      gload16(Al + aoff[p] + k0, &smA[1][ldsb[p]]);
      gload16(Bhi + boff[p] + k0, &smB[0][ldsb[p]]);
      gload16(Blo + boff[p] + k0, &smB[1][ldsb[p]]);
    }
    __syncthreads();
    bf16x8 ah[4], al[4], bh[4], bl[4];
#pragma unroll
    for (int i = 0; i < 4; ++i) {
      ah[i] = *(const bf16x8*)&smA[0][offA[i]];
      al[i] = *(const bf16x8*)&smA[1][offA[i]];
      bh[i] = *(const bf16x8*)&smB[0][offB[i]];
      bl[i] = *(const bf16x8*)&smB[1][offB[i]];
    }
#pragma unroll
    for (int i = 0; i < 4; ++i)
#pragma unroll
      for (int j = 0; j < 4; ++j)
        acc[i][j] = __builtin_amdgcn_mfma_f32_16x16x32_bf16(ah[i], bh[j],
                                                            acc[i][j], 0, 0, 0);
#pragma unroll
    for (int i = 0; i < 4; ++i)
#pragma unroll
      for (int j = 0; j < 4; ++j)
        acc[i][j] = __builtin_amdgcn_mfma_f32_16x16x32_bf16(ah[i], bl[j],
                                                            acc[i][j], 0, 0, 0);
#pragma unroll
    for (int i = 0; i < 4; ++i)
#pragma unroll
      for (int j = 0; j < 4; ++j)
        acc[i][j] = __builtin_amdgcn_mfma_f32_16x16x32_bf16(al[i], bh[j],
                                                            acc[i][j], 0, 0, 0);
    __syncthreads();
  }

  const float* mr = murs + 2 * ((size_t)slot * kNPIX);
  float* dst = qkb + (size_t)slot * kQKB_FLOATS;
  const int rbase = m0 + wm * 64;
  const int cbase = n0 + wn * 64;
#pragma unroll
  for (int i = 0; i < 4; ++i) {
#pragma unroll
    for (int j = 0; j < 4; ++j) {
      const int col = cbase + j * 16 + (lane & 15);
      if (col < kC) {
        const float uu = uvec[col], vv = vvec[col];
#pragma unroll
        for (int r = 0; r < 4; ++r) {
          const int row = rbase + i * 16 + (lane >> 4) * 4 + r;
          const float mu = mr[2 * row], rs = mr[2 * row + 1];
          dst[(size_t)row * kLDQ + col] =
              rs * acc[i][j][r] - rs * mu * uu + vv;
        }
      } else if (col < kCP) {
#pragma unroll
        for (int r = 0; r < 4; ++r) {
          const int row = rbase + i * 16 + (lane >> 4) * 4 + r;
          dst[(size_t)row * kLDQ + col] = 0.f;
        }
      }
    }
  }
}

// ---- table GEMM: Atab[t][128][kCP] = tabsplit[t] x Wk_{1+(t&1)} (3-term) --
__global__ void __launch_bounds__(256) gemm_tab_kernel(
    const unsigned short* __restrict__ Thi,
    const unsigned short* __restrict__ Tlo,
    const unsigned short* __restrict__ Wkhi,
    const unsigned short* __restrict__ Wklo, float* __restrict__ Atab) {
  __shared__ unsigned short smA[2][128 * 32];
  __shared__ unsigned short smB[2][128 * 32];
  const int t = blockIdx.y;
  const int n0 = blockIdx.x * 128;
  const int h = 1 + (t & 1);
  const unsigned short* Ah = Thi + (size_t)t * 128 * kKP;
  const unsigned short* Al = Tlo + (size_t)t * 128 * kKP;
  const unsigned short* Bh = Wkhi + (size_t)h * kBROWS * kKP;
  const unsigned short* Bl = Wklo + (size_t)h * kBROWS * kKP;
  const int tid = threadIdx.x;
  const int lane = tid & 63, w = tid >> 6;
  const int wm = w >> 1, wn = w & 1;

  const int sr0 = w * 16 + (lane >> 2);
  const int ss = lane & 3;
  size_t aoff[2], boff[2];
  int ldsb[2];
#pragma unroll
  for (int p = 0; p < 2; ++p) {
    const int r = p * 64 + sr0;
    const int kl = (ss ^ ((r >> 1) & 3)) * 8;
    aoff[p] = (size_t)r * kKP + kl;
    boff[p] = (size_t)(n0 + r) * kKP + kl;
    ldsb[p] = (p * 64 + w * 16) * 32;
  }
  int offA[4], offB[4];
#pragma unroll
  for (int i = 0; i < 4; ++i) {
    const int ra = wm * 64 + i * 16 + (lane & 15);
    offA[i] = ra * 32 + (((lane >> 4) ^ ((ra >> 1) & 3)) << 3);
    const int rb = wn * 64 + i * 16 + (lane & 15);
    offB[i] = rb * 32 + (((lane >> 4) ^ ((rb >> 1) & 3)) << 3);
  }
  f32x4 acc[4][4];
#pragma unroll
  for (int i = 0; i < 4; ++i)
#pragma unroll
    for (int j = 0; j < 4; ++j) acc[i][j] = f32x4{0.f, 0.f, 0.f, 0.f};

  for (int k0 = 0; k0 < kKP; k0 += 32) {
#pragma unroll
    for (int p = 0; p < 2; ++p) {
      gload16(Ah + aoff[p] + k0, &smA[0][ldsb[p]]);
      gload16(Al + aoff[p] + k0, &smA[1][ldsb[p]]);
      gload16(Bh + boff[p] + k0, &smB[0][ldsb[p]]);
      gload16(Bl + boff[p] + k0, &smB[1][ldsb[p]]);
    }
    __syncthreads();
    bf16x8 ah[4], al[4], bh[4], bl[4];
#pragma unroll
    for (int i = 0; i < 4; ++i) {
      ah[i] = *(const bf16x8*)&smA[0][offA[i]];
      al[i] = *(const bf16x8*)&smA[1][offA[i]];
      bh[i] = *(const bf16x8*)&smB[0][offB[i]];
      bl[i] = *(const bf16x8*)&smB[1][offB[i]];
    }
#pragma unroll
    for (int i = 0; i < 4; ++i)
#pragma unroll
      for (int j = 0; j < 4; ++j)
        acc[i][j] = __builtin_amdgcn_mfma_f32_16x16x32_bf16(ah[i], bh[j],
                                                            acc[i][j], 0, 0, 0);
#pragma unroll
    for (int i = 0; i < 4; ++i)
#pragma unroll
      for (int j = 0; j < 4; ++j)
        acc[i][j] = __builtin_amdgcn_mfma_f32_16x16x32_bf16(ah[i], bl[j],
                                                            acc[i][j], 0, 0, 0);
#pragma unroll
    for (int i = 0; i < 4; ++i)
#pragma unroll
      for (int j = 0; j < 4; ++j)
        acc[i][j] = __builtin_amdgcn_mfma_f32_16x16x32_bf16(al[i], bh[j],
                                                            acc[i][j], 0, 0, 0);
    __syncthreads();
  }

  float* C = Atab + (size_t)t * 128 * kCP;
  const int rbase = wm * 64;
  const int cbase = n0 + wn * 64;
#pragma unroll
  for (int i = 0; i < 4; ++i) {
#pragma unroll
    for (int j = 0; j < 4; ++j) {
      const int col = cbase + j * 16 + (lane & 15);
      if (col < kCP) {
        const float keep = (col < kC) ? 1.f : 0.f;
#pragma unroll
        for (int r = 0; r < 4; ++r) {
          const int row = rbase + i * 16 + (lane >> 4) * 4 + r;
          C[(size_t)row * kCP + col] = acc[i][j][r] * keep;
        }
      }
    }
  }
}

// ---- combine: fill qkb heads 1/2 from Atab tables + uv + (mu,rstd) --------
__global__ void __launch_bounds__(256) combine_qk_kernel(
    const float* __restrict__ Atab, const float* __restrict__ u,
    const float* __restrict__ v, const float* __restrict__ murs,
    float* __restrict__ qkb) {
  const int slot = blockIdx.y, n = blockIdx.x;
  const int i = n >> 6, j = n & 63, tid = threadIdx.x;
  const float mu = murs[2 * ((size_t)slot * kNPIX + n)];
  const float rs = murs[2 * ((size_t)slot * kNPIX + n) + 1];
  const float rsmu = rs * mu;
  float* dst = qkb + (size_t)slot * kQKB_FLOATS + (size_t)n * kLDQ;
  const float* A1 = Atab + ((size_t)(slot * 2 + 0) * 128 + j) * kCP;
  const float* A2 = Atab + ((size_t)(slot * 2 + 1) * 128 + i) * kCP;
  if (tid < kNG) {
    const int c4 = tid << 2;
    const float4 a1 = *(const float4*)&A1[c4];
    const float4 u1 = *(const float4*)&u[kCP + c4];
    const float4 v1 = *(const float4*)&v[kCP + c4];
    float4 r1;
    r1.x = rs * a1.x - rsmu * u1.x + v1.x;
    r1.y = rs * a1.y - rsmu * u1.y + v1.y;
    r1.z = rs * a1.z - rsmu * u1.z + v1.z;
    r1.w = rs * a1.w - rsmu * u1.w + v1.w;
    *(float4*)&dst[kCP + c4] = r1;
    const float4 a2 = *(const float4*)&A2[c4];
    const float4 u2 = *(const float4*)&u[2 * kCP + c4];
    const float4 v2 = *(const float4*)&v[2 * kCP + c4];
    float4 r2;
    r2.x = rs * a2.x - rsmu * u2.x + v2.x;
    r2.y = rs * a2.y - rsmu * u2.y + v2.y;
    r2.z = rs * a2.z - rsmu * u2.z + v2.z;
    r2.w = rs * a2.w - rsmu * u2.w + v2.w;
    *(float4*)&dst[2 * kCP + c4] = r2;
  }
}

// ---- fused sample+attn (r6/r9, unchanged) ---------------------------------
__global__ void __launch_bounds__(512, 6) sample_attn4_kernel(
    const float* __restrict__ imgt, const float* __restrict__ w2c,
    const float* __restrict__ Kin, const float* __restrict__ qkb,
    const float* __restrict__ qbk, const int plane_base,
    unsigned short* __restrict__ whi) {
  __shared__ __align__(16) float ctx[kL][kCP];
  __shared__ float sW2[kL][4];
  __shared__ int sI2[kL][4];
  __shared__ float sscp[2][48];
  __shared__ float ssc[48], swt[48];
  const int slot = blockIdx.y, plane = plane_base + slot;
  const int bid = blockIdx.x;
  const int n = ((bid & 7) << 9) | (bid >> 3);
  const int i = n >> 6, j = n & 63, tid = threadIdx.x;
  const float* qkn = qkb + (size_t)slot * kQKB_FLOATS + (size_t)n * kLDQ;

  if (tid < kL) {
    const int s = tid >> 2, m = tid & 3;
    const float Xi = -1.f + 2.f * i / 63.f;
    const float Xj = -1.f + 2.f * j / 63.f;
    const float Ts = -1.f + 2.f * s / 3.f;
    float px, py, pz;
    if (plane == 0) { px = Xj; py = Xi; pz = Ts; }
    else if (plane == 1) { px = Xj; py = Ts; pz = Xi; }
    else { px = Ts; py = Xj; pz = Xi; }
    const float* W = w2c + m * 16;
    const float c0 = W[0] * px + W[1] * py + W[2] * pz + W[3];
    const float c1 = W[4] * px + W[5] * py + W[6] * pz + W[7];
    const float c2 = W[8] * px + W[9] * py + W[10] * pz + W[11];
    const float* Km = Kin + m * 9;
    const float un = Km[0] * c0 + Km[1] * c1 + Km[2] * c2;
    const float vn = Km[3] * c0 + Km[4] * c1 + Km[5] * c2;
    const float ds = c2 + 1e-8f;
    const float u = un / ds, v = vn / ds;
    const bool mk =
        (c2 > 0.f && u >= 0.f && u < 64.f && v >= 0.f && v < 64.f);
    float w00 = 0.f, w10 = 0.f, w01 = 0.f, w11 = 0.f;
    int i00 = 0, i10 = 0, i01 = 0, i11 = 0;
    if (mk) {
      const float gx = 2.f * (u / 63.f) - 1.f;
      const float gy = 2.f * (v / 63.f) - 1.f;
      const float ix = (gx + 1.f) * 0.5f * 63.f;
      const float iy = (gy + 1.f) * 0.5f * 63.f;
      const float x0 = floorf(ix), y0 = floorf(iy);
      const float x1 = x0 + 1.f, y1 = y0 + 1.f;
      const float wx = ix - x0, wy = iy - y0;
      const float v00 = (x0 >= 0.f && x0 <= 63.f && y0 >= 0.f && y0 <= 63.f) ? 1.f : 0.f;
      const float v10 = (x1 >= 0.f && x1 <= 63.f && y0 >= 0.f && y0 <= 63.f) ? 1.f : 0.f;
      const float v01 = (x0 >= 0.f && x0 <= 63.f && y1 >= 0.f && y1 <= 63.f) ? 1.f : 0.f;
      const float v11 = (x1 >= 0.f && x1 <= 63.f && y1 >= 0.f && y1 <= 63.f) ? 1.f : 0.f;
      w00 = (1.f - wx) * (1.f - wy) * v00;
      w10 = wx * (1.f - wy) * v10;
      w01 = (1.f - wx) * wy * v01;
      w11 = wx * wy * v11;
      const int x0i = (int)fminf(fmaxf(x0, 0.f), 63.f);
      const int x1i = (int)fminf(fmaxf(x1, 0.f), 63.f);
      const int y0i = (int)fminf(fmaxf(y0, 0.f), 63.f);
      const int y1i = (int)fminf(fmaxf(y1, 0.f), 63.f);
      const int mb = m * kIMS2;
      i00 = mb + (y0i * 64 + x0i) * kCP;
      i10 = mb + (y0i * 64 + x1i) * kCP;
      i01 = mb + (y1i * 64 + x0i) * kCP;
      i11 = mb + (y1i * 64 + x1i) * kCP;
    }
    sI2[tid][0] = i00; sI2[tid][1] = i10; sI2[tid][2] = i01; sI2[tid][3] = i11;
    sW2[tid][0] = w00; sW2[tid][1] = w10; sW2[tid][2] = w01; sW2[tid][3] = w11;
  }
  __syncthreads();

  const int lane = tid & 63, wv = tid >> 6;
#pragma unroll
  for (int q = 0; q < 2; ++q) {
    const int l = (wv << 1) + q;
    const float a0 = sW2[l][0], a1 = sW2[l][1], a2 = sW2[l][2], a3 = sW2[l][3];
    const int b0 = sI2[l][0], b1 = sI2[l][1], b2 = sI2[l][2], b3 = sI2[l][3];
    for (int g = lane; g < kNG; g += 64) {
      const int c4 = g << 2;
      const float4 t0 = *(const float4*)&imgt[b0 + c4];
      const float4 t1 = *(const float4*)&imgt[b1 + c4];
      const float4 t2 = *(const float4*)&imgt[b2 + c4];
      const float4 t3 = *(const float4*)&imgt[b3 + c4];
      float4 r;
      r.x = fmaf(t0.x, a0, fmaf(t1.x, a1, fmaf(t2.x, a2, t3.x * a3)));
      r.y = fmaf(t0.y, a0, fmaf(t1.y, a1, fmaf(t2.y, a2, t3.y * a3)));
      r.z = fmaf(t0.z, a0, fmaf(t1.z, a1, fmaf(t2.z, a2, t3.z * a3)));
      r.w = fmaf(t0.w, a0, fmaf(t1.w, a1, fmaf(t2.w, a2, t3.w * a3)));
      *(float4*)&ctx[l][c4] = r;
    }
  }
  __syncthreads();

  const int g16 = tid >> 4, l16 = tid & 15;
  const float* qbkn = qbk + ((size_t)slot * kNPIX + n) * 3;
  {
    const int l = g16 & 15, half = g16 >> 4;
    float p0 = 0.f, p1 = 0.f, p2 = 0.f;
#pragma unroll
    for (int it = 0; it < 6; ++it) {
      const int c4 = (l16 + ((2 * it + half) << 4)) << 2;
      const float4 cv = *(const float4*)&ctx[l][c4];
      const float4 q0 = *(const float4*)&qkn[c4];
      const float4 q1 = *(const float4*)&qkn[kCP + c4];
      const float4 q2 = *(const float4*)&qkn[2 * kCP + c4];
      p0 = fmaf(cv.x, q0.x, fmaf(cv.y, q0.y, fmaf(cv.z, q0.z, fmaf(cv.w, q0.w, p0))));
      p1 = fmaf(cv.x, q1.x, fmaf(cv.y, q1.y, fmaf(cv.z, q1.z, fmaf(cv.w, q1.w, p1))));
      p2 = fmaf(cv.x, q2.x, fmaf(cv.y, q2.y, fmaf(cv.z, q2.z, fmaf(cv.w, q2.w, p2))));
    }
    if (half == 0 && l16 < 2) {
      const int c4 = (192 + l16) << 2;
      const float4 cv = *(const float4*)&ctx[l][c4];
      const float4 q0 = *(const float4*)&qkn[c4];
      const float4 q1 = *(const float4*)&qkn[kCP + c4];
      const float4 q2 = *(const float4*)&qkn[2 * kCP + c4];
      p0 = fmaf(cv.x, q0.x, fmaf(cv.y, q0.y, fmaf(cv.z, q0.z, fmaf(cv.w, q0.w, p0))));
      p1 = fmaf(cv.x, q1.x, fmaf(cv.y, q1.y, fmaf(cv.z, q1.z, fmaf(cv.w, q1.w, p1))));
      p2 = fmaf(cv.x, q2.x, fmaf(cv.y, q2.y, fmaf(cv.z, q2.z, fmaf(cv.w, q2.w, p2))));
    }
#pragma unroll
    for (int off = 8; off; off >>= 1) {
      p0 += __shfl_down(p0, off, 16);
      p1 += __shfl_down(p1, off, 16);
      p2 += __shfl_down(p2, off, 16);
    }
    if (l16 == 0) {
      sscp[half][l] = p0;
      sscp[half][16 + l] = p1;
      sscp[half][32 + l] = p2;
    }
  }
  __syncthreads();
  if (tid < 48) ssc[tid] = sscp[0][tid] + sscp[1][tid] + qbkn[tid >> 4];
  __syncthreads();
  if (tid < 3) {
    float mx = ssc[tid * 16];
#pragma unroll
    for (int l = 1; l < kL; ++l) mx = fmaxf(mx, ssc[tid * 16 + l]);
    float e[kL];
    float sum = 0.f;
#pragma unroll
    for (int l = 0; l < kL; ++l) {
      e[l] = expf(ssc[tid * 16 + l] - mx);
      sum += e[l];
    }
    const float inv = 1.f / sum;
#pragma unroll
    for (int l = 0; l < kL; ++l) swt[tid * 16 + l] = e[l] * inv;
  }
  __syncthreads();

  unsigned short* wh = whi + (size_t)slot * kWH_ELEMS + (size_t)n * kLDA;
  if (tid < 2 * kNG) {
    const int c4 = (tid >> 1) << 2;
    const int l0 = (tid & 1) << 3;
    float4 o0{0.f, 0.f, 0.f, 0.f}, o1{0.f, 0.f, 0.f, 0.f},
        o2{0.f, 0.f, 0.f, 0.f};
#pragma unroll
    for (int dl = 0; dl < 8; ++dl) {
      const int l = l0 + dl;
      const float4 cv = *(const float4*)&ctx[l][c4];
      const float s0 = swt[l], s1 = swt[16 + l], s2 = swt[32 + l];
      o0.x = fmaf(cv.x, s0, o0.x); o0.y = fmaf(cv.y, s0, o0.y);
      o0.z = fmaf(cv.z, s0, o0.z); o0.w = fmaf(cv.w, s0, o0.w);
      o1.x = fmaf(cv.x, s1, o1.x); o1.y = fmaf(cv.y, s1, o1.y);
      o1.z = fmaf(cv.z, s1, o1.z); o1.w = fmaf(cv.w, s1, o1.w);
      o2.x = fmaf(cv.x, s2, o2.x); o2.y = fmaf(cv.y, s2, o2.y);
      o2.z = fmaf(cv.z, s2, o2.z); o2.w = fmaf(cv.w, s2, o2.w);
    }
    o0.x += __shfl_xor(o0.x, 1); o0.y += __shfl_xor(o0.y, 1);
    o0.z += __shfl_xor(o0.z, 1); o0.w += __shfl_xor(o0.w, 1);
    o1.x += __shfl_xor(o1.x, 1); o1.y += __shfl_xor(o1.y, 1);
    o1.z += __shfl_xor(o1.z, 1); o1.w += __shfl_xor(o1.w, 1);
    o2.x += __shfl_xor(o2.x, 1); o2.y += __shfl_xor(o2.y, 1);
    o2.z += __shfl_xor(o2.z, 1); o2.w += __shfl_xor(o2.w, 1);
    if ((tid & 1) == 0) {
      float4 ov[3] = {o0, o1, o2};
#pragma unroll
      for (int h = 0; h < 3; ++h) {
        ushort4 hi;
        hi.x = f2bf(ov[h].x);
        hi.y = f2bf(ov[h].y);
        hi.z = f2bf(ov[h].z);
        hi.w = f2bf(ov[h].w);
        *(ushort4*)&wh[h * kKP + c4] = hi;
      }
    }
  }
  if (tid < 72) {
    const int h = tid / 24, k2 = kCP + tid % 24;
    wh[h * kKP + k2] = 0;
  }
}

// ---- out-GEMM: whi x Wv split (2-term), XCD panel swizzle (r6) ------------
__global__ void __launch_bounds__(256) gemm_out_kernel(
    const unsigned short* __restrict__ Ahi,
    const unsigned short* __restrict__ Bhi,
    const unsigned short* __restrict__ Blo, float* __restrict__ C,
    const float* __restrict__ bias) {
  __shared__ unsigned short smA[128 * 32];
  __shared__ unsigned short smB[2][128 * 32];
  const int slot = blockIdx.z / 3, h = blockIdx.z % 3;
  const int t = blockIdx.y * 7 + blockIdx.x;
  const int xcd = t & 7, idx = t >> 3;
  const int nb = idx % 7, mb = (xcd << 2) + idx / 7;
  const int m0 = mb * 128, n0 = nb * 128;
  const unsigned short* Ah = Ahi + (size_t)slot * kWH_ELEMS;
  float* Cs = C + (size_t)slot * kQN_FLOATS;
  const int tid = threadIdx.x;
  const int lane = tid & 63, w = tid >> 6;
  const int wm = w >> 1, wn = w & 1;

  const int sr0 = w * 16 + (lane >> 2);
  const int ss = lane & 3;
  size_t aoff[2], boff[2];
  int ldsb[2];
#pragma unroll
  for (int p = 0; p < 2; ++p) {
    const int r = p * 64 + sr0;
    const int kl = (ss ^ ((r >> 1) & 3)) * 8;
    aoff[p] = (size_t)(m0 + r) * kLDA + (size_t)h * kKP + kl;
    boff[p] = ((size_t)h * kBROWS + (n0 + r)) * kKP + kl;
    ldsb[p] = (p * 64 + w * 16) * 32;
  }
  int offA[4], offB[4];
#pragma unroll
  for (int i = 0; i < 4; ++i) {
    const int ra = wm * 64 + i * 16 + (lane & 15);
    offA[i] = ra * 32 + (((lane >> 4) ^ ((ra >> 1) & 3)) << 3);
    const int rb = wn * 64 + i * 16 + (lane & 15);
    offB[i] = rb * 32 + (((lane >> 4) ^ ((rb >> 1) & 3)) << 3);
  }
  f32x4 acc[4][4];
#pragma unroll
  for (int i = 0; i < 4; ++i)
#pragma unroll
    for (int j = 0; j < 4; ++j) acc[i][j] = f32x4{0.f, 0.f, 0.f, 0.f};

  for (int k0 = 0; k0 < kKP; k0 += 32) {
#pragma unroll
    for (int p = 0; p < 2; ++p) {
      gload16(Ah + aoff[p] + k0, &smA[ldsb[p]]);
      gload16(Bhi + boff[p] + k0, &smB[0][ldsb[p]]);
      gload16(Blo + boff[p] + k0, &smB[1][ldsb[p]]);
    }
    __syncthreads();
    bf16x8 ah[4], bh[4], bl[4];
#pragma unroll
    for (int i = 0; i < 4; ++i) {
      ah[i] = *(const bf16x8*)&smA[offA[i]];
      bh[i] = *(const bf16x8*)&smB[0][offB[i]];
      bl[i] = *(const bf16x8*)&smB[1][offB[i]];
    }
#pragma unroll
    for (int i = 0; i < 4; ++i)
#pragma unroll
      for (int j = 0; j < 4; ++j)
        acc[i][j] = __builtin_amdgcn_mfma_f32_16x16x32_bf16(ah[i], bh[j],
                                                            acc[i][j], 0, 0, 0);
#pragma unroll
    for (int i = 0; i < 4; ++i)
#pragma unroll
      for (int j = 0; j < 4; ++j)
        acc[i][j] = __builtin_amdgcn_mfma_f32_16x16x32_bf16(ah[i], bl[j],
                                                            acc[i][j], 0, 0, 0);
    __syncthreads();
  }

  const int rbase = m0 + wm * 64;
  const int cbase = n0 + wn * 64;
#pragma unroll
  for (int i = 0; i < 4; ++i) {
#pragma unroll
    for (int j = 0; j < 4; ++j) {
      const int col = cbase + j * 16 + (lane & 15);
      if (col < kC) {
        const float bb = bias[h * kC + col];
#pragma unroll
        for (int r = 0; r < 4; ++r) {
          const int row = rbase + i * 16 + (lane >> 4) * 4 + r;
          Cs[(size_t)row * kQD + h * kC + col] = acc[i][j][r] + bb;
        }
      }
    }
  }
}

// ======================= tier-D f32 fallback path ==========================
__global__ void __launch_bounds__(256) build_q_f32(
    const float* __restrict__ q_xy, const float* __restrict__ q_xz,
    const float* __restrict__ q_yz, const int plane,
    const float* __restrict__ ln_g, const float* __restrict__ ln_b,
    const float* __restrict__ bk, float* __restrict__ qn,
    float* __restrict__ qbk) {
  const float* qp = (plane == 0) ? q_xy : (plane == 1) ? q_xz : q_yz;
  const float* qo0 = (plane == 0) ? q_xz : q_xy;
  const float* qo1 = (plane == 2) ? q_xz : q_yz;
  const int n = blockIdx.x, i = n >> 6, j = n & 63, tid = threadIdx.x;
  __shared__ float qf[kQD];
  __shared__ int sIdx[2][4][4];
  __shared__ float sW[2][4][4];
  __shared__ float red[16];

  if (tid < 8) {
    const int part = tid >> 2, s = tid & 3;
    const float Xi = -1.f + 2.f * i / 63.f;
    const float Xj = -1.f + 2.f * j / 63.f;
    const float Ts = -1.f + 2.f * s / 3.f;
    float a, b;
    if (plane == 0) { a = part ? Xi : Xj; b = Ts; }
    else if (plane == 1) {
      if (part == 0) { a = Xj; b = Ts; } else { a = Ts; b = Xi; }
    } else { a = Ts; b = part ? Xi : Xj; }
    const float ga = fminf(fmaxf((a * 0.5f + 0.5f) * 63.f, 0.f), 63.f);
    const float gb = fminf(fmaxf((b * 0.5f + 0.5f) * 63.f, 0.f), 63.f);
    const float ix = fminf(fmaxf((ga + 1.f) * 0.5f * 63.f, 0.f), 63.f);
    const float iy = fminf(fmaxf((gb + 1.f) * 0.5f * 63.f, 0.f), 63.f);
    const float x0 = floorf(ix), y0 = floorf(iy);
    const float wx = ix - x0, wy = iy - y0;
    const int x0i = (int)x0, y0i = (int)y0;
    const int x1i = (x0i + 1 > 63) ? 63 : x0i + 1;
    const int y1i = (y0i + 1 > 63) ? 63 : y0i + 1;
    sIdx[part][s][0] = (y0i * 64 + x0i) * kC;
    sIdx[part][s][1] = (y0i * 64 + x1i) * kC;
    sIdx[part][s][2] = (y1i * 64 + x0i) * kC;
    sIdx[part][s][3] = (y1i * 64 + x1i) * kC;
    sW[part][s][0] = (1.f - wx) * (1.f - wy);
    sW[part][s][1] = wx * (1.f - wy);
    sW[part][s][2] = (1.f - wx) * wy;
    sW[part][s][3] = wx * wy;
  }
  __syncthreads();
  for (int c = tid; c < kC; c += 256) {
    qf[c] = qp[(size_t)n * kC + c];
    float a1 = 0.f, a2 = 0.f;
#pragma unroll
    for (int s = 0; s < 4; ++s) {
      a1 += qo0[sIdx[0][s][0] + c] * sW[0][s][0]
          + qo0[sIdx[0][s][1] + c] * sW[0][s][1]
          + qo0[sIdx[0][s][2] + c] * sW[0][s][2]
          + qo0[sIdx[0][s][3] + c] * sW[0][s][3];
      a2 += qo1[sIdx[1][s][0] + c] * sW[1][s][0]
          + qo1[sIdx[1][s][1] + c] * sW[1][s][1]
          + qo1[sIdx[1][s][2] + c] * sW[1][s][2]
          + qo1[sIdx[1][s][3] + c] * sW[1][s][3];
    }
    qf[kC + c] = a1 * 0.25f;
    qf[2 * kC + c] = a2 * 0.25f;
  }
  __syncthreads();
  float sm = 0.f;
  for (int idx = tid; idx < kQD; idx += 256) sm += qf[idx];
#pragma unroll
  for (int off = 32; off; off >>= 1) sm += __shfl_down(sm, off);
  if ((tid & 63) == 0) red[tid >> 6] = sm;
  __syncthreads();
  const float mu = (red[0] + red[1] + red[2] + red[3]) * (1.f / kQD);
  __syncthreads();
  float sq = 0.f;
  for (int idx = tid; idx < kQD; idx += 256) {
    const float d = qf[idx] - mu;
    sq += d * d;
  }
#pragma unroll
  for (int off = 32; off; off >>= 1) sq += __shfl_down(sq, off);
  if ((tid & 63) == 0) red[tid >> 6] = sq;
  __syncthreads();
  const float var = (red[0] + red[1] + red[2] + red[3]) * (1.f / kQD);
  const float rstd = 1.f / sqrtf(var + 1e-5f);
  __syncthreads();
  float h0 = 0.f, h1 = 0.f, h2 = 0.f;
  for (int idx = tid; idx < kQD; idx += 256) {
    const float v = (qf[idx] - mu) * rstd * ln_g[idx] + ln_b[idx];
    qn[(size_t)n * kQD + idx] = v;
    const float pb = v * bk[idx];
    if (idx < kC) h0 += pb;
    else if (idx < 2 * kC) h1 += pb;
    else h2 += pb;
  }
#pragma unroll
  for (int off = 32; off; off >>= 1) {
    h0 += __shfl_down(h0, off);
    h1 += __shfl_down(h1, off);
    h2 += __shfl_down(h2, off);
  }
  if ((tid & 63) == 0) {
    red[(tid >> 6) * 4 + 0] = h0;
    red[(tid >> 6) * 4 + 1] = h1;
    red[(tid >> 6) * 4 + 2] = h2;
  }
  __syncthreads();
  if (tid < 3)
    qbk[n * 3 + tid] = red[tid] + red[4 + tid] + red[8 + tid] + red[12 + tid];
}

__global__ void __launch_bounds__(256) sample_attn_f32(
    const float* __restrict__ src, const float* __restrict__ w2c,
    const float* __restrict__ Kin, const float* __restrict__ qk,
    const float* __restrict__ qbk, const int plane, float* __restrict__ wctx) {
  __shared__ float ctx[kL * kC];
  __shared__ float su[kL], sv[kL], smk[kL];
  __shared__ float spart[4][48];
  __shared__ float ssc[48];
  __shared__ float swt[48];
  const int n = blockIdx.x, i = n >> 6, j = n & 63, tid = threadIdx.x;

  if (tid < kL) {
    const int s = tid >> 2, m = tid & 3;
    const float Xi = -1.f + 2.f * i / 63.f;
    const float Xj = -1.f + 2.f * j / 63.f;
    const float Ts = -1.f + 2.f * s / 3.f;
    float px, py, pz;
    if (plane == 0) { px = Xj; py = Xi; pz = Ts; }
    else if (plane == 1) { px = Xj; py = Ts; pz = Xi; }
    else { px = Ts; py = Xj; pz = Xi; }
    const float* W = w2c + m * 16;
    const float c0 = W[0] * px + W[1] * py + W[2] * pz + W[3];
    const float c1 = W[4] * px + W[5] * py + W[6] * pz + W[7];
    const float c2 = W[8] * px + W[9] * py + W[10] * pz + W[11];
    const float* Km = Kin + m * 9;
    const float un = Km[0] * c0 + Km[1] * c1 + Km[2] * c2;
    const float vn = Km[3] * c0 + Km[4] * c1 + Km[5] * c2;
    const float ds = c2 + 1e-8f;
    const float u = un / ds, v = vn / ds;
    const float mk =
        (c2 > 0.f && u >= 0.f && u < 64.f && v >= 0.f && v < 64.f) ? 1.f : 0.f;
    su[tid] = u; sv[tid] = v; smk[tid] = mk;
  }
  __syncthreads();

  for (int l = 0; l < kL; ++l) {
    const int m = l & 3;
    const float u = su[l], v = sv[l], mk = smk[l];
    float w00 = 0.f, w10 = 0.f, w01 = 0.f, w11 = 0.f;
    int i00 = 0, i10 = 0, i01 = 0, i11 = 0;
    if (mk != 0.f) {
      const float gx = 2.f * (u / 63.f) - 1.f;
      const float gy = 2.f * (v / 63.f) - 1.f;
      const float ix = (gx + 1.f) * 0.5f * 63.f;
      const float iy = (gy + 1.f) * 0.5f * 63.f;
      const float x0 = floorf(ix), y0 = floorf(iy);
      const float x1 = x0 + 1.f, y1 = y0 + 1.f;
      const float wx = ix - x0, wy = iy - y0;
      const float v00 = (x0 >= 0.f && x0 <= 63.f && y0 >= 0.f && y0 <= 63.f) ? 1.f : 0.f;
      const float v10 = (x1 >= 0.f && x1 <= 63.f && y0 >= 0.f && y0 <= 63.f) ? 1.f : 0.f;
      const float v01 = (x0 >= 0.f && x0 <= 63.f && y1 >= 0.f && y1 <= 63.f) ? 1.f : 0.f;
      const float v11 = (x1 >= 0.f && x1 <= 63.f && y1 >= 0.f && y1 <= 63.f) ? 1.f : 0.f;
      w00 = (1.f - wx) * (1.f - wy) * v00;
      w10 = wx * (1.f - wy) * v10;
      w01 = (1.f - wx) * wy * v01;
      w11 = wx * wy * v11;
      const int x0i = (int)fminf(fmaxf(x0, 0.f), 63.f);
      const int x1i = (int)fminf(fmaxf(x1, 0.f), 63.f);
      const int y0i = (int)fminf(fmaxf(y0, 0.f), 63.f);
      const int y1i = (int)fminf(fmaxf(y1, 0.f), 63.f);
      const int mb = m * kImgMStride;
      i00 = mb + (y0i * 64 + x0i);
      i10 = mb + (y0i * 64 + x1i);
      i01 = mb + (y1i * 64 + x0i);
      i11 = mb + (y1i * 64 + x1i);
    }
    for (int c = tid; c < kC; c += 256) {
      const int cs = c * (kG * kG);
      ctx[l * kC + c] = src[i00 + cs] * w00 + src[i10 + cs] * w10 +
                        src[i01 + cs] * w01 + src[i11 + cs] * w11;
    }
  }
  __syncthreads();

  float acc[48];
#pragma unroll
  for (int t = 0; t < 48; ++t) acc[t] = 0.f;
  const float* qkn = qk + (size_t)n * kQD;
  for (int c = tid; c < kC; c += 256) {
    const float q0 = qkn[c], q1 = qkn[kC + c], q2 = qkn[2 * kC + c];
#pragma unroll
    for (int l = 0; l < kL; ++l) {
      const float cv = ctx[l * kC + c];
      acc[l] = fmaf(cv, q0, acc[l]);
      acc[16 + l] = fmaf(cv, q1, acc[16 + l]);
      acc[32 + l] = fmaf(cv, q2, acc[32 + l]);
    }
  }
#pragma unroll
  for (int t = 0; t < 48; ++t) {
    float x = acc[t];
#pragma unroll
    for (int off = 32; off; off >>= 1) x += __shfl_down(x, off);
    acc[t] = x;
  }
  if ((tid & 63) == 0) {
#pragma unroll
    for (int t = 0; t < 48; ++t) spart[tid >> 6][t] = acc[t];
  }
  __syncthreads();
  if (tid < 48)
    ssc[tid] = spart[0][tid] + spart[1][tid] + spart[2][tid] + spart[3][tid] +
               qbk[n * 3 + (tid >> 4)];
  __syncthreads();
  if (tid < 3) {
    float mx = ssc[tid * 16];
#pragma unroll
    for (int l = 1; l < kL; ++l) mx = fmaxf(mx, ssc[tid * 16 + l]);
    float e[kL];
    float sum = 0.f;
#pragma unroll
    for (int l = 0; l < kL; ++l) {
      e[l] = expf(ssc[tid * 16 + l] - mx);
      sum += e[l];
    }
    const float inv = 1.f / sum;
#pragma unroll
    for (int l = 0; l < kL; ++l) swt[tid * 16 + l] = e[l] * inv;
  }
  __syncthreads();
  for (int c = tid; c < kC; c += 256) {
    float o0 = 0.f, o1 = 0.f, o2 = 0.f;
#pragma unroll
    for (int l = 0; l < kL; ++l) {
      const float cv = ctx[l * kC + c];
      o0 = fmaf(swt[l], cv, o0);
      o1 = fmaf(swt[16 + l], cv, o1);
      o2 = fmaf(swt[32 + l], cv, o2);
    }
    float* wn = wctx + (size_t)n * kQD;
    wn[c] = o0;
    wn[kC + c] = o1;
    wn[2 * kC + c] = o2;
  }
}

template <bool BT, bool BIAS>
__global__ void __launch_bounds__(256) gemm_f32(
    const float* __restrict__ A, const float* __restrict__ B,
    float* __restrict__ Cp, const float* __restrict__ bias, const int M,
    const int N, const int K, const int lda, const int ldb, const int ldc,
    const int hstride) {
  constexpr int BM = 128, BN = 64, BK = 16;
  __shared__ float As[BK][BM + 4];
  __shared__ float Bs[BK][BN + 4];
  const int hoff = blockIdx.z * hstride;
  const int m0 = blockIdx.y * BM, n0 = blockIdx.x * BN;
  const int tid = threadIdx.x;
  const int ty = tid >> 4, tx = tid & 15;
  float acc[8][4];
#pragma unroll
  for (int r = 0; r < 8; ++r)
#pragma unroll
    for (int c = 0; c < 4; ++c) acc[r][c] = 0.f;
  for (int k0 = 0; k0 < K; k0 += BK) {
#pragma unroll
    for (int p = 0; p < 8; ++p) {
      const int idx = tid + p * 256;
      const int mm = idx >> 4, kk = idx & 15;
      float v = 0.f;
      if (k0 + kk < K) v = A[(size_t)(m0 + mm) * lda + hoff + k0 + kk];
      As[kk][mm] = v;
    }
    if (BT) {
#pragma unroll
      for (int p = 0; p < 4; ++p) {
        const int idx = tid + p * 256;
        const int jj = idx >> 4, kk = idx & 15;
        float v = 0.f;
        if ((n0 + jj) < N && (k0 + kk) < K)
          v = B[(size_t)(n0 + jj) * ldb + hoff + k0 + kk];
        Bs[kk][jj] = v;
      }
    } else {
#pragma unroll
      for (int p = 0; p < 4; ++p) {
        const int idx = tid + p * 256;
        const int kk = idx >> 6, jj = idx & 63;
        float v = 0.f;
        if ((n0 + jj) < N && (k0 + kk) < K)
          v = B[(size_t)(k0 + kk) * ldb + hoff + n0 + jj];
        Bs[kk][jj] = v;
      }
    }
    __syncthreads();
#pragma unroll
    for (int kk = 0; kk < BK; ++kk) {
      float a[8], b[4];
#pragma unroll
      for (int r = 0; r < 8; ++r) a[r] = As[kk][ty * 8 + r];
#pragma unroll
      for (int c = 0; c < 4; ++c) b[c] = Bs[kk][tx * 4 + c];
#pragma unroll
      for (int r = 0; r < 8; ++r)
#pragma unroll
        for (int c = 0; c < 4; ++c) acc[r][c] = fmaf(a[r], b[c], acc[r][c]);
    }
    __syncthreads();
  }
#pragma unroll
  for (int r = 0; r < 8; ++r) {
    const int mm = m0 + ty * 8 + r;
    if (mm >= M) continue;
#pragma unroll
    for (int c = 0; c < 4; ++c) {
      const int jj = n0 + tx * 4 + c;
      if (jj < N) {
        float v = acc[r][c];
        if (BIAS) v += bias[hoff + jj];
        Cp[(size_t)mm * ldc + hoff + jj] = v;
      }
    }
  }
}

// ---------------------------------------------------------------------------
extern "C" void kernel_launch(void* const* d_in, const int* in_sizes, int n_in,
                              void* d_out, int out_size, void* d_ws,
                              size_t ws_size, hipStream_t stream) {
  const float* imgf = (const float*)d_in[0];
  const float* c2w = (const float*)d_in[2];
  const float* Kin = (const float*)d_in[3];
  const float* qpl[3] = {(const float*)d_in[5], (const float*)d_in[6],
                         (const float*)d_in[7]};
  const float* Wk = (const float*)d_in[8];
  const float* bk = (const float*)d_in[9];
  const float* Wv = (const float*)d_in[10];
  const float* bv = (const float*)d_in[11];
  const float* ln_g = (const float*)d_in[12];
  const float* ln_b = (const float*)d_in[13];
  float* out = (float*)d_out;
  char* wsb = (char*)d_ws;

  const size_t IMGT_FLOATS = (size_t)kNV * kIMS2;

  size_t off = 0;
  auto take = [&](size_t bytes) {
    size_t p = off;
    off = (off + bytes + 511) & ~(size_t)511;
    return p;
  };
  const size_t o_w2c = take(64 * 4);
  const size_t o_qbk = take((size_t)3 * kNPIX * 3 * 4);
  const size_t o_qkb = take((size_t)3 * kQKB_FLOATS * 4);
  const size_t o_wkhi = take(kW_ELEMS * 2);
  const size_t o_wklo = take(kW_ELEMS * 2);
  const size_t o_wvthi = take(kW_ELEMS * 2);
  const size_t o_wvtlo = take(kW_ELEMS * 2);
  const size_t o_a0hi = take((size_t)3 * kA0_ELEMS * 2);
  const size_t o_a0lo = take((size_t)3 * kA0_ELEMS * 2);
  const size_t o_whi = take((size_t)3 * kWH_ELEMS * 2);
  const size_t o_murs = take((size_t)3 * kNPIX * 2 * 4);
  const size_t o_u = take((size_t)3 * kCP * 4);
  const size_t o_v = take((size_t)3 * kCP * 4);
  const size_t o_tab = take(kTAB_FLOATS * 4);
  const size_t o_tshi = take((size_t)6 * 128 * kKP * 2);
  const size_t o_tslo = take((size_t)6 * 128 * kKP * 2);
  const size_t o_atab = take((size_t)6 * 128 * kCP * 4);
  const size_t o_imgt = take(IMGT_FLOATS * 4);
  const size_t need = off;

  if (ws_size >= need) {
    float* w2c = (float*)(wsb + o_w2c);
    float* qbk = (float*)(wsb + o_qbk);
    float* qkb = (float*)(wsb + o_qkb);
    unsigned short* wkhi = (unsigned short*)(wsb + o_wkhi);
    unsigned short* wklo = (unsigned short*)(wsb + o_wklo);
    unsigned short* wvthi = (unsigned short*)(wsb + o_wvthi);
    unsigned short* wvtlo = (unsigned short*)(wsb + o_wvtlo);
    unsigned short* a0hi = (unsigned short*)(wsb + o_a0hi);
    unsigned short* a0lo = (unsigned short*)(wsb + o_a0lo);
    unsigned short* whi = (unsigned short*)(wsb + o_whi);
    float* murs = (float*)(wsb + o_murs);
    float* uvec = (float*)(wsb + o_u);
    float* vvec = (float*)(wsb + o_v);
    float* meantab = (float*)(wsb + o_tab);
    unsigned short* tshi = (unsigned short*)(wsb + o_tshi);
    unsigned short* tslo = (unsigned short*)(wsb + o_tslo);
    float* atab = (float*)(wsb + o_atab);
    float* imgt = (float*)(wsb + o_imgt);

    invert4_kernel<<<1, 64, 0, stream>>>(c2w, w2c);
    prep_wk_kernel<<<dim3(kBROWS, 3), 256, 0, stream>>>(Wk, wkhi, wklo);
    prep_wvt_kernel<<<dim3(13, 14, 3), 256, 0, stream>>>(Wv, wvthi, wvtlo);
    prep_meantab_kernel<<<dim3(64, 6), 256, 0, stream>>>(qpl[0], qpl[1],
                                                         qpl[2], meantab);
    prep_tabsplit_kernel<<<dim3(128, 6), 256, 0, stream>>>(meantab, ln_g,
                                                           tshi, tslo);
    prep_uv_kernel<<<dim3(4, 3), 256, 0, stream>>>(Wk, ln_g, ln_b, uvec,
                                                   vvec);
    transpose_img_kernel<<<dim3(64, kNV), 256, 0, stream>>>(imgf, imgt);
    gemm_tab_kernel<<<dim3(7, 6), 256, 0, stream>>>(tshi, tslo, wkhi, wklo,
                                                    atab);
    build_a0_kernel<<<dim3(kNPIX, 3), 256, 0, stream>>>(
        qpl[0], qpl[1], qpl[2], meantab, ln_g, ln_b, bk, a0hi, a0lo, murs,
        qbk);
    gemm_a0_kernel<<<dim3(7, 32, 3), 256, 0, stream>>>(
        a0hi, a0lo, wkhi, wklo, murs, uvec, vvec, qkb);
    combine_qk_kernel<<<dim3(kNPIX, 3), 256, 0, stream>>>(atab, uvec, vvec,
                                                          murs, qkb);
    sample_attn4_kernel<<<dim3(kNPIX, 3), 512, 0, stream>>>(
        imgt, w2c, Kin, qkb, qbk, 0, whi);
    gemm_out_kernel<<<dim3(7, 32, 9), 256, 0, stream>>>(whi, wvthi, wvtlo,
                                                        out, bv);
  } else {
    // tier-D: f32 fallback (r1-style)
    float* ws = (float*)d_ws;
    const size_t OFF_QBK = 64;
    const size_t OFF_BIG = OFF_QBK + (size_t)kNPIX * 3;
    float* w2c = ws;
    float* qbk = ws + OFF_QBK;
    float* qn = ws + OFF_BIG;
    float* qkb = qn + kQN_FLOATS;

    invert4_kernel<<<1, 64, 0, stream>>>(c2w, w2c);
    for (int p = 0; p < 3; ++p) {
      build_q_f32<<<kNPIX, 256, 0, stream>>>(qpl[0], qpl[1], qpl[2], p, ln_g,
                                             ln_b, bk, qn, qbk);
      gemm_f32<true, false><<<dim3(13, 32, 3), 256, 0, stream>>>(
          qn, Wk, qkb, nullptr, kNPIX, kC, kC, kQD, kQD, kQD, kC);
      sample_attn_f32<<<kNPIX, 256, 0, stream>>>(imgf, w2c, Kin, qkb, qbk, p,
                                                 qn);
      gemm_f32<false, true><<<dim3(13, 32, 3), 256, 0, stream>>>(
          qn, Wv, out + (size_t)p * kQN_FLOATS, bv, kNPIX, kC, kC, kQD, kQD,
          kQD, kC);
    }
  }
}

// Round 12
// 669.915 us; speedup vs baseline: 1.0612x; 1.0612x over previous
//
#include <hip/hip_runtime.h>
#include <math.h>

// ---------------------------------------------------------------------------
// Round 11: r10 factorization kept (passed, absmax 0.0156) with its latency
// overheads removed: (a) combine_qk fused into attn's score phase as 7
// register dots (S_h = rs*(ctx.a_h) - rs*mu*(ctx.u_h) + ctx.v_h) -> attn no
// longer reads qkb heads 1/2 (-76MB HBM), combine kernel deleted, qk0 buffer
// compact [4096][776]; (b) prep_uv parallelized (776x3 blocks, coalesced
// K-reduction) instead of 12-block serial loop.
// ---------------------------------------------------------------------------

constexpr int kG = 64, kS = 4, kC = 771, kNV = 4;
constexpr int kQD = 2313;
constexpr int kNPIX = 4096;
constexpr int kL = 16;
constexpr int kImgMStride = kC * kG * kG;
constexpr int kKP = 800;
constexpr int kLDA = 2400;
constexpr int kBROWS = 896;
constexpr int kCP = 776;
constexpr int kNG = kCP / 4;
constexpr int kIMS2 = kNPIX * kCP;

constexpr size_t kQ0_FLOATS = (size_t)kNPIX * kCP;  // per-slot compact qk0
constexpr size_t kW_ELEMS = (size_t)3 * kBROWS * kKP;
constexpr size_t kA0_ELEMS = (size_t)kNPIX * kKP;   // per-slot a0 split
constexpr size_t kWH_ELEMS = (size_t)kNPIX * kLDA;  // per-slot whi
constexpr size_t kQN_FLOATS = (size_t)kNPIX * kQD;
constexpr size_t kTAB_FLOATS = (size_t)6 * 64 * kC;

using bf16x8 = __attribute__((ext_vector_type(8))) short;
using f32x4 = __attribute__((ext_vector_type(4))) float;

__device__ __forceinline__ unsigned short f2bf(float x) {
  unsigned int u = __float_as_uint(x);
  u = (u + 0x7FFFu + ((u >> 16) & 1u)) >> 16;
  return (unsigned short)u;
}
__device__ __forceinline__ float bf2f(unsigned short h) {
  return __uint_as_float(((unsigned int)h) << 16);
}
__device__ __forceinline__ void gload16(const unsigned short* g,
                                        unsigned short* l) {
  __builtin_amdgcn_global_load_lds(
      (const __attribute__((address_space(1))) void*)g,
      (__attribute__((address_space(3))) void*)l, 16, 0, 0);
}

// ---- tiny 4x4 batched inverse --------------------------------------------
__global__ void invert4_kernel(const float* __restrict__ c2w,
                               float* __restrict__ w2c) {
  const int m = threadIdx.x;
  if (m >= kNV) return;
  float a[4][8];
  for (int r = 0; r < 4; ++r)
    for (int c = 0; c < 4; ++c) {
      a[r][c] = c2w[m * 16 + r * 4 + c];
      a[r][4 + c] = (r == c) ? 1.f : 0.f;
    }
  for (int col = 0; col < 4; ++col) {
    int piv = col;
    float best = fabsf(a[col][col]);
    for (int r = col + 1; r < 4; ++r) {
      float t = fabsf(a[r][col]);
      if (t > best) { best = t; piv = r; }
    }
    if (piv != col)
      for (int c = 0; c < 8; ++c) {
        float t = a[col][c]; a[col][c] = a[piv][c]; a[piv][c] = t;
      }
    const float inv = 1.f / a[col][col];
    for (int c = 0; c < 8; ++c) a[col][c] *= inv;
    for (int r = 0; r < 4; ++r)
      if (r != col) {
        const float f = a[r][col];
        for (int c = 0; c < 8; ++c) a[r][c] -= f * a[col][c];
      }
  }
  for (int r = 0; r < 4; ++r)
    for (int c = 0; c < 4; ++c) w2c[m * 16 + r * 4 + c] = a[r][4 + c];
}

// ---- image transpose [NV,C,H,W] -> [NV,H,W,776] f32 ----------------------
__global__ void __launch_bounds__(256) transpose_img_kernel(
    const float* __restrict__ img, float* __restrict__ out) {
  __shared__ float t[64][65];
  const int y = blockIdx.x, m = blockIdx.y, tid = threadIdx.x;
  const size_t obase = ((size_t)m * kNPIX + (size_t)y * 64) * kCP;
  for (int c0 = 0; c0 < kC; c0 += 64) {
    const int cw = (kC - c0) < 64 ? (kC - c0) : 64;
    for (int idx = tid; idx < cw * 64; idx += 256) {
      const int cl = idx >> 6, x = idx & 63;
      t[cl][x] = img[(((size_t)m * kC + c0 + cl) * 64 + y) * 64 + x];
    }
    __syncthreads();
    for (int idx = tid; idx < 64 * 64; idx += 256) {
      const int x = idx >> 6, cl = idx & 63;
      if (cl < cw) out[obase + (size_t)x * kCP + c0 + cl] = t[cl][x];
    }
    __syncthreads();
  }
  for (int idx = tid; idx < 64 * 8; idx += 256) {
    const int x = idx >> 3, c = 768 + (idx & 7);
    if (c >= kC && c < kCP) out[obase + (size_t)x * kCP + c] = 0.f;
  }
}

// ---- weight prep ----------------------------------------------------------
__global__ void __launch_bounds__(256) prep_wk_kernel(
    const float* __restrict__ Wk, unsigned short* __restrict__ hi,
    unsigned short* __restrict__ lo) {
  const int c = blockIdx.x, h = blockIdx.y;
  const size_t base = ((size_t)h * kBROWS + c) * kKP;
  for (int k = threadIdx.x; k < kKP; k += 256) {
    float v = (c < kC && k < kC) ? Wk[(size_t)c * kQD + h * kC + k] : 0.f;
    const unsigned short a = f2bf(v);
    hi[base + k] = a;
    lo[base + k] = f2bf(v - bf2f(a));
  }
}

__global__ void __launch_bounds__(256) prep_wvt_kernel(
    const float* __restrict__ Wv, unsigned short* __restrict__ hi,
    unsigned short* __restrict__ lo) {
  __shared__ float t[64][65];
  const int k0 = blockIdx.x * 64, j0 = blockIdx.y * 64, h = blockIdx.z;
  const int tx = threadIdx.x & 63, ty4 = threadIdx.x >> 6;
  for (int ty = ty4; ty < 64; ty += 4) {
    const int k = k0 + ty, j = j0 + tx;
    t[ty][tx] = (k < kC && j < kC) ? Wv[(size_t)k * kQD + h * kC + j] : 0.f;
  }
  __syncthreads();
  for (int ty = ty4; ty < 64; ty += 4) {
    const int j = j0 + ty, k = k0 + tx;
    if (j < kBROWS && k < kKP) {
      const float v = t[tx][ty];
      const unsigned short a = f2bf(v);
      const size_t p = ((size_t)h * kBROWS + j) * kKP + k;
      hi[p] = a;
      lo[p] = f2bf(v - bf2f(a));
    }
  }
}

// ---- other-plane mean table (bit-exact) ------------------------------------
__global__ void __launch_bounds__(256) prep_meantab_kernel(
    const float* __restrict__ q_xy, const float* __restrict__ q_xz,
    const float* __restrict__ q_yz, float* __restrict__ tab) {
  const int v = blockIdx.x;  // 0..63
  const int t = blockIdx.y;  // plane*2+part
  const int plane = t >> 1, part = t & 1;
  const float* src;
  if (plane == 0) src = part ? q_yz : q_xz;
  else if (plane == 1) src = part ? q_yz : q_xy;
  else src = part ? q_xz : q_xy;
  __shared__ int sIdx[4][4];
  __shared__ float sW[4][4];
  if (threadIdx.x < 4) {
    const int s = threadIdx.x;
    const float Xv = -1.f + 2.f * v / 63.f;
    const float Ts = -1.f + 2.f * s / 3.f;
    float a, b;
    if (plane == 0) { a = Xv; b = Ts; }
    else if (plane == 1) {
      if (part == 0) { a = Xv; b = Ts; } else { a = Ts; b = Xv; }
    } else { a = Ts; b = Xv; }
    const float ga = fminf(fmaxf((a * 0.5f + 0.5f) * 63.f, 0.f), 63.f);
    const float gb = fminf(fmaxf((b * 0.5f + 0.5f) * 63.f, 0.f), 63.f);
    const float ix = fminf(fmaxf((ga + 1.f) * 0.5f * 63.f, 0.f), 63.f);
    const float iy = fminf(fmaxf((gb + 1.f) * 0.5f * 63.f, 0.f), 63.f);
    const float x0 = floorf(ix), y0 = floorf(iy);
    const float wx = ix - x0, wy = iy - y0;
    const int x0i = (int)x0, y0i = (int)y0;
    const int x1i = (x0i + 1 > 63) ? 63 : x0i + 1;
    const int y1i = (y0i + 1 > 63) ? 63 : y0i + 1;
    sIdx[s][0] = (y0i * 64 + x0i) * kC;
    sIdx[s][1] = (y0i * 64 + x1i) * kC;
    sIdx[s][2] = (y1i * 64 + x0i) * kC;
    sIdx[s][3] = (y1i * 64 + x1i) * kC;
    sW[s][0] = (1.f - wx) * (1.f - wy);
    sW[s][1] = wx * (1.f - wy);
    sW[s][2] = (1.f - wx) * wy;
    sW[s][3] = wx * wy;
  }
  __syncthreads();
  for (int c = threadIdx.x; c < kC; c += 256) {
    float a1 = 0.f;
#pragma unroll
    for (int s = 0; s < 4; ++s) {
      a1 += src[sIdx[s][0] + c] * sW[s][0] + src[sIdx[s][1] + c] * sW[s][1]
          + src[sIdx[s][2] + c] * sW[s][2] + src[sIdx[s][3] + c] * sW[s][3];
    }
    tab[((size_t)t * 64 + v) * kC + c] = a1 * 0.25f;
  }
}

// ---- bf16 split of meantab*g (A-operand for table GEMMs, M padded 128) ----
__global__ void __launch_bounds__(256) prep_tabsplit_kernel(
    const float* __restrict__ tab, const float* __restrict__ ln_g,
    unsigned short* __restrict__ hi, unsigned short* __restrict__ lo) {
  const int v = blockIdx.x;  // 0..127
  const int t = blockIdx.y;  // 0..5
  const int h = 1 + (t & 1);
  const size_t base = ((size_t)t * 128 + v) * kKP;
  for (int k = threadIdx.x; k < kKP; k += 256) {
    float val = 0.f;
    if (v < 64 && k < kC)
      val = tab[((size_t)t * 64 + v) * kC + k] * ln_g[h * kC + k];
    const unsigned short a = f2bf(val);
    hi[base + k] = a;
    lo[base + k] = f2bf(val - bf2f(a));
  }
}

// ---- u_h = Wk_h^T g, v_h = Wk_h^T b — PARALLEL (block per (c,h)) ----------
__global__ void __launch_bounds__(256) prep_uv_kernel(
    const float* __restrict__ Wk, const float* __restrict__ ln_g,
    const float* __restrict__ ln_b, float* __restrict__ u,
    float* __restrict__ v) {
  const int c = blockIdx.x;  // 0..kCP-1
  const int h = blockIdx.y;
  __shared__ float ru[4], rv[4];
  float su = 0.f, sv = 0.f;
  if (c < kC) {
    const float* wr = Wk + (size_t)c * kQD + h * kC;
    const float* g = ln_g + h * kC;
    const float* b = ln_b + h * kC;
    for (int k = threadIdx.x; k < kC; k += 256) {
      const float w = wr[k];
      su = fmaf(w, g[k], su);
      sv = fmaf(w, b[k], sv);
    }
  }
#pragma unroll
  for (int off = 32; off; off >>= 1) {
    su += __shfl_down(su, off);
    sv += __shfl_down(sv, off);
  }
  if ((threadIdx.x & 63) == 0) {
    ru[threadIdx.x >> 6] = su;
    rv[threadIdx.x >> 6] = sv;
  }
  __syncthreads();
  if (threadIdx.x == 0) {
    u[h * kCP + c] = ru[0] + ru[1] + ru[2] + ru[3];
    v[h * kCP + c] = rv[0] + rv[1] + rv[2] + rv[3];
  }
}

// ---- build_a0: stats + qbk + head-0 split (y0 = qp*g) + (mu,rstd) ---------
__global__ void __launch_bounds__(256) build_a0_kernel(
    const float* __restrict__ q_xy, const float* __restrict__ q_xz,
    const float* __restrict__ q_yz, const float* __restrict__ tab,
    const float* __restrict__ ln_g, const float* __restrict__ ln_b,
    const float* __restrict__ bk, unsigned short* __restrict__ a0hi,
    unsigned short* __restrict__ a0lo, float* __restrict__ murs,
    float* __restrict__ qbk) {
  const int slot = blockIdx.y, plane = slot;
  const float* qp = (plane == 0) ? q_xy : (plane == 1) ? q_xz : q_yz;
  const int n = blockIdx.x, i = n >> 6, j = n & 63, tid = threadIdx.x;
  __shared__ float qf[kQD];
  __shared__ float red[16];

  const float* t0 = tab + ((size_t)(plane * 2 + 0) * 64 + j) * kC;
  const float* t1 = tab + ((size_t)(plane * 2 + 1) * 64 + i) * kC;
  for (int c = tid; c < kC; c += 256) {
    qf[c] = qp[(size_t)n * kC + c];
    qf[kC + c] = t0[c];
    qf[2 * kC + c] = t1[c];
  }
  __syncthreads();

  float sm = 0.f;
  for (int idx = tid; idx < kQD; idx += 256) sm += qf[idx];
#pragma unroll
  for (int off = 32; off; off >>= 1) sm += __shfl_down(sm, off);
  if ((tid & 63) == 0) red[tid >> 6] = sm;
  __syncthreads();
  const float mu = (red[0] + red[1] + red[2] + red[3]) * (1.f / kQD);
  __syncthreads();
  float sq = 0.f;
  for (int idx = tid; idx < kQD; idx += 256) {
    const float d = qf[idx] - mu;
    sq += d * d;
  }
#pragma unroll
  for (int off = 32; off; off >>= 1) sq += __shfl_down(sq, off);
  if ((tid & 63) == 0) red[tid >> 6] = sq;
  __syncthreads();
  const float var = (red[0] + red[1] + red[2] + red[3]) * (1.f / kQD);
  const float rstd = 1.f / sqrtf(var + 1e-5f);
  if (tid == 0) {
    murs[2 * ((size_t)slot * kNPIX + n)] = mu;
    murs[2 * ((size_t)slot * kNPIX + n) + 1] = rstd;
  }
  __syncthreads();

  float h0 = 0.f, h1 = 0.f, h2 = 0.f;
  unsigned short* ah = a0hi + (size_t)slot * kA0_ELEMS + (size_t)n * kKP;
  unsigned short* al = a0lo + (size_t)slot * kA0_ELEMS + (size_t)n * kKP;
  for (int idx = tid; idx < 3 * kKP; idx += 256) {
    int h, k;
    if (idx < kKP) { h = 0; k = idx; }
    else if (idx < 2 * kKP) { h = 1; k = idx - kKP; }
    else { h = 2; k = idx - 2 * kKP; }
    if (k < kC) {
      const int li = h * kC + k;
      const float v = (qf[li] - mu) * rstd * ln_g[li] + ln_b[li];
      const float pb = v * bk[li];
      if (h == 0) h0 += pb; else if (h == 1) h1 += pb; else h2 += pb;
    }
    if (idx < kKP) {  // head-0 split operand y0 = qf0 * g (NO mu/b)
      const float y = (idx < kC) ? qf[idx] * ln_g[idx] : 0.f;
      const unsigned short hv = f2bf(y);
      ah[idx] = hv;
      al[idx] = f2bf(y - bf2f(hv));
    }
  }
#pragma unroll
  for (int off = 32; off; off >>= 1) {
    h0 += __shfl_down(h0, off);
    h1 += __shfl_down(h1, off);
    h2 += __shfl_down(h2, off);
  }
  if ((tid & 63) == 0) {
    red[(tid >> 6) * 4 + 0] = h0;
    red[(tid >> 6) * 4 + 1] = h1;
    red[(tid >> 6) * 4 + 2] = h2;
  }
  __syncthreads();
  if (tid < 3)
    qbk[((size_t)slot * kNPIX + n) * 3 + tid] =
        red[tid] + red[4 + tid] + red[8 + tid] + red[12 + tid];
}

// ---- head-0 GEMM: A0(=y0 split) x Wk_0 split, 3-term; uv epilogue ---------
// Writes compact qk0 [slot][4096][kCP].
__global__ void __launch_bounds__(256) gemm_a0_kernel(
    const unsigned short* __restrict__ A0hi,
    const unsigned short* __restrict__ A0lo,
    const unsigned short* __restrict__ Bhi,
    const unsigned short* __restrict__ Blo, const float* __restrict__ murs,
    const float* __restrict__ uvec, const float* __restrict__ vvec,
    float* __restrict__ qk0) {
  __shared__ unsigned short smA[2][128 * 32];
  __shared__ unsigned short smB[2][128 * 32];
  const int slot = blockIdx.z;
  const int t = blockIdx.y * 7 + blockIdx.x;
  const int xcd = t & 7, idx = t >> 3;
  const int nb = idx % 7, mb = (xcd << 2) + idx / 7;
  const int m0 = mb * 128, n0 = nb * 128;
  const unsigned short* Ah = A0hi + (size_t)slot * kA0_ELEMS;
  const unsigned short* Al = A0lo + (size_t)slot * kA0_ELEMS;
  const int tid = threadIdx.x;
  const int lane = tid & 63, w = tid >> 6;
  const int wm = w >> 1, wn = w & 1;

  const int sr0 = w * 16 + (lane >> 2);
  const int ss = lane & 3;
  size_t aoff[2], boff[2];
  int ldsb[2];
#pragma unroll
  for (int p = 0; p < 2; ++p) {
    const int r = p * 64 + sr0;
    const int kl = (ss ^ ((r >> 1) & 3)) * 8;
    aoff[p] = (size_t)(m0 + r) * kKP + kl;
    boff[p] = (size_t)(n0 + r) * kKP + kl;
    ldsb[p] = (p * 64 + w * 16) * 32;
  }
  int offA[4], offB[4];
#pragma unroll
  for (int i = 0; i < 4; ++i) {
    const int ra = wm * 64 + i * 16 + (lane & 15);
    offA[i] = ra * 32 + (((lane >> 4) ^ ((ra >> 1) & 3)) << 3);
    const int rb = wn * 64 + i * 16 + (lane & 15);
    offB[i] = rb * 32 + (((lane >> 4) ^ ((rb >> 1) & 3)) << 3);
  }
  f32x4 acc[4][4];
#pragma unroll
  for (int i = 0; i < 4; ++i)
#pragma unroll
    for (int j = 0; j < 4; ++j) acc[i][j] = f32x4{0.f, 0.f, 0.f, 0.f};

  for (int k0 = 0; k0 < kKP; k0 += 32) {
#pragma unroll
    for (int p = 0; p < 2; ++p) {
      gload16(Ah + aoff[p] + k0, &smA[0][ldsb[p]]);
      gload16(Al + aoff[p] + k0, &smA[1][ldsb[p]]);
      gload16(Bhi + boff[p] + k0, &smB[0][ldsb[p]]);
      gload16(Blo + boff[p] + k0, &smB[1][ldsb[p]]);
    }
    __syncthreads();
    bf16x8 ah[4], al[4], bh[4], bl[4];
#pragma unroll
    for (int i = 0; i < 4; ++i) {
      ah[i] = *(const bf16x8*)&smA[0][offA[i]];
      al[i] = *(const bf16x8*)&smA[1][offA[i]];
      bh[i] = *(const bf16x8*)&smB[0][offB[i]];
      bl[i] = *(const bf16x8*)&smB[1][offB[i]];
    }
#pragma unroll
    for (int i = 0; i < 4; ++i)
#pragma unroll
      for (int j = 0; j < 4; ++j)
        acc[i][j] = __builtin_amdgcn_mfma_f32_16x16x32_bf16(ah[i], bh[j],
                                                            acc[i][j], 0, 0, 0);
#pragma unroll
    for (int i = 0; i < 4; ++i)
#pragma unroll
      for (int j = 0; j < 4; ++j)
        acc[i][j] = __builtin_amdgcn_mfma_f32_16x16x32_bf16(ah[i], bl[j],
                                                            acc[i][j], 0, 0, 0);
#pragma unroll
    for (int i = 0; i < 4; ++i)
#pragma unroll
      for (int j = 0; j < 4; ++j)
        acc[i][j] = __builtin_amdgcn_mfma_f32_16x16x32_bf16(al[i], bh[j],
                                                            acc[i][j], 0, 0, 0);
    __syncthreads();
  }

  const float* mr = murs + 2 * ((size_t)slot * kNPIX);
  float* dst = qk0 + (size_t)slot * kQ0_FLOATS;
  const int rbase = m0 + wm * 64;
  const int cbase = n0 + wn * 64;
#pragma unroll
  for (int i = 0; i < 4; ++i) {
#pragma unroll
    for (int j = 0; j < 4; ++j) {
      const int col = cbase + j * 16 + (lane & 15);
      if (col < kC) {
        const float uu = uvec[col], vv = vvec[col];
#pragma unroll
        for (int r = 0; r < 4; ++r) {
          const int row = rbase + i * 16 + (lane >> 4) * 4 + r;
          const float mu = mr[2 * row], rs = mr[2 * row + 1];
          dst[(size_t)row * kCP + col] = rs * acc[i][j][r] - rs * mu * uu + vv;
        }
      } else if (col < kCP) {
#pragma unroll
        for (int r = 0; r < 4; ++r) {
          const int row = rbase + i * 16 + (lane >> 4) * 4 + r;
          dst[(size_t)row * kCP + col] = 0.f;
        }
      }
    }
  }
}

// ---- table GEMM: Atab[t][128][kCP] = tabsplit[t] x Wk_{1+(t&1)} (3-term) --
__global__ void __launch_bounds__(256) gemm_tab_kernel(
    const unsigned short* __restrict__ Thi,
    const unsigned short* __restrict__ Tlo,
    const unsigned short* __restrict__ Wkhi,
    const unsigned short* __restrict__ Wklo, float* __restrict__ Atab) {
  __shared__ unsigned short smA[2][128 * 32];
  __shared__ unsigned short smB[2][128 * 32];
  const int t = blockIdx.y;
  const int n0 = blockIdx.x * 128;
  const int h = 1 + (t & 1);
  const unsigned short* Ah = Thi + (size_t)t * 128 * kKP;
  const unsigned short* Al = Tlo + (size_t)t * 128 * kKP;
  const unsigned short* Bh = Wkhi + (size_t)h * kBROWS * kKP;
  const unsigned short* Bl = Wklo + (size_t)h * kBROWS * kKP;
  const int tid = threadIdx.x;
  const int lane = tid & 63, w = tid >> 6;
  const int wm = w >> 1, wn = w & 1;

  const int sr0 = w * 16 + (lane >> 2);
  const int ss = lane & 3;
  size_t aoff[2], boff[2];
  int ldsb[2];
#pragma unroll
  for (int p = 0; p < 2; ++p) {
    const int r = p * 64 + sr0;
    const int kl = (ss ^ ((r >> 1) & 3)) * 8;
    aoff[p] = (size_t)r * kKP + kl;
    boff[p] = (size_t)(n0 + r) * kKP + kl;
    ldsb[p] = (p * 64 + w * 16) * 32;
  }
  int offA[4], offB[4];
#pragma unroll
  for (int i = 0; i < 4; ++i) {
    const int ra = wm * 64 + i * 16 + (lane & 15);
    offA[i] = ra * 32 + (((lane >> 4) ^ ((ra >> 1) & 3)) << 3);
    const int rb = wn * 64 + i * 16 + (lane & 15);
    offB[i] = rb * 32 + (((lane >> 4) ^ ((rb >> 1) & 3)) << 3);
  }
  f32x4 acc[4][4];
#pragma unroll
  for (int i = 0; i < 4; ++i)
#pragma unroll
    for (int j = 0; j < 4; ++j) acc[i][j] = f32x4{0.f, 0.f, 0.f, 0.f};

  for (int k0 = 0; k0 < kKP; k0 += 32) {
#pragma unroll
    for (int p = 0; p < 2; ++p) {
      gload16(Ah + aoff[p] + k0, &smA[0][ldsb[p]]);
      gload16(Al + aoff[p] + k0, &smA[1][ldsb[p]]);
      gload16(Bh + boff[p] + k0, &smB[0][ldsb[p]]);
      gload16(Bl + boff[p] + k0, &smB[1][ldsb[p]]);
    }
    __syncthreads();
    bf16x8 ah[4], al[4], bh[4], bl[4];
#pragma unroll
    for (int i = 0; i < 4; ++i) {
      ah[i] = *(const bf16x8*)&smA[0][offA[i]];
      al[i] = *(const bf16x8*)&smA[1][offA[i]];
      bh[i] = *(const bf16x8*)&smB[0][offB[i]];
      bl[i] = *(const bf16x8*)&smB[1][offB[i]];
    }
#pragma unroll
    for (int i = 0; i < 4; ++i)
#pragma unroll
      for (int j = 0; j < 4; ++j)
        acc[i][j] = __builtin_amdgcn_mfma_f32_16x16x32_bf16(ah[i], bh[j],
                                                            acc[i][j], 0, 0, 0);
#pragma unroll
    for (int i = 0; i < 4; ++i)
#pragma unroll
      for (int j = 0; j < 4; ++j)
        acc[i][j] = __builtin_amdgcn_mfma_f32_16x16x32_bf16(ah[i], bl[j],
                                                            acc[i][j], 0, 0, 0);
#pragma unroll
    for (int i = 0; i < 4; ++i)
#pragma unroll
      for (int j = 0; j < 4; ++j)
        acc[i][j] = __builtin_amdgcn_mfma_f32_16x16x32_bf16(al[i], bh[j],
                                                            acc[i][j], 0, 0, 0);
    __syncthreads();
  }

  float* C = Atab + (size_t)t * 128 * kCP;
  const int rbase = wm * 64;
  const int cbase = n0 + wn * 64;
#pragma unroll
  for (int i = 0; i < 4; ++i) {
#pragma unroll
    for (int j = 0; j < 4; ++j) {
      const int col = cbase + j * 16 + (lane & 15);
      if (col < kCP) {
        const float keep = (col < kC) ? 1.f : 0.f;
#pragma unroll
        for (int r = 0; r < 4; ++r) {
          const int row = rbase + i * 16 + (lane >> 4) * 4 + r;
          C[(size_t)row * kCP + col] = acc[i][j][r] * keep;
        }
      }
    }
  }
}

// ---- fused sample+attn: heads 1/2 scores via 7-dot factorization ----------
__global__ void __launch_bounds__(512, 6) sample_attn5_kernel(
    const float* __restrict__ imgt, const float* __restrict__ w2c,
    const float* __restrict__ Kin, const float* __restrict__ qk0,
    const float* __restrict__ atab, const float* __restrict__ uvec,
    const float* __restrict__ vvec, const float* __restrict__ murs,
    const float* __restrict__ qbk, unsigned short* __restrict__ whi) {
  __shared__ __align__(16) float ctx[kL][kCP];
  __shared__ float sW2[kL][4];
  __shared__ int sI2[kL][4];
  __shared__ float sscp[2][48];
  __shared__ float ssc[48], swt[48];
  const int slot = blockIdx.y, plane = slot;
  const int bid = blockIdx.x;
  const int n = ((bid & 7) << 9) | (bid >> 3);  // XCD swizzle (bijective)
  const int i = n >> 6, j = n & 63, tid = threadIdx.x;

  if (tid < kL) {
    const int s = tid >> 2, m = tid & 3;
    const float Xi = -1.f + 2.f * i / 63.f;
    const float Xj = -1.f + 2.f * j / 63.f;
    const float Ts = -1.f + 2.f * s / 3.f;
    float px, py, pz;
    if (plane == 0) { px = Xj; py = Xi; pz = Ts; }
    else if (plane == 1) { px = Xj; py = Ts; pz = Xi; }
    else { px = Ts; py = Xj; pz = Xi; }
    const float* W = w2c + m * 16;
    const float c0 = W[0] * px + W[1] * py + W[2] * pz + W[3];
    const float c1 = W[4] * px + W[5] * py + W[6] * pz + W[7];
    const float c2 = W[8] * px + W[9] * py + W[10] * pz + W[11];
    const float* Km = Kin + m * 9;
    const float un = Km[0] * c0 + Km[1] * c1 + Km[2] * c2;
    const float vn = Km[3] * c0 + Km[4] * c1 + Km[5] * c2;
    const float ds = c2 + 1e-8f;
    const float u = un / ds, v = vn / ds;
    const bool mk =
        (c2 > 0.f && u >= 0.f && u < 64.f && v >= 0.f && v < 64.f);
    float w00 = 0.f, w10 = 0.f, w01 = 0.f, w11 = 0.f;
    int i00 = 0, i10 = 0, i01 = 0, i11 = 0;
    if (mk) {
      const float gx = 2.f * (u / 63.f) - 1.f;
      const float gy = 2.f * (v / 63.f) - 1.f;
      const float ix = (gx + 1.f) * 0.5f * 63.f;
      const float iy = (gy + 1.f) * 0.5f * 63.f;
      const float x0 = floorf(ix), y0 = floorf(iy);
      const float x1 = x0 + 1.f, y1 = y0 + 1.f;
      const float wx = ix - x0, wy = iy - y0;
      const float v00 = (x0 >= 0.f && x0 <= 63.f && y0 >= 0.f && y0 <= 63.f) ? 1.f : 0.f;
      const float v10 = (x1 >= 0.f && x1 <= 63.f && y0 >= 0.f && y0 <= 63.f) ? 1.f : 0.f;
      const float v01 = (x0 >= 0.f && x0 <= 63.f && y1 >= 0.f && y1 <= 63.f) ? 1.f : 0.f;
      const float v11 = (x1 >= 0.f && x1 <= 63.f && y1 >= 0.f && y1 <= 63.f) ? 1.f : 0.f;
      w00 = (1.f - wx) * (1.f - wy) * v00;
      w10 = wx * (1.f - wy) * v10;
      w01 = (1.f - wx) * wy * v01;
      w11 = wx * wy * v11;
      const int x0i = (int)fminf(fmaxf(x0, 0.f), 63.f);
      const int x1i = (int)fminf(fmaxf(x1, 0.f), 63.f);
      const int y0i = (int)fminf(fmaxf(y0, 0.f), 63.f);
      const int y1i = (int)fminf(fmaxf(y1, 0.f), 63.f);
      const int mb = m * kIMS2;
      i00 = mb + (y0i * 64 + x0i) * kCP;
      i10 = mb + (y0i * 64 + x1i) * kCP;
      i01 = mb + (y1i * 64 + x0i) * kCP;
      i11 = mb + (y1i * 64 + x1i) * kCP;
    }
    sI2[tid][0] = i00; sI2[tid][1] = i10; sI2[tid][2] = i01; sI2[tid][3] = i11;
    sW2[tid][0] = w00; sW2[tid][1] = w10; sW2[tid][2] = w01; sW2[tid][3] = w11;
  }
  __syncthreads();

  // staging: 8 waves, wave wv handles l = wv*2 + {0,1}
  const int lane = tid & 63, wv = tid >> 6;
#pragma unroll
  for (int q = 0; q < 2; ++q) {
    const int l = (wv << 1) + q;
    const float a0 = sW2[l][0], a1 = sW2[l][1], a2 = sW2[l][2], a3 = sW2[l][3];
    const int b0 = sI2[l][0], b1 = sI2[l][1], b2 = sI2[l][2], b3 = sI2[l][3];
    for (int g = lane; g < kNG; g += 64) {
      const int c4 = g << 2;
      const float4 t0 = *(const float4*)&imgt[b0 + c4];
      const float4 t1 = *(const float4*)&imgt[b1 + c4];
      const float4 t2 = *(const float4*)&imgt[b2 + c4];
      const float4 t3 = *(const float4*)&imgt[b3 + c4];
      float4 r;
      r.x = fmaf(t0.x, a0, fmaf(t1.x, a1, fmaf(t2.x, a2, t3.x * a3)));
      r.y = fmaf(t0.y, a0, fmaf(t1.y, a1, fmaf(t2.y, a2, t3.y * a3)));
      r.z = fmaf(t0.z, a0, fmaf(t1.z, a1, fmaf(t2.z, a2, t3.z * a3)));
      r.w = fmaf(t0.w, a0, fmaf(t1.w, a1, fmaf(t2.w, a2, t3.w * a3)));
      *(float4*)&ctx[l][c4] = r;
    }
  }
  __syncthreads();

  // scores: head0 dot vs qk0; heads 1/2 via rs*(ctx.a) - rs*mu*(ctx.u) + ctx.v
  const int g16 = tid >> 4, l16 = tid & 15;
  const float* qbkn = qbk + ((size_t)slot * kNPIX + n) * 3;
  const float* qk0n = qk0 + (size_t)slot * kQ0_FLOATS + (size_t)n * kCP;
  const float* A1r = atab + ((size_t)(slot * 2 + 0) * 128 + j) * kCP;
  const float* A2r = atab + ((size_t)(slot * 2 + 1) * 128 + i) * kCP;
  const float* u1 = uvec + kCP;
  const float* u2 = uvec + 2 * kCP;
  const float* v1 = vvec + kCP;
  const float* v2 = vvec + 2 * kCP;
  const float mun = murs[2 * ((size_t)slot * kNPIX + n)];
  const float rsn = murs[2 * ((size_t)slot * kNPIX + n) + 1];
  const float rsmu = rsn * mun;
  {
    const int l = g16 & 15, half = g16 >> 4;
    float p0 = 0.f, pa1 = 0.f, pu1 = 0.f, pv1 = 0.f;
    float pa2 = 0.f, pu2 = 0.f, pv2 = 0.f;
    auto dot7 = [&](int c4) {
      const float4 cv = *(const float4*)&ctx[l][c4];
      const float4 q0 = *(const float4*)&qk0n[c4];
      const float4 xa1 = *(const float4*)&A1r[c4];
      const float4 xu1 = *(const float4*)&u1[c4];
      const float4 xv1 = *(const float4*)&v1[c4];
      const float4 xa2 = *(const float4*)&A2r[c4];
      const float4 xu2 = *(const float4*)&u2[c4];
      const float4 xv2 = *(const float4*)&v2[c4];
      p0 = fmaf(cv.x, q0.x, fmaf(cv.y, q0.y, fmaf(cv.z, q0.z, fmaf(cv.w, q0.w, p0))));
      pa1 = fmaf(cv.x, xa1.x, fmaf(cv.y, xa1.y, fmaf(cv.z, xa1.z, fmaf(cv.w, xa1.w, pa1))));
      pu1 = fmaf(cv.x, xu1.x, fmaf(cv.y, xu1.y, fmaf(cv.z, xu1.z, fmaf(cv.w, xu1.w, pu1))));
      pv1 = fmaf(cv.x, xv1.x, fmaf(cv.y, xv1.y, fmaf(cv.z, xv1.z, fmaf(cv.w, xv1.w, pv1))));
      pa2 = fmaf(cv.x, xa2.x, fmaf(cv.y, xa2.y, fmaf(cv.z, xa2.z, fmaf(cv.w, xa2.w, pa2))));
      pu2 = fmaf(cv.x, xu2.x, fmaf(cv.y, xu2.y, fmaf(cv.z, xu2.z, fmaf(cv.w, xu2.w, pu2))));
      pv2 = fmaf(cv.x, xv2.x, fmaf(cv.y, xv2.y, fmaf(cv.z, xv2.z, fmaf(cv.w, xv2.w, pv2))));
    };
#pragma unroll
    for (int it = 0; it < 6; ++it) dot7((l16 + ((2 * it + half) << 4)) << 2);
    if (half == 0 && l16 < 2) dot7((192 + l16) << 2);
#pragma unroll
    for (int off = 8; off; off >>= 1) {
      p0 += __shfl_down(p0, off, 16);
      pa1 += __shfl_down(pa1, off, 16);
      pu1 += __shfl_down(pu1, off, 16);
      pv1 += __shfl_down(pv1, off, 16);
      pa2 += __shfl_down(pa2, off, 16);
      pu2 += __shfl_down(pu2, off, 16);
      pv2 += __shfl_down(pv2, off, 16);
    }
    if (l16 == 0) {
      sscp[half][l] = p0;
      sscp[half][16 + l] = rsn * pa1 - rsmu * pu1 + pv1;
      sscp[half][32 + l] = rsn * pa2 - rsmu * pu2 + pv2;
    }
  }
  __syncthreads();
  if (tid < 48) ssc[tid] = sscp[0][tid] + sscp[1][tid] + qbkn[tid >> 4];
  __syncthreads();
  if (tid < 3) {
    float mx = ssc[tid * 16];
#pragma unroll
    for (int l = 1; l < kL; ++l) mx = fmaxf(mx, ssc[tid * 16 + l]);
    float e[kL];
    float sum = 0.f;
#pragma unroll
    for (int l = 0; l < kL; ++l) {
      e[l] = expf(ssc[tid * 16 + l] - mx);
      sum += e[l];
    }
    const float inv = 1.f / sum;
#pragma unroll
    for (int l = 0; l < kL; ++l) swt[tid * 16 + l] = e[l] * inv;
  }
  __syncthreads();

  // PV: thread pair (2k,2k+1) shares c4-group k, splits l-halves; whi only
  unsigned short* wh = whi + (size_t)slot * kWH_ELEMS + (size_t)n * kLDA;
  if (tid < 2 * kNG) {
    const int c4 = (tid >> 1) << 2;
    const int l0 = (tid & 1) << 3;
    float4 o0{0.f, 0.f, 0.f, 0.f}, o1{0.f, 0.f, 0.f, 0.f},
        o2{0.f, 0.f, 0.f, 0.f};
#pragma unroll
    for (int dl = 0; dl < 8; ++dl) {
      const int l = l0 + dl;
      const float4 cv = *(const float4*)&ctx[l][c4];
      const float s0 = swt[l], s1 = swt[16 + l], s2 = swt[32 + l];
      o0.x = fmaf(cv.x, s0, o0.x); o0.y = fmaf(cv.y, s0, o0.y);
      o0.z = fmaf(cv.z, s0, o0.z); o0.w = fmaf(cv.w, s0, o0.w);
      o1.x = fmaf(cv.x, s1, o1.x); o1.y = fmaf(cv.y, s1, o1.y);
      o1.z = fmaf(cv.z, s1, o1.z); o1.w = fmaf(cv.w, s1, o1.w);
      o2.x = fmaf(cv.x, s2, o2.x); o2.y = fmaf(cv.y, s2, o2.y);
      o2.z = fmaf(cv.z, s2, o2.z); o2.w = fmaf(cv.w, s2, o2.w);
    }
    o0.x += __shfl_xor(o0.x, 1); o0.y += __shfl_xor(o0.y, 1);
    o0.z += __shfl_xor(o0.z, 1); o0.w += __shfl_xor(o0.w, 1);
    o1.x += __shfl_xor(o1.x, 1); o1.y += __shfl_xor(o1.y, 1);
    o1.z += __shfl_xor(o1.z, 1); o1.w += __shfl_xor(o1.w, 1);
    o2.x += __shfl_xor(o2.x, 1); o2.y += __shfl_xor(o2.y, 1);
    o2.z += __shfl_xor(o2.z, 1); o2.w += __shfl_xor(o2.w, 1);
    if ((tid & 1) == 0) {
      float4 ov[3] = {o0, o1, o2};
#pragma unroll
      for (int h = 0; h < 3; ++h) {
        ushort4 hi;
        hi.x = f2bf(ov[h].x);
        hi.y = f2bf(ov[h].y);
        hi.z = f2bf(ov[h].z);
        hi.w = f2bf(ov[h].w);
        *(ushort4*)&wh[h * kKP + c4] = hi;
      }
    }
  }
  if (tid < 72) {
    const int h = tid / 24, k2 = kCP + tid % 24;
    wh[h * kKP + k2] = 0;
  }
}

// ---- out-GEMM: whi x Wv split (2-term), XCD panel swizzle -----------------
__global__ void __launch_bounds__(256) gemm_out_kernel(
    const unsigned short* __restrict__ Ahi,
    const unsigned short* __restrict__ Bhi,
    const unsigned short* __restrict__ Blo, float* __restrict__ C,
    const float* __restrict__ bias) {
  __shared__ unsigned short smA[128 * 32];
  __shared__ unsigned short smB[2][128 * 32];
  const int slot = blockIdx.z / 3, h = blockIdx.z % 3;
  const int t = blockIdx.y * 7 + blockIdx.x;
  const int xcd = t & 7, idx = t >> 3;
  const int nb = idx % 7, mb = (xcd << 2) + idx / 7;
  const int m0 = mb * 128, n0 = nb * 128;
  const unsigned short* Ah = Ahi + (size_t)slot * kWH_ELEMS;
  float* Cs = C + (size_t)slot * kQN_FLOATS;
  const int tid = threadIdx.x;
  const int lane = tid & 63, w = tid >> 6;
  const int wm = w >> 1, wn = w & 1;

  const int sr0 = w * 16 + (lane >> 2);
  const int ss = lane & 3;
  size_t aoff[2], boff[2];
  int ldsb[2];
#pragma unroll
  for (int p = 0; p < 2; ++p) {
    const int r = p * 64 + sr0;
    const int kl = (ss ^ ((r >> 1) & 3)) * 8;
    aoff[p] = (size_t)(m0 + r) * kLDA + (size_t)h * kKP + kl;
    boff[p] = ((size_t)h * kBROWS + (n0 + r)) * kKP + kl;
    ldsb[p] = (p * 64 + w * 16) * 32;
  }
  int offA[4], offB[4];
#pragma unroll
  for (int i = 0; i < 4; ++i) {
    const int ra = wm * 64 + i * 16 + (lane & 15);
    offA[i] = ra * 32 + (((lane >> 4) ^ ((ra >> 1) & 3)) << 3);
    const int rb = wn * 64 + i * 16 + (lane & 15);
    offB[i] = rb * 32 + (((lane >> 4) ^ ((rb >> 1) & 3)) << 3);
  }
  f32x4 acc[4][4];
#pragma unroll
  for (int i = 0; i < 4; ++i)
#pragma unroll
    for (int j = 0; j < 4; ++j) acc[i][j] = f32x4{0.f, 0.f, 0.f, 0.f};

  for (int k0 = 0; k0 < kKP; k0 += 32) {
#pragma unroll
    for (int p = 0; p < 2; ++p) {
      gload16(Ah + aoff[p] + k0, &smA[ldsb[p]]);
      gload16(Bhi + boff[p] + k0, &smB[0][ldsb[p]]);
      gload16(Blo + boff[p] + k0, &smB[1][ldsb[p]]);
    }
    __syncthreads();
    bf16x8 ah[4], bh[4], bl[4];
#pragma unroll
    for (int i = 0; i < 4; ++i) {
      ah[i] = *(const bf16x8*)&smA[offA[i]];
      bh[i] = *(const bf16x8*)&smB[0][offB[i]];
      bl[i] = *(const bf16x8*)&smB[1][offB[i]];
    }
#pragma unroll
    for (int i = 0; i < 4; ++i)
#pragma unroll
      for (int j = 0; j < 4; ++j)
        acc[i][j] = __builtin_amdgcn_mfma_f32_16x16x32_bf16(ah[i], bh[j],
                                                            acc[i][j], 0, 0, 0);
#pragma unroll
    for (int i = 0; i < 4; ++i)
#pragma unroll
      for (int j = 0; j < 4; ++j)
        acc[i][j] = __builtin_amdgcn_mfma_f32_16x16x32_bf16(ah[i], bl[j],
                                                            acc[i][j], 0, 0, 0);
    __syncthreads();
  }

  const int rbase = m0 + wm * 64;
  const int cbase = n0 + wn * 64;
#pragma unroll
  for (int i = 0; i < 4; ++i) {
#pragma unroll
    for (int j = 0; j < 4; ++j) {
      const int col = cbase + j * 16 + (lane & 15);
      if (col < kC) {
        const float bb = bias[h * kC + col];
#pragma unroll
        for (int r = 0; r < 4; ++r) {
          const int row = rbase + i * 16 + (lane >> 4) * 4 + r;
          Cs[(size_t)row * kQD + h * kC + col] = acc[i][j][r] + bb;
        }
      }
    }
  }
}

// ======================= tier-D f32 fallback path ==========================
__global__ void __launch_bounds__(256) build_q_f32(
    const float* __restrict__ q_xy, const float* __restrict__ q_xz,
    const float* __restrict__ q_yz, const int plane,
    const float* __restrict__ ln_g, const float* __restrict__ ln_b,
    const float* __restrict__ bk, float* __restrict__ qn,
    float* __restrict__ qbk) {
  const float* qp = (plane == 0) ? q_xy : (plane == 1) ? q_xz : q_yz;
  const float* qo0 = (plane == 0) ? q_xz : q_xy;
  const float* qo1 = (plane == 2) ? q_xz : q_yz;
  const int n = blockIdx.x, i = n >> 6, j = n & 63, tid = threadIdx.x;
  __shared__ float qf[kQD];
  __shared__ int sIdx[2][4][4];
  __shared__ float sW[2][4][4];
  __shared__ float red[16];

  if (tid < 8) {
    const int part = tid >> 2, s = tid & 3;
    const float Xi = -1.f + 2.f * i / 63.f;
    const float Xj = -1.f + 2.f * j / 63.f;
    const float Ts = -1.f + 2.f * s / 3.f;
    float a, b;
    if (plane == 0) { a = part ? Xi : Xj; b = Ts; }
    else if (plane == 1) {
      if (part == 0) { a = Xj; b = Ts; } else { a = Ts; b = Xi; }
    } else { a = Ts; b = part ? Xi : Xj; }
    const float ga = fminf(fmaxf((a * 0.5f + 0.5f) * 63.f, 0.f), 63.f);
    const float gb = fminf(fmaxf((b * 0.5f + 0.5f) * 63.f, 0.f), 63.f);
    const float ix = fminf(fmaxf((ga + 1.f) * 0.5f * 63.f, 0.f), 63.f);
    const float iy = fminf(fmaxf((gb + 1.f) * 0.5f * 63.f, 0.f), 63.f);
    const float x0 = floorf(ix), y0 = floorf(iy);
    const float wx = ix - x0, wy = iy - y0;
    const int x0i = (int)x0, y0i = (int)y0;
    const int x1i = (x0i + 1 > 63) ? 63 : x0i + 1;
    const int y1i = (y0i + 1 > 63) ? 63 : y0i + 1;
    sIdx[part][s][0] = (y0i * 64 + x0i) * kC;
    sIdx[part][s][1] = (y0i * 64 + x1i) * kC;
    sIdx[part][s][2] = (y1i * 64 + x0i) * kC;
    sIdx[part][s][3] = (y1i * 64 + x1i) * kC;
    sW[part][s][0] = (1.f - wx) * (1.f - wy);
    sW[part][s][1] = wx * (1.f - wy);
    sW[part][s][2] = (1.f - wx) * wy;
    sW[part][s][3] = wx * wy;
  }
  __syncthreads();
  for (int c = tid; c < kC; c += 256) {
    qf[c] = qp[(size_t)n * kC + c];
    float a1 = 0.f, a2 = 0.f;
#pragma unroll
    for (int s = 0; s < 4; ++s) {
      a1 += qo0[sIdx[0][s][0] + c] * sW[0][s][0]
          + qo0[sIdx[0][s][1] + c] * sW[0][s][1]
          + qo0[sIdx[0][s][2] + c] * sW[0][s][2]
          + qo0[sIdx[0][s][3] + c] * sW[0][s][3];
      a2 += qo1[sIdx[1][s][0] + c] * sW[1][s][0]
          + qo1[sIdx[1][s][1] + c] * sW[1][s][1]
          + qo1[sIdx[1][s][2] + c] * sW[1][s][2]
          + qo1[sIdx[1][s][3] + c] * sW[1][s][3];
    }
    qf[kC + c] = a1 * 0.25f;
    qf[2 * kC + c] = a2 * 0.25f;
  }
  __syncthreads();
  float sm = 0.f;
  for (int idx = tid; idx < kQD; idx += 256) sm += qf[idx];
#pragma unroll
  for (int off = 32; off; off >>= 1) sm += __shfl_down(sm, off);
  if ((tid & 63) == 0) red[tid >> 6] = sm;
  __syncthreads();
  const float mu = (red[0] + red[1] + red[2] + red[3]) * (1.f / kQD);
  __syncthreads();
  float sq = 0.f;
  for (int idx = tid; idx < kQD; idx += 256) {
    const float d = qf[idx] - mu;
    sq += d * d;
  }
#pragma unroll
  for (int off = 32; off; off >>= 1) sq += __shfl_down(sq, off);
  if ((tid & 63) == 0) red[tid >> 6] = sq;
  __syncthreads();
  const float var = (red[0] + red[1] + red[2] + red[3]) * (1.f / kQD);
  const float rstd = 1.f / sqrtf(var + 1e-5f);
  __syncthreads();
  float h0 = 0.f, h1 = 0.f, h2 = 0.f;
  for (int idx = tid; idx < kQD; idx += 256) {
    const float v = (qf[idx] - mu) * rstd * ln_g[idx] + ln_b[idx];
    qn[(size_t)n * kQD + idx] = v;
    const float pb = v * bk[idx];
    if (idx < kC) h0 += pb;
    else if (idx < 2 * kC) h1 += pb;
    else h2 += pb;
  }
#pragma unroll
  for (int off = 32; off; off >>= 1) {
    h0 += __shfl_down(h0, off);
    h1 += __shfl_down(h1, off);
    h2 += __shfl_down(h2, off);
  }
  if ((tid & 63) == 0) {
    red[(tid >> 6) * 4 + 0] = h0;
    red[(tid >> 6) * 4 + 1] = h1;
    red[(tid >> 6) * 4 + 2] = h2;
  }
  __syncthreads();
  if (tid < 3)
    qbk[n * 3 + tid] = red[tid] + red[4 + tid] + red[8 + tid] + red[12 + tid];
}

__global__ void __launch_bounds__(256) sample_attn_f32(
    const float* __restrict__ src, const float* __restrict__ w2c,
    const float* __restrict__ Kin, const float* __restrict__ qk,
    const float* __restrict__ qbk, const int plane, float* __restrict__ wctx) {
  __shared__ float ctx[kL * kC];
  __shared__ float su[kL], sv[kL], smk[kL];
  __shared__ float spart[4][48];
  __shared__ float ssc[48];
  __shared__ float swt[48];
  const int n = blockIdx.x, i = n >> 6, j = n & 63, tid = threadIdx.x;

  if (tid < kL) {
    const int s = tid >> 2, m = tid & 3;
    const float Xi = -1.f + 2.f * i / 63.f;
    const float Xj = -1.f + 2.f * j / 63.f;
    const float Ts = -1.f + 2.f * s / 3.f;
    float px, py, pz;
    if (plane == 0) { px = Xj; py = Xi; pz = Ts; }
    else if (plane == 1) { px = Xj; py = Ts; pz = Xi; }
    else { px = Ts; py = Xj; pz = Xi; }
    const float* W = w2c + m * 16;
    const float c0 = W[0] * px + W[1] * py + W[2] * pz + W[3];
    const float c1 = W[4] * px + W[5] * py + W[6] * pz + W[7];
    const float c2 = W[8] * px + W[9] * py + W[10] * pz + W[11];
    const float* Km = Kin + m * 9;
    const float un = Km[0] * c0 + Km[1] * c1 + Km[2] * c2;
    const float vn = Km[3] * c0 + Km[4] * c1 + Km[5] * c2;
    const float ds = c2 + 1e-8f;
    const float u = un / ds, v = vn / ds;
    const float mk =
        (c2 > 0.f && u >= 0.f && u < 64.f && v >= 0.f && v < 64.f) ? 1.f : 0.f;
    su[tid] = u; sv[tid] = v; smk[tid] = mk;
  }
  __syncthreads();

  for (int l = 0; l < kL; ++l) {
    const int m = l & 3;
    const float u = su[l], v = sv[l], mk = smk[l];
    float w00 = 0.f, w10 = 0.f, w01 = 0.f, w11 = 0.f;
    int i00 = 0, i10 = 0, i01 = 0, i11 = 0;
    if (mk != 0.f) {
      const float gx = 2.f * (u / 63.f) - 1.f;
      const float gy = 2.f * (v / 63.f) - 1.f;
      const float ix = (gx + 1.f) * 0.5f * 63.f;
      const float iy = (gy + 1.f) * 0.5f * 63.f;
      const float x0 = floorf(ix), y0 = floorf(iy);
      const float x1 = x0 + 1.f, y1 = y0 + 1.f;
      const float wx = ix - x0, wy = iy - y0;
      const float v00 = (x0 >= 0.f && x0 <= 63.f && y0 >= 0.f && y0 <= 63.f) ? 1.f : 0.f;
      const float v10 = (x1 >= 0.f && x1 <= 63.f && y0 >= 0.f && y0 <= 63.f) ? 1.f : 0.f;
      const float v01 = (x0 >= 0.f && x0 <= 63.f && y1 >= 0.f && y1 <= 63.f) ? 1.f : 0.f;
      const float v11 = (x1 >= 0.f && x1 <= 63.f && y1 >= 0.f && y1 <= 63.f) ? 1.f : 0.f;
      w00 = (1.f - wx) * (1.f - wy) * v00;
      w10 = wx * (1.f - wy) * v10;
      w01 = (1.f - wx) * wy * v01;
      w11 = wx * wy * v11;
      const int x0i = (int)fminf(fmaxf(x0, 0.f), 63.f);
      const int x1i = (int)fminf(fmaxf(x1, 0.f), 63.f);
      const int y0i = (int)fminf(fmaxf(y0, 0.f), 63.f);
      const int y1i = (int)fminf(fmaxf(y1, 0.f), 63.f);
      const int mb = m * kImgMStride;
      i00 = mb + (y0i * 64 + x0i);
      i10 = mb + (y0i * 64 + x1i);
      i01 = mb + (y1i * 64 + x0i);
      i11 = mb + (y1i * 64 + x1i);
    }
    for (int c = tid; c < kC; c += 256) {
      const int cs = c * (kG * kG);
      ctx[l * kC + c] = src[i00 + cs] * w00 + src[i10 + cs] * w10 +
                        src[i01 + cs] * w01 + src[i11 + cs] * w11;
    }
  }
  __syncthreads();

  float acc[48];
#pragma unroll
  for (int t = 0; t < 48; ++t) acc[t] = 0.f;
  const float* qkn = qk + (size_t)n * kQD;
  for (int c = tid; c < kC; c += 256) {
    const float q0 = qkn[c], q1 = qkn[kC + c], q2 = qkn[2 * kC + c];
#pragma unroll
    for (int l = 0; l < kL; ++l) {
      const float cv = ctx[l * kC + c];
      acc[l] = fmaf(cv, q0, acc[l]);
      acc[16 + l] = fmaf(cv, q1, acc[16 + l]);
      acc[32 + l] = fmaf(cv, q2, acc[32 + l]);
    }
  }
#pragma unroll
  for (int t = 0; t < 48; ++t) {
    float x = acc[t];
#pragma unroll
    for (int off = 32; off; off >>= 1) x += __shfl_down(x, off);
    acc[t] = x;
  }
  if ((tid & 63) == 0) {
#pragma unroll
    for (int t = 0; t < 48; ++t) spart[tid >> 6][t] = acc[t];
  }
  __syncthreads();
  if (tid < 48)
    ssc[tid] = spart[0][tid] + spart[1][tid] + spart[2][tid] + spart[3][tid] +
               qbk[n * 3 + (tid >> 4)];
  __syncthreads();
  if (tid < 3) {
    float mx = ssc[tid * 16];
#pragma unroll
    for (int l = 1; l < kL; ++l) mx = fmaxf(mx, ssc[tid * 16 + l]);
    float e[kL];
    float sum = 0.f;
#pragma unroll
    for (int l = 0; l < kL; ++l) {
      e[l] = expf(ssc[tid * 16 + l] - mx);
      sum += e[l];
    }
    const float inv = 1.f / sum;
#pragma unroll
    for (int l = 0; l < kL; ++l) swt[tid * 16 + l] = e[l] * inv;
  }
  __syncthreads();
  for (int c = tid; c < kC; c += 256) {
    float o0 = 0.f, o1 = 0.f, o2 = 0.f;
#pragma unroll
    for (int l = 0; l < kL; ++l) {
      const float cv = ctx[l * kC + c];
      o0 = fmaf(swt[l], cv, o0);
      o1 = fmaf(swt[16 + l], cv, o1);
      o2 = fmaf(swt[32 + l], cv, o2);
    }
    float* wn = wctx + (size_t)n * kQD;
    wn[c] = o0;
    wn[kC + c] = o1;
    wn[2 * kC + c] = o2;
  }
}

template <bool BT, bool BIAS>
__global__ void __launch_bounds__(256) gemm_f32(
    const float* __restrict__ A, const float* __restrict__ B,
    float* __restrict__ Cp, const float* __restrict__ bias, const int M,
    const int N, const int K, const int lda, const int ldb, const int ldc,
    const int hstride) {
  constexpr int BM = 128, BN = 64, BK = 16;
  __shared__ float As[BK][BM + 4];
  __shared__ float Bs[BK][BN + 4];
  const int hoff = blockIdx.z * hstride;
  const int m0 = blockIdx.y * BM, n0 = blockIdx.x * BN;
  const int tid = threadIdx.x;
  const int ty = tid >> 4, tx = tid & 15;
  float acc[8][4];
#pragma unroll
  for (int r = 0; r < 8; ++r)
#pragma unroll
    for (int c = 0; c < 4; ++c) acc[r][c] = 0.f;
  for (int k0 = 0; k0 < K; k0 += BK) {
#pragma unroll
    for (int p = 0; p < 8; ++p) {
      const int idx = tid + p * 256;
      const int mm = idx >> 4, kk = idx & 15;
      float v = 0.f;
      if (k0 + kk < K) v = A[(size_t)(m0 + mm) * lda + hoff + k0 + kk];
      As[kk][mm] = v;
    }
    if (BT) {
#pragma unroll
      for (int p = 0; p < 4; ++p) {
        const int idx = tid + p * 256;
        const int jj = idx >> 4, kk = idx & 15;
        float v = 0.f;
        if ((n0 + jj) < N && (k0 + kk) < K)
          v = B[(size_t)(n0 + jj) * ldb + hoff + k0 + kk];
        Bs[kk][jj] = v;
      }
    } else {
#pragma unroll
      for (int p = 0; p < 4; ++p) {
        const int idx = tid + p * 256;
        const int kk = idx >> 6, jj = idx & 63;
        float v = 0.f;
        if ((n0 + jj) < N && (k0 + kk) < K)
          v = B[(size_t)(k0 + kk) * ldb + hoff + n0 + jj];
        Bs[kk][jj] = v;
      }
    }
    __syncthreads();
#pragma unroll
    for (int kk = 0; kk < BK; ++kk) {
      float a[8], b[4];
#pragma unroll
      for (int r = 0; r < 8; ++r) a[r] = As[kk][ty * 8 + r];
#pragma unroll
      for (int c = 0; c < 4; ++c) b[c] = Bs[kk][tx * 4 + c];
#pragma unroll
      for (int r = 0; r < 8; ++r)
#pragma unroll
        for (int c = 0; c < 4; ++c) acc[r][c] = fmaf(a[r], b[c], acc[r][c]);
    }
    __syncthreads();
  }
#pragma unroll
  for (int r = 0; r < 8; ++r) {
    const int mm = m0 + ty * 8 + r;
    if (mm >= M) continue;
#pragma unroll
    for (int c = 0; c < 4; ++c) {
      const int jj = n0 + tx * 4 + c;
      if (jj < N) {
        float v = acc[r][c];
        if (BIAS) v += bias[hoff + jj];
        Cp[(size_t)mm * ldc + hoff + jj] = v;
      }
    }
  }
}

// ---------------------------------------------------------------------------
extern "C" void kernel_launch(void* const* d_in, const int* in_sizes, int n_in,
                              void* d_out, int out_size, void* d_ws,
                              size_t ws_size, hipStream_t stream) {
  const float* imgf = (const float*)d_in[0];
  const float* c2w = (const float*)d_in[2];
  const float* Kin = (const float*)d_in[3];
  const float* qpl[3] = {(const float*)d_in[5], (const float*)d_in[6],
                         (const float*)d_in[7]};
  const float* Wk = (const float*)d_in[8];
  const float* bk = (const float*)d_in[9];
  const float* Wv = (const float*)d_in[10];
  const float* bv = (const float*)d_in[11];
  const float* ln_g = (const float*)d_in[12];
  const float* ln_b = (const float*)d_in[13];
  float* out = (float*)d_out;
  char* wsb = (char*)d_ws;

  const size_t IMGT_FLOATS = (size_t)kNV * kIMS2;

  size_t off = 0;
  auto take = [&](size_t bytes) {
    size_t p = off;
    off = (off + bytes + 511) & ~(size_t)511;
    return p;
  };
  const size_t o_w2c = take(64 * 4);
  const size_t o_qbk = take((size_t)3 * kNPIX * 3 * 4);
  const size_t o_qk0 = take((size_t)3 * kQ0_FLOATS * 4);
  const size_t o_wkhi = take(kW_ELEMS * 2);
  const size_t o_wklo = take(kW_ELEMS * 2);
  const size_t o_wvthi = take(kW_ELEMS * 2);
  const size_t o_wvtlo = take(kW_ELEMS * 2);
  const size_t o_a0hi = take((size_t)3 * kA0_ELEMS * 2);
  const size_t o_a0lo = take((size_t)3 * kA0_ELEMS * 2);
  const size_t o_whi = take((size_t)3 * kWH_ELEMS * 2);
  const size_t o_murs = take((size_t)3 * kNPIX * 2 * 4);
  const size_t o_u = take((size_t)3 * kCP * 4);
  const size_t o_v = take((size_t)3 * kCP * 4);
  const size_t o_tab = take(kTAB_FLOATS * 4);
  const size_t o_tshi = take((size_t)6 * 128 * kKP * 2);
  const size_t o_tslo = take((size_t)6 * 128 * kKP * 2);
  const size_t o_atab = take((size_t)6 * 128 * kCP * 4);
  const size_t o_imgt = take(IMGT_FLOATS * 4);
  const size_t need = off;

  if (ws_size >= need) {
    float* w2c = (float*)(wsb + o_w2c);
    float* qbk = (float*)(wsb + o_qbk);
    float* qk0 = (float*)(wsb + o_qk0);
    unsigned short* wkhi = (unsigned short*)(wsb + o_wkhi);
    unsigned short* wklo = (unsigned short*)(wsb + o_wklo);
    unsigned short* wvthi = (unsigned short*)(wsb + o_wvthi);
    unsigned short* wvtlo = (unsigned short*)(wsb + o_wvtlo);
    unsigned short* a0hi = (unsigned short*)(wsb + o_a0hi);
    unsigned short* a0lo = (unsigned short*)(wsb + o_a0lo);
    unsigned short* whi = (unsigned short*)(wsb + o_whi);
    float* murs = (float*)(wsb + o_murs);
    float* uvec = (float*)(wsb + o_u);
    float* vvec = (float*)(wsb + o_v);
    float* meantab = (float*)(wsb + o_tab);
    unsigned short* tshi = (unsigned short*)(wsb + o_tshi);
    unsigned short* tslo = (unsigned short*)(wsb + o_tslo);
    float* atab = (float*)(wsb + o_atab);
    float* imgt = (float*)(wsb + o_imgt);

    invert4_kernel<<<1, 64, 0, stream>>>(c2w, w2c);
    prep_wk_kernel<<<dim3(kBROWS, 3), 256, 0, stream>>>(Wk, wkhi, wklo);
    prep_wvt_kernel<<<dim3(13, 14, 3), 256, 0, stream>>>(Wv, wvthi, wvtlo);
    prep_meantab_kernel<<<dim3(64, 6), 256, 0, stream>>>(qpl[0], qpl[1],
                                                         qpl[2], meantab);
    prep_tabsplit_kernel<<<dim3(128, 6), 256, 0, stream>>>(meantab, ln_g,
                                                           tshi, tslo);
    prep_uv_kernel<<<dim3(kCP, 3), 256, 0, stream>>>(Wk, ln_g, ln_b, uvec,
                                                     vvec);
    transpose_img_kernel<<<dim3(64, kNV), 256, 0, stream>>>(imgf, imgt);
    gemm_tab_kernel<<<dim3(7, 6), 256, 0, stream>>>(tshi, tslo, wkhi, wklo,
                                                    atab);
    build_a0_kernel<<<dim3(kNPIX, 3), 256, 0, stream>>>(
        qpl[0], qpl[1], qpl[2], meantab, ln_g, ln_b, bk, a0hi, a0lo, murs,
        qbk);
    gemm_a0_kernel<<<dim3(7, 32, 3), 256, 0, stream>>>(
        a0hi, a0lo, wkhi, wklo, murs, uvec, vvec, qk0);
    sample_attn5_kernel<<<dim3(kNPIX, 3), 512, 0, stream>>>(
        imgt, w2c, Kin, qk0, atab, uvec, vvec, murs, qbk, whi);
    gemm_out_kernel<<<dim3(7, 32, 9), 256, 0, stream>>>(whi, wvthi, wvtlo,
                                                        out, bv);
  } else {
    // tier-D: f32 fallback (r1-style)
    float* ws = (float*)d_ws;
    const size_t OFF_QBK = 64;
    const size_t OFF_BIG = OFF_QBK + (size_t)kNPIX * 3;
    float* w2c = ws;
    float* qbk = ws + OFF_QBK;
    float* qn = ws + OFF_BIG;
    float* qkb = qn + kQN_FLOATS;

    invert4_kernel<<<1, 64, 0, stream>>>(c2w, w2c);
    for (int p = 0; p < 3; ++p) {
      build_q_f32<<<kNPIX, 256, 0, stream>>>(qpl[0], qpl[1], qpl[2], p, ln_g,
                                             ln_b, bk, qn, qbk);
      gemm_f32<true, false><<<dim3(13, 32, 3), 256, 0, stream>>>(
          qn, Wk, qkb, nullptr, kNPIX, kC, kC, kQD, kQD, kQD, kC);
      sample_attn_f32<<<kNPIX, 256, 0, stream>>>(imgf, w2c, Kin, qkb, qbk, p,
                                                 qn);
      gemm_f32<false, true><<<dim3(13, 32, 3), 256, 0, stream>>>(
          qn, Wv, out + (size_t)p * kQN_FLOATS, bv, kNPIX, kC, kC, kQD, kQD,
          kQD, kC);
    }
  }
}

// Round 13
// 625.343 us; speedup vs baseline: 1.1368x; 1.0713x over previous
//
#include <hip/hip_runtime.h>
#include <math.h>

// ---------------------------------------------------------------------------
// Round 12: best-of recombination. r10's factored qk path (gemm_a0 + combine
// -> full qkb, attn reads 3 dots) + r11's parallel prep_uv + NEW: attn block
// order remapped to 8x8 pixel tiles per XCD (bijective) so co-resident
// blocks share a compact image-tap working set (tap refetch was ~250MB).
// ---------------------------------------------------------------------------

constexpr int kG = 64, kS = 4, kC = 771, kNV = 4;
constexpr int kQD = 2313;
constexpr int kNPIX = 4096;
constexpr int kL = 16;
constexpr int kImgMStride = kC * kG * kG;
constexpr int kKP = 800;
constexpr int kLDA = 2400;
constexpr int kBROWS = 896;
constexpr int kCP = 776;
constexpr int kNG = kCP / 4;
constexpr int kLDQ = 3 * kCP;
constexpr int kIMS2 = kNPIX * kCP;

constexpr size_t kQKB_FLOATS = (size_t)kNPIX * kLDQ;
constexpr size_t kW_ELEMS = (size_t)3 * kBROWS * kKP;
constexpr size_t kA0_ELEMS = (size_t)kNPIX * kKP;
constexpr size_t kWH_ELEMS = (size_t)kNPIX * kLDA;
constexpr size_t kQN_FLOATS = (size_t)kNPIX * kQD;
constexpr size_t kTAB_FLOATS = (size_t)6 * 64 * kC;

using bf16x8 = __attribute__((ext_vector_type(8))) short;
using f32x4 = __attribute__((ext_vector_type(4))) float;

__device__ __forceinline__ unsigned short f2bf(float x) {
  unsigned int u = __float_as_uint(x);
  u = (u + 0x7FFFu + ((u >> 16) & 1u)) >> 16;
  return (unsigned short)u;
}
__device__ __forceinline__ float bf2f(unsigned short h) {
  return __uint_as_float(((unsigned int)h) << 16);
}
__device__ __forceinline__ void gload16(const unsigned short* g,
                                        unsigned short* l) {
  __builtin_amdgcn_global_load_lds(
      (const __attribute__((address_space(1))) void*)g,
      (__attribute__((address_space(3))) void*)l, 16, 0, 0);
}

// ---- tiny 4x4 batched inverse --------------------------------------------
__global__ void invert4_kernel(const float* __restrict__ c2w,
                               float* __restrict__ w2c) {
  const int m = threadIdx.x;
  if (m >= kNV) return;
  float a[4][8];
  for (int r = 0; r < 4; ++r)
    for (int c = 0; c < 4; ++c) {
      a[r][c] = c2w[m * 16 + r * 4 + c];
      a[r][4 + c] = (r == c) ? 1.f : 0.f;
    }
  for (int col = 0; col < 4; ++col) {
    int piv = col;
    float best = fabsf(a[col][col]);
    for (int r = col + 1; r < 4; ++r) {
      float t = fabsf(a[r][col]);
      if (t > best) { best = t; piv = r; }
    }
    if (piv != col)
      for (int c = 0; c < 8; ++c) {
        float t = a[col][c]; a[col][c] = a[piv][c]; a[piv][c] = t;
      }
    const float inv = 1.f / a[col][col];
    for (int c = 0; c < 8; ++c) a[col][c] *= inv;
    for (int r = 0; r < 4; ++r)
      if (r != col) {
        const float f = a[r][col];
        for (int c = 0; c < 8; ++c) a[r][c] -= f * a[col][c];
      }
  }
  for (int r = 0; r < 4; ++r)
    for (int c = 0; c < 4; ++c) w2c[m * 16 + r * 4 + c] = a[r][4 + c];
}

// ---- image transpose [NV,C,H,W] -> [NV,H,W,776] f32 ----------------------
__global__ void __launch_bounds__(256) transpose_img_kernel(
    const float* __restrict__ img, float* __restrict__ out) {
  __shared__ float t[64][65];
  const int y = blockIdx.x, m = blockIdx.y, tid = threadIdx.x;
  const size_t obase = ((size_t)m * kNPIX + (size_t)y * 64) * kCP;
  for (int c0 = 0; c0 < kC; c0 += 64) {
    const int cw = (kC - c0) < 64 ? (kC - c0) : 64;
    for (int idx = tid; idx < cw * 64; idx += 256) {
      const int cl = idx >> 6, x = idx & 63;
      t[cl][x] = img[(((size_t)m * kC + c0 + cl) * 64 + y) * 64 + x];
    }
    __syncthreads();
    for (int idx = tid; idx < 64 * 64; idx += 256) {
      const int x = idx >> 6, cl = idx & 63;
      if (cl < cw) out[obase + (size_t)x * kCP + c0 + cl] = t[cl][x];
    }
    __syncthreads();
  }
  for (int idx = tid; idx < 64 * 8; idx += 256) {
    const int x = idx >> 3, c = 768 + (idx & 7);
    if (c >= kC && c < kCP) out[obase + (size_t)x * kCP + c] = 0.f;
  }
}

// ---- weight prep ----------------------------------------------------------
__global__ void __launch_bounds__(256) prep_wk_kernel(
    const float* __restrict__ Wk, unsigned short* __restrict__ hi,
    unsigned short* __restrict__ lo) {
  const int c = blockIdx.x, h = blockIdx.y;
  const size_t base = ((size_t)h * kBROWS + c) * kKP;
  for (int k = threadIdx.x; k < kKP; k += 256) {
    float v = (c < kC && k < kC) ? Wk[(size_t)c * kQD + h * kC + k] : 0.f;
    const unsigned short a = f2bf(v);
    hi[base + k] = a;
    lo[base + k] = f2bf(v - bf2f(a));
  }
}

__global__ void __launch_bounds__(256) prep_wvt_kernel(
    const float* __restrict__ Wv, unsigned short* __restrict__ hi,
    unsigned short* __restrict__ lo) {
  __shared__ float t[64][65];
  const int k0 = blockIdx.x * 64, j0 = blockIdx.y * 64, h = blockIdx.z;
  const int tx = threadIdx.x & 63, ty4 = threadIdx.x >> 6;
  for (int ty = ty4; ty < 64; ty += 4) {
    const int k = k0 + ty, j = j0 + tx;
    t[ty][tx] = (k < kC && j < kC) ? Wv[(size_t)k * kQD + h * kC + j] : 0.f;
  }
  __syncthreads();
  for (int ty = ty4; ty < 64; ty += 4) {
    const int j = j0 + ty, k = k0 + tx;
    if (j < kBROWS && k < kKP) {
      const float v = t[tx][ty];
      const unsigned short a = f2bf(v);
      const size_t p = ((size_t)h * kBROWS + j) * kKP + k;
      hi[p] = a;
      lo[p] = f2bf(v - bf2f(a));
    }
  }
}

// ---- other-plane mean table (bit-exact) ------------------------------------
__global__ void __launch_bounds__(256) prep_meantab_kernel(
    const float* __restrict__ q_xy, const float* __restrict__ q_xz,
    const float* __restrict__ q_yz, float* __restrict__ tab) {
  const int v = blockIdx.x;  // 0..63
  const int t = blockIdx.y;  // plane*2+part
  const int plane = t >> 1, part = t & 1;
  const float* src;
  if (plane == 0) src = part ? q_yz : q_xz;
  else if (plane == 1) src = part ? q_yz : q_xy;
  else src = part ? q_xz : q_xy;
  __shared__ int sIdx[4][4];
  __shared__ float sW[4][4];
  if (threadIdx.x < 4) {
    const int s = threadIdx.x;
    const float Xv = -1.f + 2.f * v / 63.f;
    const float Ts = -1.f + 2.f * s / 3.f;
    float a, b;
    if (plane == 0) { a = Xv; b = Ts; }
    else if (plane == 1) {
      if (part == 0) { a = Xv; b = Ts; } else { a = Ts; b = Xv; }
    } else { a = Ts; b = Xv; }
    const float ga = fminf(fmaxf((a * 0.5f + 0.5f) * 63.f, 0.f), 63.f);
    const float gb = fminf(fmaxf((b * 0.5f + 0.5f) * 63.f, 0.f), 63.f);
    const float ix = fminf(fmaxf((ga + 1.f) * 0.5f * 63.f, 0.f), 63.f);
    const float iy = fminf(fmaxf((gb + 1.f) * 0.5f * 63.f, 0.f), 63.f);
    const float x0 = floorf(ix), y0 = floorf(iy);
    const float wx = ix - x0, wy = iy - y0;
    const int x0i = (int)x0, y0i = (int)y0;
    const int x1i = (x0i + 1 > 63) ? 63 : x0i + 1;
    const int y1i = (y0i + 1 > 63) ? 63 : y0i + 1;
    sIdx[s][0] = (y0i * 64 + x0i) * kC;
    sIdx[s][1] = (y0i * 64 + x1i) * kC;
    sIdx[s][2] = (y1i * 64 + x0i) * kC;
    sIdx[s][3] = (y1i * 64 + x1i) * kC;
    sW[s][0] = (1.f - wx) * (1.f - wy);
    sW[s][1] = wx * (1.f - wy);
    sW[s][2] = (1.f - wx) * wy;
    sW[s][3] = wx * wy;
  }
  __syncthreads();
  for (int c = threadIdx.x; c < kC; c += 256) {
    float a1 = 0.f;
#pragma unroll
    for (int s = 0; s < 4; ++s) {
      a1 += src[sIdx[s][0] + c] * sW[s][0] + src[sIdx[s][1] + c] * sW[s][1]
          + src[sIdx[s][2] + c] * sW[s][2] + src[sIdx[s][3] + c] * sW[s][3];
    }
    tab[((size_t)t * 64 + v) * kC + c] = a1 * 0.25f;
  }
}

// ---- bf16 split of meantab*g ----------------------------------------------
__global__ void __launch_bounds__(256) prep_tabsplit_kernel(
    const float* __restrict__ tab, const float* __restrict__ ln_g,
    unsigned short* __restrict__ hi, unsigned short* __restrict__ lo) {
  const int v = blockIdx.x;  // 0..127
  const int t = blockIdx.y;  // 0..5
  const int h = 1 + (t & 1);
  const size_t base = ((size_t)t * 128 + v) * kKP;
  for (int k = threadIdx.x; k < kKP; k += 256) {
    float val = 0.f;
    if (v < 64 && k < kC)
      val = tab[((size_t)t * 64 + v) * kC + k] * ln_g[h * kC + k];
    const unsigned short a = f2bf(val);
    hi[base + k] = a;
    lo[base + k] = f2bf(val - bf2f(a));
  }
}

// ---- u_h = Wk_h^T g, v_h = Wk_h^T b — parallel -----------------------------
__global__ void __launch_bounds__(256) prep_uv_kernel(
    const float* __restrict__ Wk, const float* __restrict__ ln_g,
    const float* __restrict__ ln_b, float* __restrict__ u,
    float* __restrict__ v) {
  const int c = blockIdx.x;
  const int h = blockIdx.y;
  __shared__ float ru[4], rv[4];
  float su = 0.f, sv = 0.f;
  if (c < kC) {
    const float* wr = Wk + (size_t)c * kQD + h * kC;
    const float* g = ln_g + h * kC;
    const float* b = ln_b + h * kC;
    for (int k = threadIdx.x; k < kC; k += 256) {
      const float w = wr[k];
      su = fmaf(w, g[k], su);
      sv = fmaf(w, b[k], sv);
    }
  }
#pragma unroll
  for (int off = 32; off; off >>= 1) {
    su += __shfl_down(su, off);
    sv += __shfl_down(sv, off);
  }
  if ((threadIdx.x & 63) == 0) {
    ru[threadIdx.x >> 6] = su;
    rv[threadIdx.x >> 6] = sv;
  }
  __syncthreads();
  if (threadIdx.x == 0) {
    u[h * kCP + c] = ru[0] + ru[1] + ru[2] + ru[3];
    v[h * kCP + c] = rv[0] + rv[1] + rv[2] + rv[3];
  }
}

// ---- build_a0 --------------------------------------------------------------
__global__ void __launch_bounds__(256) build_a0_kernel(
    const float* __restrict__ q_xy, const float* __restrict__ q_xz,
    const float* __restrict__ q_yz, const float* __restrict__ tab,
    const float* __restrict__ ln_g, const float* __restrict__ ln_b,
    const float* __restrict__ bk, unsigned short* __restrict__ a0hi,
    unsigned short* __restrict__ a0lo, float* __restrict__ murs,
    float* __restrict__ qbk) {
  const int slot = blockIdx.y, plane = slot;
  const float* qp = (plane == 0) ? q_xy : (plane == 1) ? q_xz : q_yz;
  const int n = blockIdx.x, i = n >> 6, j = n & 63, tid = threadIdx.x;
  __shared__ float qf[kQD];
  __shared__ float red[16];

  const float* t0 = tab + ((size_t)(plane * 2 + 0) * 64 + j) * kC;
  const float* t1 = tab + ((size_t)(plane * 2 + 1) * 64 + i) * kC;
  for (int c = tid; c < kC; c += 256) {
    qf[c] = qp[(size_t)n * kC + c];
    qf[kC + c] = t0[c];
    qf[2 * kC + c] = t1[c];
  }
  __syncthreads();

  float sm = 0.f;
  for (int idx = tid; idx < kQD; idx += 256) sm += qf[idx];
#pragma unroll
  for (int off = 32; off; off >>= 1) sm += __shfl_down(sm, off);
  if ((tid & 63) == 0) red[tid >> 6] = sm;
  __syncthreads();
  const float mu = (red[0] + red[1] + red[2] + red[3]) * (1.f / kQD);
  __syncthreads();
  float sq = 0.f;
  for (int idx = tid; idx < kQD; idx += 256) {
    const float d = qf[idx] - mu;
    sq += d * d;
  }
#pragma unroll
  for (int off = 32; off; off >>= 1) sq += __shfl_down(sq, off);
  if ((tid & 63) == 0) red[tid >> 6] = sq;
  __syncthreads();
  const float var = (red[0] + red[1] + red[2] + red[3]) * (1.f / kQD);
  const float rstd = 1.f / sqrtf(var + 1e-5f);
  if (tid == 0) {
    murs[2 * ((size_t)slot * kNPIX + n)] = mu;
    murs[2 * ((size_t)slot * kNPIX + n) + 1] = rstd;
  }
  __syncthreads();

  float h0 = 0.f, h1 = 0.f, h2 = 0.f;
  unsigned short* ah = a0hi + (size_t)slot * kA0_ELEMS + (size_t)n * kKP;
  unsigned short* al = a0lo + (size_t)slot * kA0_ELEMS + (size_t)n * kKP;
  for (int idx = tid; idx < 3 * kKP; idx += 256) {
    int h, k;
    if (idx < kKP) { h = 0; k = idx; }
    else if (idx < 2 * kKP) { h = 1; k = idx - kKP; }
    else { h = 2; k = idx - 2 * kKP; }
    if (k < kC) {
      const int li = h * kC + k;
      const float v = (qf[li] - mu) * rstd * ln_g[li] + ln_b[li];
      const float pb = v * bk[li];
      if (h == 0) h0 += pb; else if (h == 1) h1 += pb; else h2 += pb;
    }
    if (idx < kKP) {
      const float y = (idx < kC) ? qf[idx] * ln_g[idx] : 0.f;
      const unsigned short hv = f2bf(y);
      ah[idx] = hv;
      al[idx] = f2bf(y - bf2f(hv));
    }
  }
#pragma unroll
  for (int off = 32; off; off >>= 1) {
    h0 += __shfl_down(h0, off);
    h1 += __shfl_down(h1, off);
    h2 += __shfl_down(h2, off);
  }
  if ((tid & 63) == 0) {
    red[(tid >> 6) * 4 + 0] = h0;
    red[(tid >> 6) * 4 + 1] = h1;
    red[(tid >> 6) * 4 + 2] = h2;
  }
  __syncthreads();
  if (tid < 3)
    qbk[((size_t)slot * kNPIX + n) * 3 + tid] =
        red[tid] + red[4 + tid] + red[8 + tid] + red[12 + tid];
}

// ---- head-0 GEMM: writes qkb head-0 section (full-width rows) -------------
__global__ void __launch_bounds__(256) gemm_a0_kernel(
    const unsigned short* __restrict__ A0hi,
    const unsigned short* __restrict__ A0lo,
    const unsigned short* __restrict__ Bhi,
    const unsigned short* __restrict__ Blo, const float* __restrict__ murs,
    const float* __restrict__ uvec, const float* __restrict__ vvec,
    float* __restrict__ qkb) {
  __shared__ unsigned short smA[2][128 * 32];
  __shared__ unsigned short smB[2][128 * 32];
  const int slot = blockIdx.z;
  const int t = blockIdx.y * 7 + blockIdx.x;
  const int xcd = t & 7, idx = t >> 3;
  const int nb = idx % 7, mb = (xcd << 2) + idx / 7;
  const int m0 = mb * 128, n0 = nb * 128;
  const unsigned short* Ah = A0hi + (size_t)slot * kA0_ELEMS;
  const unsigned short* Al = A0lo + (size_t)slot * kA0_ELEMS;
  const int tid = threadIdx.x;
  const int lane = tid & 63, w = tid >> 6;
  const int wm = w >> 1, wn = w & 1;

  const int sr0 = w * 16 + (lane >> 2);
  const int ss = lane & 3;
  size_t aoff[2], boff[2];
  int ldsb[2];
#pragma unroll
  for (int p = 0; p < 2; ++p) {
    const int r = p * 64 + sr0;
    const int kl = (ss ^ ((r >> 1) & 3)) * 8;
    aoff[p] = (size_t)(m0 + r) * kKP + kl;
    boff[p] = (size_t)(n0 + r) * kKP + kl;
    ldsb[p] = (p * 64 + w * 16) * 32;
  }
  int offA[4], offB[4];
#pragma unroll
  for (int i = 0; i < 4; ++i) {
    const int ra = wm * 64 + i * 16 + (lane & 15);
    offA[i] = ra * 32 + (((lane >> 4) ^ ((ra >> 1) & 3)) << 3);
    const int rb = wn * 64 + i * 16 + (lane & 15);
    offB[i] = rb * 32 + (((lane >> 4) ^ ((rb >> 1) & 3)) << 3);
  }
  f32x4 acc[4][4];
#pragma unroll
  for (int i = 0; i < 4; ++i)
#pragma unroll
    for (int j = 0; j < 4; ++j) acc[i][j] = f32x4{0.f, 0.f, 0.f, 0.f};

  for (int k0 = 0; k0 < kKP; k0 += 32) {
#pragma unroll
    for (int p = 0; p < 2; ++p) {
      gload16(Ah + aoff[p] + k0, &smA[0][ldsb[p]]);
      gload16(Al + aoff[p] + k0, &smA[1][ldsb[p]]);
      gload16(Bhi + boff[p] + k0, &smB[0][ldsb[p]]);
      gload16(Blo + boff[p] + k0, &smB[1][ldsb[p]]);
    }
    __syncthreads();
    bf16x8 ah[4], al[4], bh[4], bl[4];
#pragma unroll
    for (int i = 0; i < 4; ++i) {
      ah[i] = *(const bf16x8*)&smA[0][offA[i]];
      al[i] = *(const bf16x8*)&smA[1][offA[i]];
      bh[i] = *(const bf16x8*)&smB[0][offB[i]];
      bl[i] = *(const bf16x8*)&smB[1][offB[i]];
    }
#pragma unroll
    for (int i = 0; i < 4; ++i)
#pragma unroll
      for (int j = 0; j < 4; ++j)
        acc[i][j] = __builtin_amdgcn_mfma_f32_16x16x32_bf16(ah[i], bh[j],
                                                            acc[i][j], 0, 0, 0);
#pragma unroll
    for (int i = 0; i < 4; ++i)
#pragma unroll
      for (int j = 0; j < 4; ++j)
        acc[i][j] = __builtin_amdgcn_mfma_f32_16x16x32_bf16(ah[i], bl[j],
                                                            acc[i][j], 0, 0, 0);
#pragma unroll
    for (int i = 0; i < 4; ++i)
#pragma unroll
      for (int j = 0; j < 4; ++j)
        acc[i][j] = __builtin_amdgcn_mfma_f32_16x16x32_bf16(al[i], bh[j],
                                                            acc[i][j], 0, 0, 0);
    __syncthreads();
  }

  const float* mr = murs + 2 * ((size_t)slot * kNPIX);
  float* dst = qkb + (size_t)slot * kQKB_FLOATS;
  const int rbase = m0 + wm * 64;
  const int cbase = n0 + wn * 64;
#pragma unroll
  for (int i = 0; i < 4; ++i) {
#pragma unroll
    for (int j = 0; j < 4; ++j) {
      const int col = cbase + j * 16 + (lane & 15);
      if (col < kC) {
        const float uu = uvec[col], vv = vvec[col];
#pragma unroll
        for (int r = 0; r < 4; ++r) {
          const int row = rbase + i * 16 + (lane >> 4) * 4 + r;
          const float mu = mr[2 * row], rs = mr[2 * row + 1];
          dst[(size_t)row * kLDQ + col] = rs * acc[i][j][r] - rs * mu * uu + vv;
        }
      } else if (col < kCP) {
#pragma unroll
        for (int r = 0; r < 4; ++r) {
          const int row = rbase + i * 16 + (lane >> 4) * 4 + r;
          dst[(size_t)row * kLDQ + col] = 0.f;
        }
      }
    }
  }
}

// ---- table GEMM ------------------------------------------------------------
__global__ void __launch_bounds__(256) gemm_tab_kernel(
    const unsigned short* __restrict__ Thi,
    const unsigned short* __restrict__ Tlo,
    const unsigned short* __restrict__ Wkhi,
    const unsigned short* __restrict__ Wklo, float* __restrict__ Atab) {
  __shared__ unsigned short smA[2][128 * 32];
  __shared__ unsigned short smB[2][128 * 32];
  const int t = blockIdx.y;
  const int n0 = blockIdx.x * 128;
  const int h = 1 + (t & 1);
  const unsigned short* Ah = Thi + (size_t)t * 128 * kKP;
  const unsigned short* Al = Tlo + (size_t)t * 128 * kKP;
  const unsigned short* Bh = Wkhi + (size_t)h * kBROWS * kKP;
  const unsigned short* Bl = Wklo + (size_t)h * kBROWS * kKP;
  const int tid = threadIdx.x;
  const int lane = tid & 63, w = tid >> 6;
  const int wm = w >> 1, wn = w & 1;

  const int sr0 = w * 16 + (lane >> 2);
  const int ss = lane & 3;
  size_t aoff[2], boff[2];
  int ldsb[2];
#pragma unroll
  for (int p = 0; p < 2; ++p) {
    const int r = p * 64 + sr0;
    const int kl = (ss ^ ((r >> 1) & 3)) * 8;
    aoff[p] = (size_t)r * kKP + kl;
    boff[p] = (size_t)(n0 + r) * kKP + kl;
    ldsb[p] = (p * 64 + w * 16) * 32;
  }
  int offA[4], offB[4];
#pragma unroll
  for (int i = 0; i < 4; ++i) {
    const int ra = wm * 64 + i * 16 + (lane & 15);
    offA[i] = ra * 32 + (((lane >> 4) ^ ((ra >> 1) & 3)) << 3);
    const int rb = wn * 64 + i * 16 + (lane & 15);
    offB[i] = rb * 32 + (((lane >> 4) ^ ((rb >> 1) & 3)) << 3);
  }
  f32x4 acc[4][4];
#pragma unroll
  for (int i = 0; i < 4; ++i)
#pragma unroll
    for (int j = 0; j < 4; ++j) acc[i][j] = f32x4{0.f, 0.f, 0.f, 0.f};

  for (int k0 = 0; k0 < kKP; k0 += 32) {
#pragma unroll
    for (int p = 0; p < 2; ++p) {
      gload16(Ah + aoff[p] + k0, &smA[0][ldsb[p]]);
      gload16(Al + aoff[p] + k0, &smA[1][ldsb[p]]);
      gload16(Bh + boff[p] + k0, &smB[0][ldsb[p]]);
      gload16(Bl + boff[p] + k0, &smB[1][ldsb[p]]);
    }
    __syncthreads();
    bf16x8 ah[4], al[4], bh[4], bl[4];
#pragma unroll
    for (int i = 0; i < 4; ++i) {
      ah[i] = *(const bf16x8*)&smA[0][offA[i]];
      al[i] = *(const bf16x8*)&smA[1][offA[i]];
      bh[i] = *(const bf16x8*)&smB[0][offB[i]];
      bl[i] = *(const bf16x8*)&smB[1][offB[i]];
    }
#pragma unroll
    for (int i = 0; i < 4; ++i)
#pragma unroll
      for (int j = 0; j < 4; ++j)
        acc[i][j] = __builtin_amdgcn_mfma_f32_16x16x32_bf16(ah[i], bh[j],
                                                            acc[i][j], 0, 0, 0);
#pragma unroll
    for (int i = 0; i < 4; ++i)
#pragma unroll
      for (int j = 0; j < 4; ++j)
        acc[i][j] = __builtin_amdgcn_mfma_f32_16x16x32_bf16(ah[i], bl[j],
                                                            acc[i][j], 0, 0, 0);
#pragma unroll
    for (int i = 0; i < 4; ++i)
#pragma unroll
      for (int j = 0; j < 4; ++j)
        acc[i][j] = __builtin_amdgcn_mfma_f32_16x16x32_bf16(al[i], bh[j],
                                                            acc[i][j], 0, 0, 0);
    __syncthreads();
  }

  float* C = Atab + (size_t)t * 128 * kCP;
  const int rbase = wm * 64;
  const int cbase = n0 + wn * 64;
#pragma unroll
  for (int i = 0; i < 4; ++i) {
#pragma unroll
    for (int j = 0; j < 4; ++j) {
      const int col = cbase + j * 16 + (lane & 15);
      if (col < kCP) {
        const float keep = (col < kC) ? 1.f : 0.f;
#pragma unroll
        for (int r = 0; r < 4; ++r) {
          const int row = rbase + i * 16 + (lane >> 4) * 4 + r;
          C[(size_t)row * kCP + col] = acc[i][j][r] * keep;
        }
      }
    }
  }
}

// ---- combine: fill qkb heads 1/2 ------------------------------------------
__global__ void __launch_bounds__(256) combine_qk_kernel(
    const float* __restrict__ Atab, const float* __restrict__ u,
    const float* __restrict__ v, const float* __restrict__ murs,
    float* __restrict__ qkb) {
  const int slot = blockIdx.y, n = blockIdx.x;
  const int i = n >> 6, j = n & 63, tid = threadIdx.x;
  const float mu = murs[2 * ((size_t)slot * kNPIX + n)];
  const float rs = murs[2 * ((size_t)slot * kNPIX + n) + 1];
  const float rsmu = rs * mu;
  float* dst = qkb + (size_t)slot * kQKB_FLOATS + (size_t)n * kLDQ;
  const float* A1 = Atab + ((size_t)(slot * 2 + 0) * 128 + j) * kCP;
  const float* A2 = Atab + ((size_t)(slot * 2 + 1) * 128 + i) * kCP;
  if (tid < kNG) {
    const int c4 = tid << 2;
    const float4 a1 = *(const float4*)&A1[c4];
    const float4 u1 = *(const float4*)&u[kCP + c4];
    const float4 v1 = *(const float4*)&v[kCP + c4];
    float4 r1;
    r1.x = rs * a1.x - rsmu * u1.x + v1.x;
    r1.y = rs * a1.y - rsmu * u1.y + v1.y;
    r1.z = rs * a1.z - rsmu * u1.z + v1.z;
    r1.w = rs * a1.w - rsmu * u1.w + v1.w;
    *(float4*)&dst[kCP + c4] = r1;
    const float4 a2 = *(const float4*)&A2[c4];
    const float4 u2 = *(const float4*)&u[2 * kCP + c4];
    const float4 v2 = *(const float4*)&v[2 * kCP + c4];
    float4 r2;
    r2.x = rs * a2.x - rsmu * u2.x + v2.x;
    r2.y = rs * a2.y - rsmu * u2.y + v2.y;
    r2.z = rs * a2.z - rsmu * u2.z + v2.z;
    r2.w = rs * a2.w - rsmu * u2.w + v2.w;
    *(float4*)&dst[2 * kCP + c4] = r2;
  }
}

// ---- fused sample+attn (3-dot score), 8x8-tile block order -----------------
__global__ void __launch_bounds__(512, 6) sample_attn4_kernel(
    const float* __restrict__ imgt, const float* __restrict__ w2c,
    const float* __restrict__ Kin, const float* __restrict__ qkb,
    const float* __restrict__ qbk, unsigned short* __restrict__ whi) {
  __shared__ __align__(16) float ctx[kL][kCP];
  __shared__ float sW2[kL][4];
  __shared__ int sI2[kL][4];
  __shared__ float sscp[2][48];
  __shared__ float ssc[48], swt[48];
  const int slot = blockIdx.y, plane = slot;
  // 8x8 pixel-tile order within each XCD (bijective):
  //   xcd = bid&7 -> rows 8*xcd..8*xcd+7; within: i' = (t>>3)&7,
  //   j = (t>>6)*8 + (t&7). Consecutive ~64 blocks share a compact tap set.
  const int bid = blockIdx.x;
  const int xcd = bid & 7, tt = bid >> 3;
  const int i = (xcd << 3) | ((tt >> 3) & 7);
  const int j = (((tt >> 6) << 3) | (tt & 7));
  const int n = (i << 6) | j;
  const int tid = threadIdx.x;
  const float* qkn = qkb + (size_t)slot * kQKB_FLOATS + (size_t)n * kLDQ;

  if (tid < kL) {
    const int s = tid >> 2, m = tid & 3;
    const float Xi = -1.f + 2.f * i / 63.f;
    const float Xj = -1.f + 2.f * j / 63.f;
    const float Ts = -1.f + 2.f * s / 3.f;
    float px, py, pz;
    if (plane == 0) { px = Xj; py = Xi; pz = Ts; }
    else if (plane == 1) { px = Xj; py = Ts; pz = Xi; }
    else { px = Ts; py = Xj; pz = Xi; }
    const float* W = w2c + m * 16;
    const float c0 = W[0] * px + W[1] * py + W[2] * pz + W[3];
    const float c1 = W[4] * px + W[5] * py + W[6] * pz + W[7];
    const float c2 = W[8] * px + W[9] * py + W[10] * pz + W[11];
    const float* Km = Kin + m * 9;
    const float un = Km[0] * c0 + Km[1] * c1 + Km[2] * c2;
    const float vn = Km[3] * c0 + Km[4] * c1 + Km[5] * c2;
    const float ds = c2 + 1e-8f;
    const float u = un / ds, v = vn / ds;
    const bool mk =
        (c2 > 0.f && u >= 0.f && u < 64.f && v >= 0.f && v < 64.f);
    float w00 = 0.f, w10 = 0.f, w01 = 0.f, w11 = 0.f;
    int i00 = 0, i10 = 0, i01 = 0, i11 = 0;
    if (mk) {
      const float gx = 2.f * (u / 63.f) - 1.f;
      const float gy = 2.f * (v / 63.f) - 1.f;
      const float ix = (gx + 1.f) * 0.5f * 63.f;
      const float iy = (gy + 1.f) * 0.5f * 63.f;
      const float x0 = floorf(ix), y0 = floorf(iy);
      const float x1 = x0 + 1.f, y1 = y0 + 1.f;
      const float wx = ix - x0, wy = iy - y0;
      const float v00 = (x0 >= 0.f && x0 <= 63.f && y0 >= 0.f && y0 <= 63.f) ? 1.f : 0.f;
      const float v10 = (x1 >= 0.f && x1 <= 63.f && y0 >= 0.f && y0 <= 63.f) ? 1.f : 0.f;
      const float v01 = (x0 >= 0.f && x0 <= 63.f && y1 >= 0.f && y1 <= 63.f) ? 1.f : 0.f;
      const float v11 = (x1 >= 0.f && x1 <= 63.f && y1 >= 0.f && y1 <= 63.f) ? 1.f : 0.f;
      w00 = (1.f - wx) * (1.f - wy) * v00;
      w10 = wx * (1.f - wy) * v10;
      w01 = (1.f - wx) * wy * v01;
      w11 = wx * wy * v11;
      const int x0i = (int)fminf(fmaxf(x0, 0.f), 63.f);
      const int x1i = (int)fminf(fmaxf(x1, 0.f), 63.f);
      const int y0i = (int)fminf(fmaxf(y0, 0.f), 63.f);
      const int y1i = (int)fminf(fmaxf(y1, 0.f), 63.f);
      const int mb = m * kIMS2;
      i00 = mb + (y0i * 64 + x0i) * kCP;
      i10 = mb + (y0i * 64 + x1i) * kCP;
      i01 = mb + (y1i * 64 + x0i) * kCP;
      i11 = mb + (y1i * 64 + x1i) * kCP;
    }
    sI2[tid][0] = i00; sI2[tid][1] = i10; sI2[tid][2] = i01; sI2[tid][3] = i11;
    sW2[tid][0] = w00; sW2[tid][1] = w10; sW2[tid][2] = w01; sW2[tid][3] = w11;
  }
  __syncthreads();

  const int lane = tid & 63, wv = tid >> 6;
#pragma unroll
  for (int q = 0; q < 2; ++q) {
    const int l = (wv << 1) + q;
    const float a0 = sW2[l][0], a1 = sW2[l][1], a2 = sW2[l][2], a3 = sW2[l][3];
    const int b0 = sI2[l][0], b1 = sI2[l][1], b2 = sI2[l][2], b3 = sI2[l][3];
    for (int g = lane; g < kNG; g += 64) {
      const int c4 = g << 2;
      const float4 t0 = *(const float4*)&imgt[b0 + c4];
      const float4 t1 = *(const float4*)&imgt[b1 + c4];
      const float4 t2 = *(const float4*)&imgt[b2 + c4];
      const float4 t3 = *(const float4*)&imgt[b3 + c4];
      float4 r;
      r.x = fmaf(t0.x, a0, fmaf(t1.x, a1, fmaf(t2.x, a2, t3.x * a3)));
      r.y = fmaf(t0.y, a0, fmaf(t1.y, a1, fmaf(t2.y, a2, t3.y * a3)));
      r.z = fmaf(t0.z, a0, fmaf(t1.z, a1, fmaf(t2.z, a2, t3.z * a3)));
      r.w = fmaf(t0.w, a0, fmaf(t1.w, a1, fmaf(t2.w, a2, t3.w * a3)));
      *(float4*)&ctx[l][c4] = r;
    }
  }
  __syncthreads();

  const int g16 = tid >> 4, l16 = tid & 15;
  const float* qbkn = qbk + ((size_t)slot * kNPIX + n) * 3;
  {
    const int l = g16 & 15, half = g16 >> 4;
    float p0 = 0.f, p1 = 0.f, p2 = 0.f;
#pragma unroll
    for (int it = 0; it < 6; ++it) {
      const int c4 = (l16 + ((2 * it + half) << 4)) << 2;
      const float4 cv = *(const float4*)&ctx[l][c4];
      const float4 q0 = *(const float4*)&qkn[c4];
      const float4 q1 = *(const float4*)&qkn[kCP + c4];
      const float4 q2 = *(const float4*)&qkn[2 * kCP + c4];
      p0 = fmaf(cv.x, q0.x, fmaf(cv.y, q0.y, fmaf(cv.z, q0.z, fmaf(cv.w, q0.w, p0))));
      p1 = fmaf(cv.x, q1.x, fmaf(cv.y, q1.y, fmaf(cv.z, q1.z, fmaf(cv.w, q1.w, p1))));
      p2 = fmaf(cv.x, q2.x, fmaf(cv.y, q2.y, fmaf(cv.z, q2.z, fmaf(cv.w, q2.w, p2))));
    }
    if (half == 0 && l16 < 2) {
      const int c4 = (192 + l16) << 2;
      const float4 cv = *(const float4*)&ctx[l][c4];
      const float4 q0 = *(const float4*)&qkn[c4];
      const float4 q1 = *(const float4*)&qkn[kCP + c4];
      const float4 q2 = *(const float4*)&qkn[2 * kCP + c4];
      p0 = fmaf(cv.x, q0.x, fmaf(cv.y, q0.y, fmaf(cv.z, q0.z, fmaf(cv.w, q0.w, p0))));
      p1 = fmaf(cv.x, q1.x, fmaf(cv.y, q1.y, fmaf(cv.z, q1.z, fmaf(cv.w, q1.w, p1))));
      p2 = fmaf(cv.x, q2.x, fmaf(cv.y, q2.y, fmaf(cv.z, q2.z, fmaf(cv.w, q2.w, p2))));
    }
#pragma unroll
    for (int off = 8; off; off >>= 1) {
      p0 += __shfl_down(p0, off, 16);
      p1 += __shfl_down(p1, off, 16);
      p2 += __shfl_down(p2, off, 16);
    }
    if (l16 == 0) {
      sscp[half][l] = p0;
      sscp[half][16 + l] = p1;
      sscp[half][32 + l] = p2;
    }
  }
  __syncthreads();
  if (tid < 48) ssc[tid] = sscp[0][tid] + sscp[1][tid] + qbkn[tid >> 4];
  __syncthreads();
  if (tid < 3) {
    float mx = ssc[tid * 16];
#pragma unroll
    for (int l = 1; l < kL; ++l) mx = fmaxf(mx, ssc[tid * 16 + l]);
    float e[kL];
    float sum = 0.f;
#pragma unroll
    for (int l = 0; l < kL; ++l) {
      e[l] = expf(ssc[tid * 16 + l] - mx);
      sum += e[l];
    }
    const float inv = 1.f / sum;
#pragma unroll
    for (int l = 0; l < kL; ++l) swt[tid * 16 + l] = e[l] * inv;
  }
  __syncthreads();

  unsigned short* wh = whi + (size_t)slot * kWH_ELEMS + (size_t)n * kLDA;
  if (tid < 2 * kNG) {
    const int c4 = (tid >> 1) << 2;
    const int l0 = (tid & 1) << 3;
    float4 o0{0.f, 0.f, 0.f, 0.f}, o1{0.f, 0.f, 0.f, 0.f},
        o2{0.f, 0.f, 0.f, 0.f};
#pragma unroll
    for (int dl = 0; dl < 8; ++dl) {
      const int l = l0 + dl;
      const float4 cv = *(const float4*)&ctx[l][c4];
      const float s0 = swt[l], s1 = swt[16 + l], s2 = swt[32 + l];
      o0.x = fmaf(cv.x, s0, o0.x); o0.y = fmaf(cv.y, s0, o0.y);
      o0.z = fmaf(cv.z, s0, o0.z); o0.w = fmaf(cv.w, s0, o0.w);
      o1.x = fmaf(cv.x, s1, o1.x); o1.y = fmaf(cv.y, s1, o1.y);
      o1.z = fmaf(cv.z, s1, o1.z); o1.w = fmaf(cv.w, s1, o1.w);
      o2.x = fmaf(cv.x, s2, o2.x); o2.y = fmaf(cv.y, s2, o2.y);
      o2.z = fmaf(cv.z, s2, o2.z); o2.w = fmaf(cv.w, s2, o2.w);
    }
    o0.x += __shfl_xor(o0.x, 1); o0.y += __shfl_xor(o0.y, 1);
    o0.z += __shfl_xor(o0.z, 1); o0.w += __shfl_xor(o0.w, 1);
    o1.x += __shfl_xor(o1.x, 1); o1.y += __shfl_xor(o1.y, 1);
    o1.z += __shfl_xor(o1.z, 1); o1.w += __shfl_xor(o1.w, 1);
    o2.x += __shfl_xor(o2.x, 1); o2.y += __shfl_xor(o2.y, 1);
    o2.z += __shfl_xor(o2.z, 1); o2.w += __shfl_xor(o2.w, 1);
    if ((tid & 1) == 0) {
      float4 ov[3] = {o0, o1, o2};
#pragma unroll
      for (int h = 0; h < 3; ++h) {
        ushort4 hi;
        hi.x = f2bf(ov[h].x);
        hi.y = f2bf(ov[h].y);
        hi.z = f2bf(ov[h].z);
        hi.w = f2bf(ov[h].w);
        *(ushort4*)&wh[h * kKP + c4] = hi;
      }
    }
  }
  if (tid < 72) {
    const int h = tid / 24, k2 = kCP + tid % 24;
    wh[h * kKP + k2] = 0;
  }
}

// ---- out-GEMM: whi x Wv split (2-term), XCD panel swizzle -----------------
__global__ void __launch_bounds__(256) gemm_out_kernel(
    const unsigned short* __restrict__ Ahi,
    const unsigned short* __restrict__ Bhi,
    const unsigned short* __restrict__ Blo, float* __restrict__ C,
    const float* __restrict__ bias) {
  __shared__ unsigned short smA[128 * 32];
  __shared__ unsigned short smB[2][128 * 32];
  const int slot = blockIdx.z / 3, h = blockIdx.z % 3;
  const int t = blockIdx.y * 7 + blockIdx.x;
  const int xcd = t & 7, idx = t >> 3;
  const int nb = idx % 7, mb = (xcd << 2) + idx / 7;
  const int m0 = mb * 128, n0 = nb * 128;
  const unsigned short* Ah = Ahi + (size_t)slot * kWH_ELEMS;
  float* Cs = C + (size_t)slot * kQN_FLOATS;
  const int tid = threadIdx.x;
  const int lane = tid & 63, w = tid >> 6;
  const int wm = w >> 1, wn = w & 1;

  const int sr0 = w * 16 + (lane >> 2);
  const int ss = lane & 3;
  size_t aoff[2], boff[2];
  int ldsb[2];
#pragma unroll
  for (int p = 0; p < 2; ++p) {
    const int r = p * 64 + sr0;
    const int kl = (ss ^ ((r >> 1) & 3)) * 8;
    aoff[p] = (size_t)(m0 + r) * kLDA + (size_t)h * kKP + kl;
    boff[p] = ((size_t)h * kBROWS + (n0 + r)) * kKP + kl;
    ldsb[p] = (p * 64 + w * 16) * 32;
  }
  int offA[4], offB[4];
#pragma unroll
  for (int i = 0; i < 4; ++i) {
    const int ra = wm * 64 + i * 16 + (lane & 15);
    offA[i] = ra * 32 + (((lane >> 4) ^ ((ra >> 1) & 3)) << 3);
    const int rb = wn * 64 + i * 16 + (lane & 15);
    offB[i] = rb * 32 + (((lane >> 4) ^ ((rb >> 1) & 3)) << 3);
  }
  f32x4 acc[4][4];
#pragma unroll
  for (int i = 0; i < 4; ++i)
#pragma unroll
    for (int j = 0; j < 4; ++j) acc[i][j] = f32x4{0.f, 0.f, 0.f, 0.f};

  for (int k0 = 0; k0 < kKP; k0 += 32) {
#pragma unroll
    for (int p = 0; p < 2; ++p) {
      gload16(Ah + aoff[p] + k0, &smA[ldsb[p]]);
      gload16(Bhi + boff[p] + k0, &smB[0][ldsb[p]]);
      gload16(Blo + boff[p] + k0, &smB[1][ldsb[p]]);
    }
    __syncthreads();
    bf16x8 ah[4], bh[4], bl[4];
#pragma unroll
    for (int i = 0; i < 4; ++i) {
      ah[i] = *(const bf16x8*)&smA[offA[i]];
      bh[i] = *(const bf16x8*)&smB[0][offB[i]];
      bl[i] = *(const bf16x8*)&smB[1][offB[i]];
    }
#pragma unroll
    for (int i = 0; i < 4; ++i)
#pragma unroll
      for (int j = 0; j < 4; ++j)
        acc[i][j] = __builtin_amdgcn_mfma_f32_16x16x32_bf16(ah[i], bh[j],
                                                            acc[i][j], 0, 0, 0);
#pragma unroll
    for (int i = 0; i < 4; ++i)
#pragma unroll
      for (int j = 0; j < 4; ++j)
        acc[i][j] = __builtin_amdgcn_mfma_f32_16x16x32_bf16(ah[i], bl[j],
                                                            acc[i][j], 0, 0, 0);
    __syncthreads();
  }

  const int rbase = m0 + wm * 64;
  const int cbase = n0 + wn * 64;
#pragma unroll
  for (int i = 0; i < 4; ++i) {
#pragma unroll
    for (int j = 0; j < 4; ++j) {
      const int col = cbase + j * 16 + (lane & 15);
      if (col < kC) {
        const float bb = bias[h * kC + col];
#pragma unroll
        for (int r = 0; r < 4; ++r) {
          const int row = rbase + i * 16 + (lane >> 4) * 4 + r;
          Cs[(size_t)row * kQD + h * kC + col] = acc[i][j][r] + bb;
        }
      }
    }
  }
}

// ======================= tier-D f32 fallback path ==========================
__global__ void __launch_bounds__(256) build_q_f32(
    const float* __restrict__ q_xy, const float* __restrict__ q_xz,
    const float* __restrict__ q_yz, const int plane,
    const float* __restrict__ ln_g, const float* __restrict__ ln_b,
    const float* __restrict__ bk, float* __restrict__ qn,
    float* __restrict__ qbk) {
  const float* qp = (plane == 0) ? q_xy : (plane == 1) ? q_xz : q_yz;
  const float* qo0 = (plane == 0) ? q_xz : q_xy;
  const float* qo1 = (plane == 2) ? q_xz : q_yz;
  const int n = blockIdx.x, i = n >> 6, j = n & 63, tid = threadIdx.x;
  __shared__ float qf[kQD];
  __shared__ int sIdx[2][4][4];
  __shared__ float sW[2][4][4];
  __shared__ float red[16];

  if (tid < 8) {
    const int part = tid >> 2, s = tid & 3;
    const float Xi = -1.f + 2.f * i / 63.f;
    const float Xj = -1.f + 2.f * j / 63.f;
    const float Ts = -1.f + 2.f * s / 3.f;
    float a, b;
    if (plane == 0) { a = part ? Xi : Xj; b = Ts; }
    else if (plane == 1) {
      if (part == 0) { a = Xj; b = Ts; } else { a = Ts; b = Xi; }
    } else { a = Ts; b = part ? Xi : Xj; }
    const float ga = fminf(fmaxf((a * 0.5f + 0.5f) * 63.f, 0.f), 63.f);
    const float gb = fminf(fmaxf((b * 0.5f + 0.5f) * 63.f, 0.f), 63.f);
    const float ix = fminf(fmaxf((ga + 1.f) * 0.5f * 63.f, 0.f), 63.f);
    const float iy = fminf(fmaxf((gb + 1.f) * 0.5f * 63.f, 0.f), 63.f);
    const float x0 = floorf(ix), y0 = floorf(iy);
    const float wx = ix - x0, wy = iy - y0;
    const int x0i = (int)x0, y0i = (int)y0;
    const int x1i = (x0i + 1 > 63) ? 63 : x0i + 1;
    const int y1i = (y0i + 1 > 63) ? 63 : y0i + 1;
    sIdx[part][s][0] = (y0i * 64 + x0i) * kC;
    sIdx[part][s][1] = (y0i * 64 + x1i) * kC;
    sIdx[part][s][2] = (y1i * 64 + x0i) * kC;
    sIdx[part][s][3] = (y1i * 64 + x1i) * kC;
    sW[part][s][0] = (1.f - wx) * (1.f - wy);
    sW[part][s][1] = wx * (1.f - wy);
    sW[part][s][2] = (1.f - wx) * wy;
    sW[part][s][3] = wx * wy;
  }
  __syncthreads();
  for (int c = tid; c < kC; c += 256) {
    qf[c] = qp[(size_t)n * kC + c];
    float a1 = 0.f, a2 = 0.f;
#pragma unroll
    for (int s = 0; s < 4; ++s) {
      a1 += qo0[sIdx[0][s][0] + c] * sW[0][s][0]
          + qo0[sIdx[0][s][1] + c] * sW[0][s][1]
          + qo0[sIdx[0][s][2] + c] * sW[0][s][2]
          + qo0[sIdx[0][s][3] + c] * sW[0][s][3];
      a2 += qo1[sIdx[1][s][0] + c] * sW[1][s][0]
          + qo1[sIdx[1][s][1] + c] * sW[1][s][1]
          + qo1[sIdx[1][s][2] + c] * sW[1][s][2]
          + qo1[sIdx[1][s][3] + c] * sW[1][s][3];
    }
    qf[kC + c] = a1 * 0.25f;
    qf[2 * kC + c] = a2 * 0.25f;
  }
  __syncthreads();
  float sm = 0.f;
  for (int idx = tid; idx < kQD; idx += 256) sm += qf[idx];
#pragma unroll
  for (int off = 32; off; off >>= 1) sm += __shfl_down(sm, off);
  if ((tid & 63) == 0) red[tid >> 6] = sm;
  __syncthreads();
  const float mu = (red[0] + red[1] + red[2] + red[3]) * (1.f / kQD);
  __syncthreads();
  float sq = 0.f;
  for (int idx = tid; idx < kQD; idx += 256) {
    const float d = qf[idx] - mu;
    sq += d * d;
  }
#pragma unroll
  for (int off = 32; off; off >>= 1) sq += __shfl_down(sq, off);
  if ((tid & 63) == 0) red[tid >> 6] = sq;
  __syncthreads();
  const float var = (red[0] + red[1] + red[2] + red[3]) * (1.f / kQD);
  const float rstd = 1.f / sqrtf(var + 1e-5f);
  __syncthreads();
  float h0 = 0.f, h1 = 0.f, h2 = 0.f;
  for (int idx = tid; idx < kQD; idx += 256) {
    const float v = (qf[idx] - mu) * rstd * ln_g[idx] + ln_b[idx];
    qn[(size_t)n * kQD + idx] = v;
    const float pb = v * bk[idx];
    if (idx < kC) h0 += pb;
    else if (idx < 2 * kC) h1 += pb;
    else h2 += pb;
  }
#pragma unroll
  for (int off = 32; off; off >>= 1) {
    h0 += __shfl_down(h0, off);
    h1 += __shfl_down(h1, off);
    h2 += __shfl_down(h2, off);
  }
  if ((tid & 63) == 0) {
    red[(tid >> 6) * 4 + 0] = h0;
    red[(tid >> 6) * 4 + 1] = h1;
    red[(tid >> 6) * 4 + 2] = h2;
  }
  __syncthreads();
  if (tid < 3)
    qbk[n * 3 + tid] = red[tid] + red[4 + tid] + red[8 + tid] + red[12 + tid];
}

__global__ void __launch_bounds__(256) sample_attn_f32(
    const float* __restrict__ src, const float* __restrict__ w2c,
    const float* __restrict__ Kin, const float* __restrict__ qk,
    const float* __restrict__ qbk, const int plane, float* __restrict__ wctx) {
  __shared__ float ctx[kL * kC];
  __shared__ float su[kL], sv[kL], smk[kL];
  __shared__ float spart[4][48];
  __shared__ float ssc[48];
  __shared__ float swt[48];
  const int n = blockIdx.x, i = n >> 6, j = n & 63, tid = threadIdx.x;

  if (tid < kL) {
    const int s = tid >> 2, m = tid & 3;
    const float Xi = -1.f + 2.f * i / 63.f;
    const float Xj = -1.f + 2.f * j / 63.f;
    const float Ts = -1.f + 2.f * s / 3.f;
    float px, py, pz;
    if (plane == 0) { px = Xj; py = Xi; pz = Ts; }
    else if (plane == 1) { px = Xj; py = Ts; pz = Xi; }
    else { px = Ts; py = Xj; pz = Xi; }
    const float* W = w2c + m * 16;
    const float c0 = W[0] * px + W[1] * py + W[2] * pz + W[3];
    const float c1 = W[4] * px + W[5] * py + W[6] * pz + W[7];
    const float c2 = W[8] * px + W[9] * py + W[10] * pz + W[11];
    const float* Km = Kin + m * 9;
    const float un = Km[0] * c0 + Km[1] * c1 + Km[2] * c2;
    const float vn = Km[3] * c0 + Km[4] * c1 + Km[5] * c2;
    const float ds = c2 + 1e-8f;
    const float u = un / ds, v = vn / ds;
    const float mk =
        (c2 > 0.f && u >= 0.f && u < 64.f && v >= 0.f && v < 64.f) ? 1.f : 0.f;
    su[tid] = u; sv[tid] = v; smk[tid] = mk;
  }
  __syncthreads();

  for (int l = 0; l < kL; ++l) {
    const int m = l & 3;
    const float u = su[l], v = sv[l], mk = smk[l];
    float w00 = 0.f, w10 = 0.f, w01 = 0.f, w11 = 0.f;
    int i00 = 0, i10 = 0, i01 = 0, i11 = 0;
    if (mk != 0.f) {
      const float gx = 2.f * (u / 63.f) - 1.f;
      const float gy = 2.f * (v / 63.f) - 1.f;
      const float ix = (gx + 1.f) * 0.5f * 63.f;
      const float iy = (gy + 1.f) * 0.5f * 63.f;
      const float x0 = floorf(ix), y0 = floorf(iy);
      const float x1 = x0 + 1.f, y1 = y0 + 1.f;
      const float wx = ix - x0, wy = iy - y0;
      const float v00 = (x0 >= 0.f && x0 <= 63.f && y0 >= 0.f && y0 <= 63.f) ? 1.f : 0.f;
      const float v10 = (x1 >= 0.f && x1 <= 63.f && y0 >= 0.f && y0 <= 63.f) ? 1.f : 0.f;
      const float v01 = (x0 >= 0.f && x0 <= 63.f && y1 >= 0.f && y1 <= 63.f) ? 1.f : 0.f;
      const float v11 = (x1 >= 0.f && x1 <= 63.f && y1 >= 0.f && y1 <= 63.f) ? 1.f : 0.f;
      w00 = (1.f - wx) * (1.f - wy) * v00;
      w10 = wx * (1.f - wy) * v10;
      w01 = (1.f - wx) * wy * v01;
      w11 = wx * wy * v11;
      const int x0i = (int)fminf(fmaxf(x0, 0.f), 63.f);
      const int x1i = (int)fminf(fmaxf(x1, 0.f), 63.f);
      const int y0i = (int)fminf(fmaxf(y0, 0.f), 63.f);
      const int y1i = (int)fminf(fmaxf(y1, 0.f), 63.f);
      const int mb = m * kImgMStride;
      i00 = mb + (y0i * 64 + x0i);
      i10 = mb + (y0i * 64 + x1i);
      i01 = mb + (y1i * 64 + x0i);
      i11 = mb + (y1i * 64 + x1i);
    }
    for (int c = tid; c < kC; c += 256) {
      const int cs = c * (kG * kG);
      ctx[l * kC + c] = src[i00 + cs] * w00 + src[i10 + cs] * w10 +
                        src[i01 + cs] * w01 + src[i11 + cs] * w11;
    }
  }
  __syncthreads();

  float acc[48];
#pragma unroll
  for (int t = 0; t < 48; ++t) acc[t] = 0.f;
  const float* qkn = qk + (size_t)n * kQD;
  for (int c = tid; c < kC; c += 256) {
    const float q0 = qkn[c], q1 = qkn[kC + c], q2 = qkn[2 * kC + c];
#pragma unroll
    for (int l = 0; l < kL; ++l) {
      const float cv = ctx[l * kC + c];
      acc[l] = fmaf(cv, q0, acc[l]);
      acc[16 + l] = fmaf(cv, q1, acc[16 + l]);
      acc[32 + l] = fmaf(cv, q2, acc[32 + l]);
    }
  }
#pragma unroll
  for (int t = 0; t < 48; ++t) {
    float x = acc[t];
#pragma unroll
    for (int off = 32; off; off >>= 1) x += __shfl_down(x, off);
    acc[t] = x;
  }
  if ((tid & 63) == 0) {
#pragma unroll
    for (int t = 0; t < 48; ++t) spart[tid >> 6][t] = acc[t];
  }
  __syncthreads();
  if (tid < 48)
    ssc[tid] = spart[0][tid] + spart[1][tid] + spart[2][tid] + spart[3][tid] +
               qbk[n * 3 + (tid >> 4)];
  __syncthreads();
  if (tid < 3) {
    float mx = ssc[tid * 16];
#pragma unroll
    for (int l = 1; l < kL; ++l) mx = fmaxf(mx, ssc[tid * 16 + l]);
    float e[kL];
    float sum = 0.f;
#pragma unroll
    for (int l = 0; l < kL; ++l) {
      e[l] = expf(ssc[tid * 16 + l] - mx);
      sum += e[l];
    }
    const float inv = 1.f / sum;
#pragma unroll
    for (int l = 0; l < kL; ++l) swt[tid * 16 + l] = e[l] * inv;
  }
  __syncthreads();
  for (int c = tid; c < kC; c += 256) {
    float o0 = 0.f, o1 = 0.f, o2 = 0.f;
#pragma unroll
    for (int l = 0; l < kL; ++l) {
      const float cv = ctx[l * kC + c];
      o0 = fmaf(swt[l], cv, o0);
      o1 = fmaf(swt[16 + l], cv, o1);
      o2 = fmaf(swt[32 + l], cv, o2);
    }
    float* wn = wctx + (size_t)n * kQD;
    wn[c] = o0;
    wn[kC + c] = o1;
    wn[2 * kC + c] = o2;
  }
}

template <bool BT, bool BIAS>
__global__ void __launch_bounds__(256) gemm_f32(
    const float* __restrict__ A, const float* __restrict__ B,
    float* __restrict__ Cp, const float* __restrict__ bias, const int M,
    const int N, const int K, const int lda, const int ldb, const int ldc,
    const int hstride) {
  constexpr int BM = 128, BN = 64, BK = 16;
  __shared__ float As[BK][BM + 4];
  __shared__ float Bs[BK][BN + 4];
  const int hoff = blockIdx.z * hstride;
  const int m0 = blockIdx.y * BM, n0 = blockIdx.x * BN;
  const int tid = threadIdx.x;
  const int ty = tid >> 4, tx = tid & 15;
  float acc[8][4];
#pragma unroll
  for (int r = 0; r < 8; ++r)
#pragma unroll
    for (int c = 0; c < 4; ++c) acc[r][c] = 0.f;
  for (int k0 = 0; k0 < K; k0 += BK) {
#pragma unroll
    for (int p = 0; p < 8; ++p) {
      const int idx = tid + p * 256;
      const int mm = idx >> 4, kk = idx & 15;
      float v = 0.f;
      if (k0 + kk < K) v = A[(size_t)(m0 + mm) * lda + hoff + k0 + kk];
      As[kk][mm] = v;
    }
    if (BT) {
#pragma unroll
      for (int p = 0; p < 4; ++p) {
        const int idx = tid + p * 256;
        const int jj = idx >> 4, kk = idx & 15;
        float v = 0.f;
        if ((n0 + jj) < N && (k0 + kk) < K)
          v = B[(size_t)(n0 + jj) * ldb + hoff + k0 + kk];
        Bs[kk][jj] = v;
      }
    } else {
#pragma unroll
      for (int p = 0; p < 4; ++p) {
        const int idx = tid + p * 256;
        const int kk = idx >> 6, jj = idx & 63;
        float v = 0.f;
        if ((n0 + jj) < N && (k0 + kk) < K)
          v = B[(size_t)(k0 + kk) * ldb + hoff + n0 + jj];
        Bs[kk][jj] = v;
      }
    }
    __syncthreads();
#pragma unroll
    for (int kk = 0; kk < BK; ++kk) {
      float a[8], b[4];
#pragma unroll
      for (int r = 0; r < 8; ++r) a[r] = As[kk][ty * 8 + r];
#pragma unroll
      for (int c = 0; c < 4; ++c) b[c] = Bs[kk][tx * 4 + c];
#pragma unroll
      for (int r = 0; r < 8; ++r)
#pragma unroll
        for (int c = 0; c < 4; ++c) acc[r][c] = fmaf(a[r], b[c], acc[r][c]);
    }
    __syncthreads();
  }
#pragma unroll
  for (int r = 0; r < 8; ++r) {
    const int mm = m0 + ty * 8 + r;
    if (mm >= M) continue;
#pragma unroll
    for (int c = 0; c < 4; ++c) {
      const int jj = n0 + tx * 4 + c;
      if (jj < N) {
        float v = acc[r][c];
        if (BIAS) v += bias[hoff + jj];
        Cp[(size_t)mm * ldc + hoff + jj] = v;
      }
    }
  }
}

// ---------------------------------------------------------------------------
extern "C" void kernel_launch(void* const* d_in, const int* in_sizes, int n_in,
                              void* d_out, int out_size, void* d_ws,
                              size_t ws_size, hipStream_t stream) {
  const float* imgf = (const float*)d_in[0];
  const float* c2w = (const float*)d_in[2];
  const float* Kin = (const float*)d_in[3];
  const float* qpl[3] = {(const float*)d_in[5], (const float*)d_in[6],
                         (const float*)d_in[7]};
  const float* Wk = (const float*)d_in[8];
  const float* bk = (const float*)d_in[9];
  const float* Wv = (const float*)d_in[10];
  const float* bv = (const float*)d_in[11];
  const float* ln_g = (const float*)d_in[12];
  const float* ln_b = (const float*)d_in[13];
  float* out = (float*)d_out;
  char* wsb = (char*)d_ws;

  const size_t IMGT_FLOATS = (size_t)kNV * kIMS2;

  size_t off = 0;
  auto take = [&](size_t bytes) {
    size_t p = off;
    off = (off + bytes + 511) & ~(size_t)511;
    return p;
  };
  const size_t o_w2c = take(64 * 4);
  const size_t o_qbk = take((size_t)3 * kNPIX * 3 * 4);
  const size_t o_qkb = take((size_t)3 * kQKB_FLOATS * 4);
  const size_t o_wkhi = take(kW_ELEMS * 2);
  const size_t o_wklo = take(kW_ELEMS * 2);
  const size_t o_wvthi = take(kW_ELEMS * 2);
  const size_t o_wvtlo = take(kW_ELEMS * 2);
  const size_t o_a0hi = take((size_t)3 * kA0_ELEMS * 2);
  const size_t o_a0lo = take((size_t)3 * kA0_ELEMS * 2);
  const size_t o_whi = take((size_t)3 * kWH_ELEMS * 2);
  const size_t o_murs = take((size_t)3 * kNPIX * 2 * 4);
  const size_t o_u = take((size_t)3 * kCP * 4);
  const size_t o_v = take((size_t)3 * kCP * 4);
  const size_t o_tab = take(kTAB_FLOATS * 4);
  const size_t o_tshi = take((size_t)6 * 128 * kKP * 2);
  const size_t o_tslo = take((size_t)6 * 128 * kKP * 2);
  const size_t o_atab = take((size_t)6 * 128 * kCP * 4);
  const size_t o_imgt = take(IMGT_FLOATS * 4);
  const size_t need = off;

  if (ws_size >= need) {
    float* w2c = (float*)(wsb + o_w2c);
    float* qbk = (float*)(wsb + o_qbk);
    float* qkb = (float*)(wsb + o_qkb);
    unsigned short* wkhi = (unsigned short*)(wsb + o_wkhi);
    unsigned short* wklo = (unsigned short*)(wsb + o_wklo);
    unsigned short* wvthi = (unsigned short*)(wsb + o_wvthi);
    unsigned short* wvtlo = (unsigned short*)(wsb + o_wvtlo);
    unsigned short* a0hi = (unsigned short*)(wsb + o_a0hi);
    unsigned short* a0lo = (unsigned short*)(wsb + o_a0lo);
    unsigned short* whi = (unsigned short*)(wsb + o_whi);
    float* murs = (float*)(wsb + o_murs);
    float* uvec = (float*)(wsb + o_u);
    float* vvec = (float*)(wsb + o_v);
    float* meantab = (float*)(wsb + o_tab);
    unsigned short* tshi = (unsigned short*)(wsb + o_tshi);
    unsigned short* tslo = (unsigned short*)(wsb + o_tslo);
    float* atab = (float*)(wsb + o_atab);
    float* imgt = (float*)(wsb + o_imgt);

    invert4_kernel<<<1, 64, 0, stream>>>(c2w, w2c);
    prep_wk_kernel<<<dim3(kBROWS, 3), 256, 0, stream>>>(Wk, wkhi, wklo);
    prep_wvt_kernel<<<dim3(13, 14, 3), 256, 0, stream>>>(Wv, wvthi, wvtlo);
    prep_meantab_kernel<<<dim3(64, 6), 256, 0, stream>>>(qpl[0], qpl[1],
                                                         qpl[2], meantab);
    prep_tabsplit_kernel<<<dim3(128, 6), 256, 0, stream>>>(meantab, ln_g,
                                                           tshi, tslo);
    prep_uv_kernel<<<dim3(kCP, 3), 256, 0, stream>>>(Wk, ln_g, ln_b, uvec,
                                                     vvec);
    transpose_img_kernel<<<dim3(64, kNV), 256, 0, stream>>>(imgf, imgt);
    gemm_tab_kernel<<<dim3(7, 6), 256, 0, stream>>>(tshi, tslo, wkhi, wklo,
                                                    atab);
    build_a0_kernel<<<dim3(kNPIX, 3), 256, 0, stream>>>(
        qpl[0], qpl[1], qpl[2], meantab, ln_g, ln_b, bk, a0hi, a0lo, murs,
        qbk);
    gemm_a0_kernel<<<dim3(7, 32, 3), 256, 0, stream>>>(
        a0hi, a0lo, wkhi, wklo, murs, uvec, vvec, qkb);
    combine_qk_kernel<<<dim3(kNPIX, 3), 256, 0, stream>>>(atab, uvec, vvec,
                                                          murs, qkb);
    sample_attn4_kernel<<<dim3(kNPIX, 3), 512, 0, stream>>>(
        imgt, w2c, Kin, qkb, qbk, whi);
    gemm_out_kernel<<<dim3(7, 32, 9), 256, 0, stream>>>(whi, wvthi, wvtlo,
                                                        out, bv);
  } else {
    // tier-D: f32 fallback
    float* ws = (float*)d_ws;
    const size_t OFF_QBK = 64;
    const size_t OFF_BIG = OFF_QBK + (size_t)kNPIX * 3;
    float* w2c = ws;
    float* qbk = ws + OFF_QBK;
    float* qn = ws + OFF_BIG;
    float* qkb = qn + kQN_FLOATS;

    invert4_kernel<<<1, 64, 0, stream>>>(c2w, w2c);
    for (int p = 0; p < 3; ++p) {
      build_q_f32<<<kNPIX, 256, 0, stream>>>(qpl[0], qpl[1], qpl[2], p, ln_g,
                                             ln_b, bk, qn, qbk);
      gemm_f32<true, false><<<dim3(13, 32, 3), 256, 0, stream>>>(
          qn, Wk, qkb, nullptr, kNPIX, kC, kC, kQD, kQD, kQD, kC);
      sample_attn_f32<<<kNPIX, 256, 0, stream>>>(imgf, w2c, Kin, qkb, qbk, p,
                                                 qn);
      gemm_f32<false, true><<<dim3(13, 32, 3), 256, 0, stream>>>(
          qn, Wv, out + (size_t)p * kQN_FLOATS, bv, kNPIX, kC, kC, kQD, kQD,
          kQD, kC);
    }
  }
}

// Round 14
// 585.540 us; speedup vs baseline: 1.2141x; 1.0680x over previous
//
#include <hip/hip_runtime.h>
#include <math.h>

// ---------------------------------------------------------------------------
// Round 13: r12 + 1-term out-GEMM. Direct-path precision budget (calibrated
// r6: +0.008 per dropped 2^-9 term on output path vs +0.04 on score path)
// spent on dropping Wv_lo: out = bf16(wctx) x bf16(Wv). 32->16 MFMA/K-step,
// 2 staged buffers, LDS 24->16KB. wvtlo eliminated. Score path untouched.
// ---------------------------------------------------------------------------

constexpr int kG = 64, kS = 4, kC = 771, kNV = 4;
constexpr int kQD = 2313;
constexpr int kNPIX = 4096;
constexpr int kL = 16;
constexpr int kImgMStride = kC * kG * kG;
constexpr int kKP = 800;
constexpr int kLDA = 2400;
constexpr int kBROWS = 896;
constexpr int kCP = 776;
constexpr int kNG = kCP / 4;
constexpr int kLDQ = 3 * kCP;
constexpr int kIMS2 = kNPIX * kCP;

constexpr size_t kQKB_FLOATS = (size_t)kNPIX * kLDQ;
constexpr size_t kW_ELEMS = (size_t)3 * kBROWS * kKP;
constexpr size_t kA0_ELEMS = (size_t)kNPIX * kKP;
constexpr size_t kWH_ELEMS = (size_t)kNPIX * kLDA;
constexpr size_t kQN_FLOATS = (size_t)kNPIX * kQD;
constexpr size_t kTAB_FLOATS = (size_t)6 * 64 * kC;

using bf16x8 = __attribute__((ext_vector_type(8))) short;
using f32x4 = __attribute__((ext_vector_type(4))) float;

__device__ __forceinline__ unsigned short f2bf(float x) {
  unsigned int u = __float_as_uint(x);
  u = (u + 0x7FFFu + ((u >> 16) & 1u)) >> 16;
  return (unsigned short)u;
}
__device__ __forceinline__ float bf2f(unsigned short h) {
  return __uint_as_float(((unsigned int)h) << 16);
}
__device__ __forceinline__ void gload16(const unsigned short* g,
                                        unsigned short* l) {
  __builtin_amdgcn_global_load_lds(
      (const __attribute__((address_space(1))) void*)g,
      (__attribute__((address_space(3))) void*)l, 16, 0, 0);
}

// ---- tiny 4x4 batched inverse --------------------------------------------
__global__ void invert4_kernel(const float* __restrict__ c2w,
                               float* __restrict__ w2c) {
  const int m = threadIdx.x;
  if (m >= kNV) return;
  float a[4][8];
  for (int r = 0; r < 4; ++r)
    for (int c = 0; c < 4; ++c) {
      a[r][c] = c2w[m * 16 + r * 4 + c];
      a[r][4 + c] = (r == c) ? 1.f : 0.f;
    }
  for (int col = 0; col < 4; ++col) {
    int piv = col;
    float best = fabsf(a[col][col]);
    for (int r = col + 1; r < 4; ++r) {
      float t = fabsf(a[r][col]);
      if (t > best) { best = t; piv = r; }
    }
    if (piv != col)
      for (int c = 0; c < 8; ++c) {
        float t = a[col][c]; a[col][c] = a[piv][c]; a[piv][c] = t;
      }
    const float inv = 1.f / a[col][col];
    for (int c = 0; c < 8; ++c) a[col][c] *= inv;
    for (int r = 0; r < 4; ++r)
      if (r != col) {
        const float f = a[r][col];
        for (int c = 0; c < 8; ++c) a[r][c] -= f * a[col][c];
      }
  }
  for (int r = 0; r < 4; ++r)
    for (int c = 0; c < 4; ++c) w2c[m * 16 + r * 4 + c] = a[r][4 + c];
}

// ---- image transpose [NV,C,H,W] -> [NV,H,W,776] f32 ----------------------
__global__ void __launch_bounds__(256) transpose_img_kernel(
    const float* __restrict__ img, float* __restrict__ out) {
  __shared__ float t[64][65];
  const int y = blockIdx.x, m = blockIdx.y, tid = threadIdx.x;
  const size_t obase = ((size_t)m * kNPIX + (size_t)y * 64) * kCP;
  for (int c0 = 0; c0 < kC; c0 += 64) {
    const int cw = (kC - c0) < 64 ? (kC - c0) : 64;
    for (int idx = tid; idx < cw * 64; idx += 256) {
      const int cl = idx >> 6, x = idx & 63;
      t[cl][x] = img[(((size_t)m * kC + c0 + cl) * 64 + y) * 64 + x];
    }
    __syncthreads();
    for (int idx = tid; idx < 64 * 64; idx += 256) {
      const int x = idx >> 6, cl = idx & 63;
      if (cl < cw) out[obase + (size_t)x * kCP + c0 + cl] = t[cl][x];
    }
    __syncthreads();
  }
  for (int idx = tid; idx < 64 * 8; idx += 256) {
    const int x = idx >> 3, c = 768 + (idx & 7);
    if (c >= kC && c < kCP) out[obase + (size_t)x * kCP + c] = 0.f;
  }
}

// ---- weight prep ----------------------------------------------------------
__global__ void __launch_bounds__(256) prep_wk_kernel(
    const float* __restrict__ Wk, unsigned short* __restrict__ hi,
    unsigned short* __restrict__ lo) {
  const int c = blockIdx.x, h = blockIdx.y;
  const size_t base = ((size_t)h * kBROWS + c) * kKP;
  for (int k = threadIdx.x; k < kKP; k += 256) {
    float v = (c < kC && k < kC) ? Wk[(size_t)c * kQD + h * kC + k] : 0.f;
    const unsigned short a = f2bf(v);
    hi[base + k] = a;
    lo[base + k] = f2bf(v - bf2f(a));
  }
}

// Wv transpose, bf16 hi only (1-term out-GEMM)
__global__ void __launch_bounds__(256) prep_wvt_kernel(
    const float* __restrict__ Wv, unsigned short* __restrict__ hi) {
  __shared__ float t[64][65];
  const int k0 = blockIdx.x * 64, j0 = blockIdx.y * 64, h = blockIdx.z;
  const int tx = threadIdx.x & 63, ty4 = threadIdx.x >> 6;
  for (int ty = ty4; ty < 64; ty += 4) {
    const int k = k0 + ty, j = j0 + tx;
    t[ty][tx] = (k < kC && j < kC) ? Wv[(size_t)k * kQD + h * kC + j] : 0.f;
  }
  __syncthreads();
  for (int ty = ty4; ty < 64; ty += 4) {
    const int j = j0 + ty, k = k0 + tx;
    if (j < kBROWS && k < kKP)
      hi[((size_t)h * kBROWS + j) * kKP + k] = f2bf(t[tx][ty]);
  }
}

// ---- other-plane mean table (bit-exact) ------------------------------------
__global__ void __launch_bounds__(256) prep_meantab_kernel(
    const float* __restrict__ q_xy, const float* __restrict__ q_xz,
    const float* __restrict__ q_yz, float* __restrict__ tab) {
  const int v = blockIdx.x;  // 0..63
  const int t = blockIdx.y;  // plane*2+part
  const int plane = t >> 1, part = t & 1;
  const float* src;
  if (plane == 0) src = part ? q_yz : q_xz;
  else if (plane == 1) src = part ? q_yz : q_xy;
  else src = part ? q_xz : q_xy;
  __shared__ int sIdx[4][4];
  __shared__ float sW[4][4];
  if (threadIdx.x < 4) {
    const int s = threadIdx.x;
    const float Xv = -1.f + 2.f * v / 63.f;
    const float Ts = -1.f + 2.f * s / 3.f;
    float a, b;
    if (plane == 0) { a = Xv; b = Ts; }
    else if (plane == 1) {
      if (part == 0) { a = Xv; b = Ts; } else { a = Ts; b = Xv; }
    } else { a = Ts; b = Xv; }
    const float ga = fminf(fmaxf((a * 0.5f + 0.5f) * 63.f, 0.f), 63.f);
    const float gb = fminf(fmaxf((b * 0.5f + 0.5f) * 63.f, 0.f), 63.f);
    const float ix = fminf(fmaxf((ga + 1.f) * 0.5f * 63.f, 0.f), 63.f);
    const float iy = fminf(fmaxf((gb + 1.f) * 0.5f * 63.f, 0.f), 63.f);
    const float x0 = floorf(ix), y0 = floorf(iy);
    const float wx = ix - x0, wy = iy - y0;
    const int x0i = (int)x0, y0i = (int)y0;
    const int x1i = (x0i + 1 > 63) ? 63 : x0i + 1;
    const int y1i = (y0i + 1 > 63) ? 63 : y0i + 1;
    sIdx[s][0] = (y0i * 64 + x0i) * kC;
    sIdx[s][1] = (y0i * 64 + x1i) * kC;
    sIdx[s][2] = (y1i * 64 + x0i) * kC;
    sIdx[s][3] = (y1i * 64 + x1i) * kC;
    sW[s][0] = (1.f - wx) * (1.f - wy);
    sW[s][1] = wx * (1.f - wy);
    sW[s][2] = (1.f - wx) * wy;
    sW[s][3] = wx * wy;
  }
  __syncthreads();
  for (int c = threadIdx.x; c < kC; c += 256) {
    float a1 = 0.f;
#pragma unroll
    for (int s = 0; s < 4; ++s) {
      a1 += src[sIdx[s][0] + c] * sW[s][0] + src[sIdx[s][1] + c] * sW[s][1]
          + src[sIdx[s][2] + c] * sW[s][2] + src[sIdx[s][3] + c] * sW[s][3];
    }
    tab[((size_t)t * 64 + v) * kC + c] = a1 * 0.25f;
  }
}

// ---- bf16 split of meantab*g ----------------------------------------------
__global__ void __launch_bounds__(256) prep_tabsplit_kernel(
    const float* __restrict__ tab, const float* __restrict__ ln_g,
    unsigned short* __restrict__ hi, unsigned short* __restrict__ lo) {
  const int v = blockIdx.x;  // 0..127
  const int t = blockIdx.y;  // 0..5
  const int h = 1 + (t & 1);
  const size_t base = ((size_t)t * 128 + v) * kKP;
  for (int k = threadIdx.x; k < kKP; k += 256) {
    float val = 0.f;
    if (v < 64 && k < kC)
      val = tab[((size_t)t * 64 + v) * kC + k] * ln_g[h * kC + k];
    const unsigned short a = f2bf(val);
    hi[base + k] = a;
    lo[base + k] = f2bf(val - bf2f(a));
  }
}

// ---- u_h = Wk_h^T g, v_h = Wk_h^T b — parallel -----------------------------
__global__ void __launch_bounds__(256) prep_uv_kernel(
    const float* __restrict__ Wk, const float* __restrict__ ln_g,
    const float* __restrict__ ln_b, float* __restrict__ u,
    float* __restrict__ v) {
  const int c = blockIdx.x;
  const int h = blockIdx.y;
  __shared__ float ru[4], rv[4];
  float su = 0.f, sv = 0.f;
  if (c < kC) {
    const float* wr = Wk + (size_t)c * kQD + h * kC;
    const float* g = ln_g + h * kC;
    const float* b = ln_b + h * kC;
    for (int k = threadIdx.x; k < kC; k += 256) {
      const float w = wr[k];
      su = fmaf(w, g[k], su);
      sv = fmaf(w, b[k], sv);
    }
  }
#pragma unroll
  for (int off = 32; off; off >>= 1) {
    su += __shfl_down(su, off);
    sv += __shfl_down(sv, off);
  }
  if ((threadIdx.x & 63) == 0) {
    ru[threadIdx.x >> 6] = su;
    rv[threadIdx.x >> 6] = sv;
  }
  __syncthreads();
  if (threadIdx.x == 0) {
    u[h * kCP + c] = ru[0] + ru[1] + ru[2] + ru[3];
    v[h * kCP + c] = rv[0] + rv[1] + rv[2] + rv[3];
  }
}

// ---- build_a0 --------------------------------------------------------------
__global__ void __launch_bounds__(256) build_a0_kernel(
    const float* __restrict__ q_xy, const float* __restrict__ q_xz,
    const float* __restrict__ q_yz, const float* __restrict__ tab,
    const float* __restrict__ ln_g, const float* __restrict__ ln_b,
    const float* __restrict__ bk, unsigned short* __restrict__ a0hi,
    unsigned short* __restrict__ a0lo, float* __restrict__ murs,
    float* __restrict__ qbk) {
  const int slot = blockIdx.y, plane = slot;
  const float* qp = (plane == 0) ? q_xy : (plane == 1) ? q_xz : q_yz;
  const int n = blockIdx.x, i = n >> 6, j = n & 63, tid = threadIdx.x;
  __shared__ float qf[kQD];
  __shared__ float red[16];

  const float* t0 = tab + ((size_t)(plane * 2 + 0) * 64 + j) * kC;
  const float* t1 = tab + ((size_t)(plane * 2 + 1) * 64 + i) * kC;
  for (int c = tid; c < kC; c += 256) {
    qf[c] = qp[(size_t)n * kC + c];
    qf[kC + c] = t0[c];
    qf[2 * kC + c] = t1[c];
  }
  __syncthreads();

  float sm = 0.f;
  for (int idx = tid; idx < kQD; idx += 256) sm += qf[idx];
#pragma unroll
  for (int off = 32; off; off >>= 1) sm += __shfl_down(sm, off);
  if ((tid & 63) == 0) red[tid >> 6] = sm;
  __syncthreads();
  const float mu = (red[0] + red[1] + red[2] + red[3]) * (1.f / kQD);
  __syncthreads();
  float sq = 0.f;
  for (int idx = tid; idx < kQD; idx += 256) {
    const float d = qf[idx] - mu;
    sq += d * d;
  }
#pragma unroll
  for (int off = 32; off; off >>= 1) sq += __shfl_down(sq, off);
  if ((tid & 63) == 0) red[tid >> 6] = sq;
  __syncthreads();
  const float var = (red[0] + red[1] + red[2] + red[3]) * (1.f / kQD);
  const float rstd = 1.f / sqrtf(var + 1e-5f);
  if (tid == 0) {
    murs[2 * ((size_t)slot * kNPIX + n)] = mu;
    murs[2 * ((size_t)slot * kNPIX + n) + 1] = rstd;
  }
  __syncthreads();

  float h0 = 0.f, h1 = 0.f, h2 = 0.f;
  unsigned short* ah = a0hi + (size_t)slot * kA0_ELEMS + (size_t)n * kKP;
  unsigned short* al = a0lo + (size_t)slot * kA0_ELEMS + (size_t)n * kKP;
  for (int idx = tid; idx < 3 * kKP; idx += 256) {
    int h, k;
    if (idx < kKP) { h = 0; k = idx; }
    else if (idx < 2 * kKP) { h = 1; k = idx - kKP; }
    else { h = 2; k = idx - 2 * kKP; }
    if (k < kC) {
      const int li = h * kC + k;
      const float v = (qf[li] - mu) * rstd * ln_g[li] + ln_b[li];
      const float pb = v * bk[li];
      if (h == 0) h0 += pb; else if (h == 1) h1 += pb; else h2 += pb;
    }
    if (idx < kKP) {
      const float y = (idx < kC) ? qf[idx] * ln_g[idx] : 0.f;
      const unsigned short hv = f2bf(y);
      ah[idx] = hv;
      al[idx] = f2bf(y - bf2f(hv));
    }
  }
#pragma unroll
  for (int off = 32; off; off >>= 1) {
    h0 += __shfl_down(h0, off);
    h1 += __shfl_down(h1, off);
    h2 += __shfl_down(h2, off);
  }
  if ((tid & 63) == 0) {
    red[(tid >> 6) * 4 + 0] = h0;
    red[(tid >> 6) * 4 + 1] = h1;
    red[(tid >> 6) * 4 + 2] = h2;
  }
  __syncthreads();
  if (tid < 3)
    qbk[((size_t)slot * kNPIX + n) * 3 + tid] =
        red[tid] + red[4 + tid] + red[8 + tid] + red[12 + tid];
}

// ---- head-0 GEMM (3-term, score path) --------------------------------------
__global__ void __launch_bounds__(256) gemm_a0_kernel(
    const unsigned short* __restrict__ A0hi,
    const unsigned short* __restrict__ A0lo,
    const unsigned short* __restrict__ Bhi,
    const unsigned short* __restrict__ Blo, const float* __restrict__ murs,
    const float* __restrict__ uvec, const float* __restrict__ vvec,
    float* __restrict__ qkb) {
  __shared__ unsigned short smA[2][128 * 32];
  __shared__ unsigned short smB[2][128 * 32];
  const int slot = blockIdx.z;
  const int t = blockIdx.y * 7 + blockIdx.x;
  const int xcd = t & 7, idx = t >> 3;
  const int nb = idx % 7, mb = (xcd << 2) + idx / 7;
  const int m0 = mb * 128, n0 = nb * 128;
  const unsigned short* Ah = A0hi + (size_t)slot * kA0_ELEMS;
  const unsigned short* Al = A0lo + (size_t)slot * kA0_ELEMS;
  const int tid = threadIdx.x;
  const int lane = tid & 63, w = tid >> 6;
  const int wm = w >> 1, wn = w & 1;

  const int sr0 = w * 16 + (lane >> 2);
  const int ss = lane & 3;
  size_t aoff[2], boff[2];
  int ldsb[2];
#pragma unroll
  for (int p = 0; p < 2; ++p) {
    const int r = p * 64 + sr0;
    const int kl = (ss ^ ((r >> 1) & 3)) * 8;
    aoff[p] = (size_t)(m0 + r) * kKP + kl;
    boff[p] = (size_t)(n0 + r) * kKP + kl;
    ldsb[p] = (p * 64 + w * 16) * 32;
  }
  int offA[4], offB[4];
#pragma unroll
  for (int i = 0; i < 4; ++i) {
    const int ra = wm * 64 + i * 16 + (lane & 15);
    offA[i] = ra * 32 + (((lane >> 4) ^ ((ra >> 1) & 3)) << 3);
    const int rb = wn * 64 + i * 16 + (lane & 15);
    offB[i] = rb * 32 + (((lane >> 4) ^ ((rb >> 1) & 3)) << 3);
  }
  f32x4 acc[4][4];
#pragma unroll
  for (int i = 0; i < 4; ++i)
#pragma unroll
    for (int j = 0; j < 4; ++j) acc[i][j] = f32x4{0.f, 0.f, 0.f, 0.f};

  for (int k0 = 0; k0 < kKP; k0 += 32) {
#pragma unroll
    for (int p = 0; p < 2; ++p) {
      gload16(Ah + aoff[p] + k0, &smA[0][ldsb[p]]);
      gload16(Al + aoff[p] + k0, &smA[1][ldsb[p]]);
      gload16(Bhi + boff[p] + k0, &smB[0][ldsb[p]]);
      gload16(Blo + boff[p] + k0, &smB[1][ldsb[p]]);
    }
    __syncthreads();
    bf16x8 ah[4], al[4], bh[4], bl[4];
#pragma unroll
    for (int i = 0; i < 4; ++i) {
      ah[i] = *(const bf16x8*)&smA[0][offA[i]];
      al[i] = *(const bf16x8*)&smA[1][offA[i]];
      bh[i] = *(const bf16x8*)&smB[0][offB[i]];
      bl[i] = *(const bf16x8*)&smB[1][offB[i]];
    }
#pragma unroll
    for (int i = 0; i < 4; ++i)
#pragma unroll
      for (int j = 0; j < 4; ++j)
        acc[i][j] = __builtin_amdgcn_mfma_f32_16x16x32_bf16(ah[i], bh[j],
                                                            acc[i][j], 0, 0, 0);
#pragma unroll
    for (int i = 0; i < 4; ++i)
#pragma unroll
      for (int j = 0; j < 4; ++j)
        acc[i][j] = __builtin_amdgcn_mfma_f32_16x16x32_bf16(ah[i], bl[j],
                                                            acc[i][j], 0, 0, 0);
#pragma unroll
    for (int i = 0; i < 4; ++i)
#pragma unroll
      for (int j = 0; j < 4; ++j)
        acc[i][j] = __builtin_amdgcn_mfma_f32_16x16x32_bf16(al[i], bh[j],
                                                            acc[i][j], 0, 0, 0);
    __syncthreads();
  }

  const float* mr = murs + 2 * ((size_t)slot * kNPIX);
  float* dst = qkb + (size_t)slot * kQKB_FLOATS;
  const int rbase = m0 + wm * 64;
  const int cbase = n0 + wn * 64;
#pragma unroll
  for (int i = 0; i < 4; ++i) {
#pragma unroll
    for (int j = 0; j < 4; ++j) {
      const int col = cbase + j * 16 + (lane & 15);
      if (col < kC) {
        const float uu = uvec[col], vv = vvec[col];
#pragma unroll
        for (int r = 0; r < 4; ++r) {
          const int row = rbase + i * 16 + (lane >> 4) * 4 + r;
          const float mu = mr[2 * row], rs = mr[2 * row + 1];
          dst[(size_t)row * kLDQ + col] = rs * acc[i][j][r] - rs * mu * uu + vv;
        }
      } else if (col < kCP) {
#pragma unroll
        for (int r = 0; r < 4; ++r) {
          const int row = rbase + i * 16 + (lane >> 4) * 4 + r;
          dst[(size_t)row * kLDQ + col] = 0.f;
        }
      }
    }
  }
}

// ---- table GEMM ------------------------------------------------------------
__global__ void __launch_bounds__(256) gemm_tab_kernel(
    const unsigned short* __restrict__ Thi,
    const unsigned short* __restrict__ Tlo,
    const unsigned short* __restrict__ Wkhi,
    const unsigned short* __restrict__ Wklo, float* __restrict__ Atab) {
  __shared__ unsigned short smA[2][128 * 32];
  __shared__ unsigned short smB[2][128 * 32];
  const int t = blockIdx.y;
  const int n0 = blockIdx.x * 128;
  const int h = 1 + (t & 1);
  const unsigned short* Ah = Thi + (size_t)t * 128 * kKP;
  const unsigned short* Al = Tlo + (size_t)t * 128 * kKP;
  const unsigned short* Bh = Wkhi + (size_t)h * kBROWS * kKP;
  const unsigned short* Bl = Wklo + (size_t)h * kBROWS * kKP;
  const int tid = threadIdx.x;
  const int lane = tid & 63, w = tid >> 6;
  const int wm = w >> 1, wn = w & 1;

  const int sr0 = w * 16 + (lane >> 2);
  const int ss = lane & 3;
  size_t aoff[2], boff[2];
  int ldsb[2];
#pragma unroll
  for (int p = 0; p < 2; ++p) {
    const int r = p * 64 + sr0;
    const int kl = (ss ^ ((r >> 1) & 3)) * 8;
    aoff[p] = (size_t)r * kKP + kl;
    boff[p] = (size_t)(n0 + r) * kKP + kl;
    ldsb[p] = (p * 64 + w * 16) * 32;
  }
  int offA[4], offB[4];
#pragma unroll
  for (int i = 0; i < 4; ++i) {
    const int ra = wm * 64 + i * 16 + (lane & 15);
    offA[i] = ra * 32 + (((lane >> 4) ^ ((ra >> 1) & 3)) << 3);
    const int rb = wn * 64 + i * 16 + (lane & 15);
    offB[i] = rb * 32 + (((lane >> 4) ^ ((rb >> 1) & 3)) << 3);
  }
  f32x4 acc[4][4];
#pragma unroll
  for (int i = 0; i < 4; ++i)
#pragma unroll
    for (int j = 0; j < 4; ++j) acc[i][j] = f32x4{0.f, 0.f, 0.f, 0.f};

  for (int k0 = 0; k0 < kKP; k0 += 32) {
#pragma unroll
    for (int p = 0; p < 2; ++p) {
      gload16(Ah + aoff[p] + k0, &smA[0][ldsb[p]]);
      gload16(Al + aoff[p] + k0, &smA[1][ldsb[p]]);
      gload16(Bh + boff[p] + k0, &smB[0][ldsb[p]]);
      gload16(Bl + boff[p] + k0, &smB[1][ldsb[p]]);
    }
    __syncthreads();
    bf16x8 ah[4], al[4], bh[4], bl[4];
#pragma unroll
    for (int i = 0; i < 4; ++i) {
      ah[i] = *(const bf16x8*)&smA[0][offA[i]];
      al[i] = *(const bf16x8*)&smA[1][offA[i]];
      bh[i] = *(const bf16x8*)&smB[0][offB[i]];
      bl[i] = *(const bf16x8*)&smB[1][offB[i]];
    }
#pragma unroll
    for (int i = 0; i < 4; ++i)
#pragma unroll
      for (int j = 0; j < 4; ++j)
        acc[i][j] = __builtin_amdgcn_mfma_f32_16x16x32_bf16(ah[i], bh[j],
                                                            acc[i][j], 0, 0, 0);
#pragma unroll
    for (int i = 0; i < 4; ++i)
#pragma unroll
      for (int j = 0; j < 4; ++j)
        acc[i][j] = __builtin_amdgcn_mfma_f32_16x16x32_bf16(ah[i], bl[j],
                                                            acc[i][j], 0, 0, 0);
#pragma unroll
    for (int i = 0; i < 4; ++i)
#pragma unroll
      for (int j = 0; j < 4; ++j)
        acc[i][j] = __builtin_amdgcn_mfma_f32_16x16x32_bf16(al[i], bh[j],
                                                            acc[i][j], 0, 0, 0);
    __syncthreads();
  }

  float* C = Atab + (size_t)t * 128 * kCP;
  const int rbase = wm * 64;
  const int cbase = n0 + wn * 64;
#pragma unroll
  for (int i = 0; i < 4; ++i) {
#pragma unroll
    for (int j = 0; j < 4; ++j) {
      const int col = cbase + j * 16 + (lane & 15);
      if (col < kCP) {
        const float keep = (col < kC) ? 1.f : 0.f;
#pragma unroll
        for (int r = 0; r < 4; ++r) {
          const int row = rbase + i * 16 + (lane >> 4) * 4 + r;
          C[(size_t)row * kCP + col] = acc[i][j][r] * keep;
        }
      }
    }
  }
}

// ---- combine: fill qkb heads 1/2 ------------------------------------------
__global__ void __launch_bounds__(256) combine_qk_kernel(
    const float* __restrict__ Atab, const float* __restrict__ u,
    const float* __restrict__ v, const float* __restrict__ murs,
    float* __restrict__ qkb) {
  const int slot = blockIdx.y, n = blockIdx.x;
  const int i = n >> 6, j = n & 63, tid = threadIdx.x;
  const float mu = murs[2 * ((size_t)slot * kNPIX + n)];
  const float rs = murs[2 * ((size_t)slot * kNPIX + n) + 1];
  const float rsmu = rs * mu;
  float* dst = qkb + (size_t)slot * kQKB_FLOATS + (size_t)n * kLDQ;
  const float* A1 = Atab + ((size_t)(slot * 2 + 0) * 128 + j) * kCP;
  const float* A2 = Atab + ((size_t)(slot * 2 + 1) * 128 + i) * kCP;
  if (tid < kNG) {
    const int c4 = tid << 2;
    const float4 a1 = *(const float4*)&A1[c4];
    const float4 u1 = *(const float4*)&u[kCP + c4];
    const float4 v1 = *(const float4*)&v[kCP + c4];
    float4 r1;
    r1.x = rs * a1.x - rsmu * u1.x + v1.x;
    r1.y = rs * a1.y - rsmu * u1.y + v1.y;
    r1.z = rs * a1.z - rsmu * u1.z + v1.z;
    r1.w = rs * a1.w - rsmu * u1.w + v1.w;
    *(float4*)&dst[kCP + c4] = r1;
    const float4 a2 = *(const float4*)&A2[c4];
    const float4 u2 = *(const float4*)&u[2 * kCP + c4];
    const float4 v2 = *(const float4*)&v[2 * kCP + c4];
    float4 r2;
    r2.x = rs * a2.x - rsmu * u2.x + v2.x;
    r2.y = rs * a2.y - rsmu * u2.y + v2.y;
    r2.z = rs * a2.z - rsmu * u2.z + v2.z;
    r2.w = rs * a2.w - rsmu * u2.w + v2.w;
    *(float4*)&dst[2 * kCP + c4] = r2;
  }
}

// ---- fused sample+attn (3-dot score), 8x8-tile block order -----------------
__global__ void __launch_bounds__(512, 6) sample_attn4_kernel(
    const float* __restrict__ imgt, const float* __restrict__ w2c,
    const float* __restrict__ Kin, const float* __restrict__ qkb,
    const float* __restrict__ qbk, unsigned short* __restrict__ whi) {
  __shared__ __align__(16) float ctx[kL][kCP];
  __shared__ float sW2[kL][4];
  __shared__ int sI2[kL][4];
  __shared__ float sscp[2][48];
  __shared__ float ssc[48], swt[48];
  const int slot = blockIdx.y, plane = slot;
  const int bid = blockIdx.x;
  const int xcd = bid & 7, tt = bid >> 3;
  const int i = (xcd << 3) | ((tt >> 3) & 7);
  const int j = (((tt >> 6) << 3) | (tt & 7));
  const int n = (i << 6) | j;
  const int tid = threadIdx.x;
  const float* qkn = qkb + (size_t)slot * kQKB_FLOATS + (size_t)n * kLDQ;

  if (tid < kL) {
    const int s = tid >> 2, m = tid & 3;
    const float Xi = -1.f + 2.f * i / 63.f;
    const float Xj = -1.f + 2.f * j / 63.f;
    const float Ts = -1.f + 2.f * s / 3.f;
    float px, py, pz;
    if (plane == 0) { px = Xj; py = Xi; pz = Ts; }
    else if (plane == 1) { px = Xj; py = Ts; pz = Xi; }
    else { px = Ts; py = Xj; pz = Xi; }
    const float* W = w2c + m * 16;
    const float c0 = W[0] * px + W[1] * py + W[2] * pz + W[3];
    const float c1 = W[4] * px + W[5] * py + W[6] * pz + W[7];
    const float c2 = W[8] * px + W[9] * py + W[10] * pz + W[11];
    const float* Km = Kin + m * 9;
    const float un = Km[0] * c0 + Km[1] * c1 + Km[2] * c2;
    const float vn = Km[3] * c0 + Km[4] * c1 + Km[5] * c2;
    const float ds = c2 + 1e-8f;
    const float u = un / ds, v = vn / ds;
    const bool mk =
        (c2 > 0.f && u >= 0.f && u < 64.f && v >= 0.f && v < 64.f);
    float w00 = 0.f, w10 = 0.f, w01 = 0.f, w11 = 0.f;
    int i00 = 0, i10 = 0, i01 = 0, i11 = 0;
    if (mk) {
      const float gx = 2.f * (u / 63.f) - 1.f;
      const float gy = 2.f * (v / 63.f) - 1.f;
      const float ix = (gx + 1.f) * 0.5f * 63.f;
      const float iy = (gy + 1.f) * 0.5f * 63.f;
      const float x0 = floorf(ix), y0 = floorf(iy);
      const float x1 = x0 + 1.f, y1 = y0 + 1.f;
      const float wx = ix - x0, wy = iy - y0;
      const float v00 = (x0 >= 0.f && x0 <= 63.f && y0 >= 0.f && y0 <= 63.f) ? 1.f : 0.f;
      const float v10 = (x1 >= 0.f && x1 <= 63.f && y0 >= 0.f && y0 <= 63.f) ? 1.f : 0.f;
      const float v01 = (x0 >= 0.f && x0 <= 63.f && y1 >= 0.f && y1 <= 63.f) ? 1.f : 0.f;
      const float v11 = (x1 >= 0.f && x1 <= 63.f && y1 >= 0.f && y1 <= 63.f) ? 1.f : 0.f;
      w00 = (1.f - wx) * (1.f - wy) * v00;
      w10 = wx * (1.f - wy) * v10;
      w01 = (1.f - wx) * wy * v01;
      w11 = wx * wy * v11;
      const int x0i = (int)fminf(fmaxf(x0, 0.f), 63.f);
      const int x1i = (int)fminf(fmaxf(x1, 0.f), 63.f);
      const int y0i = (int)fminf(fmaxf(y0, 0.f), 63.f);
      const int y1i = (int)fminf(fmaxf(y1, 0.f), 63.f);
      const int mb = m * kIMS2;
      i00 = mb + (y0i * 64 + x0i) * kCP;
      i10 = mb + (y0i * 64 + x1i) * kCP;
      i01 = mb + (y1i * 64 + x0i) * kCP;
      i11 = mb + (y1i * 64 + x1i) * kCP;
    }
    sI2[tid][0] = i00; sI2[tid][1] = i10; sI2[tid][2] = i01; sI2[tid][3] = i11;
    sW2[tid][0] = w00; sW2[tid][1] = w10; sW2[tid][2] = w01; sW2[tid][3] = w11;
  }
  __syncthreads();

  const int lane = tid & 63, wv = tid >> 6;
#pragma unroll
  for (int q = 0; q < 2; ++q) {
    const int l = (wv << 1) + q;
    const float a0 = sW2[l][0], a1 = sW2[l][1], a2 = sW2[l][2], a3 = sW2[l][3];
    const int b0 = sI2[l][0], b1 = sI2[l][1], b2 = sI2[l][2], b3 = sI2[l][3];
    for (int g = lane; g < kNG; g += 64) {
      const int c4 = g << 2;
      const float4 t0 = *(const float4*)&imgt[b0 + c4];
      const float4 t1 = *(const float4*)&imgt[b1 + c4];
      const float4 t2 = *(const float4*)&imgt[b2 + c4];
      const float4 t3 = *(const float4*)&imgt[b3 + c4];
      float4 r;
      r.x = fmaf(t0.x, a0, fmaf(t1.x, a1, fmaf(t2.x, a2, t3.x * a3)));
      r.y = fmaf(t0.y, a0, fmaf(t1.y, a1, fmaf(t2.y, a2, t3.y * a3)));
      r.z = fmaf(t0.z, a0, fmaf(t1.z, a1, fmaf(t2.z, a2, t3.z * a3)));
      r.w = fmaf(t0.w, a0, fmaf(t1.w, a1, fmaf(t2.w, a2, t3.w * a3)));
      *(float4*)&ctx[l][c4] = r;
    }
  }
  __syncthreads();

  const int g16 = tid >> 4, l16 = tid & 15;
  const float* qbkn = qbk + ((size_t)slot * kNPIX + n) * 3;
  {
    const int l = g16 & 15, half = g16 >> 4;
    float p0 = 0.f, p1 = 0.f, p2 = 0.f;
#pragma unroll
    for (int it = 0; it < 6; ++it) {
      const int c4 = (l16 + ((2 * it + half) << 4)) << 2;
      const float4 cv = *(const float4*)&ctx[l][c4];
      const float4 q0 = *(const float4*)&qkn[c4];
      const float4 q1 = *(const float4*)&qkn[kCP + c4];
      const float4 q2 = *(const float4*)&qkn[2 * kCP + c4];
      p0 = fmaf(cv.x, q0.x, fmaf(cv.y, q0.y, fmaf(cv.z, q0.z, fmaf(cv.w, q0.w, p0))));
      p1 = fmaf(cv.x, q1.x, fmaf(cv.y, q1.y, fmaf(cv.z, q1.z, fmaf(cv.w, q1.w, p1))));
      p2 = fmaf(cv.x, q2.x, fmaf(cv.y, q2.y, fmaf(cv.z, q2.z, fmaf(cv.w, q2.w, p2))));
    }
    if (half == 0 && l16 < 2) {
      const int c4 = (192 + l16) << 2;
      const float4 cv = *(const float4*)&ctx[l][c4];
      const float4 q0 = *(const float4*)&qkn[c4];
      const float4 q1 = *(const float4*)&qkn[kCP + c4];
      const float4 q2 = *(const float4*)&qkn[2 * kCP + c4];
      p0 = fmaf(cv.x, q0.x, fmaf(cv.y, q0.y, fmaf(cv.z, q0.z, fmaf(cv.w, q0.w, p0))));
      p1 = fmaf(cv.x, q1.x, fmaf(cv.y, q1.y, fmaf(cv.z, q1.z, fmaf(cv.w, q1.w, p1))));
      p2 = fmaf(cv.x, q2.x, fmaf(cv.y, q2.y, fmaf(cv.z, q2.z, fmaf(cv.w, q2.w, p2))));
    }
#pragma unroll
    for (int off = 8; off; off >>= 1) {
      p0 += __shfl_down(p0, off, 16);
      p1 += __shfl_down(p1, off, 16);
      p2 += __shfl_down(p2, off, 16);
    }
    if (l16 == 0) {
      sscp[half][l] = p0;
      sscp[half][16 + l] = p1;
      sscp[half][32 + l] = p2;
    }
  }
  __syncthreads();
  if (tid < 48) ssc[tid] = sscp[0][tid] + sscp[1][tid] + qbkn[tid >> 4];
  __syncthreads();
  if (tid < 3) {
    float mx = ssc[tid * 16];
#pragma unroll
    for (int l = 1; l < kL; ++l) mx = fmaxf(mx, ssc[tid * 16 + l]);
    float e[kL];
    float sum = 0.f;
#pragma unroll
    for (int l = 0; l < kL; ++l) {
      e[l] = expf(ssc[tid * 16 + l] - mx);
      sum += e[l];
    }
    const float inv = 1.f / sum;
#pragma unroll
    for (int l = 0; l < kL; ++l) swt[tid * 16 + l] = e[l] * inv;
  }
  __syncthreads();

  unsigned short* wh = whi + (size_t)slot * kWH_ELEMS + (size_t)n * kLDA;
  if (tid < 2 * kNG) {
    const int c4 = (tid >> 1) << 2;
    const int l0 = (tid & 1) << 3;
    float4 o0{0.f, 0.f, 0.f, 0.f}, o1{0.f, 0.f, 0.f, 0.f},
        o2{0.f, 0.f, 0.f, 0.f};
#pragma unroll
    for (int dl = 0; dl < 8; ++dl) {
      const int l = l0 + dl;
      const float4 cv = *(const float4*)&ctx[l][c4];
      const float s0 = swt[l], s1 = swt[16 + l], s2 = swt[32 + l];
      o0.x = fmaf(cv.x, s0, o0.x); o0.y = fmaf(cv.y, s0, o0.y);
      o0.z = fmaf(cv.z, s0, o0.z); o0.w = fmaf(cv.w, s0, o0.w);
      o1.x = fmaf(cv.x, s1, o1.x); o1.y = fmaf(cv.y, s1, o1.y);
      o1.z = fmaf(cv.z, s1, o1.z); o1.w = fmaf(cv.w, s1, o1.w);
      o2.x = fmaf(cv.x, s2, o2.x); o2.y = fmaf(cv.y, s2, o2.y);
      o2.z = fmaf(cv.z, s2, o2.z); o2.w = fmaf(cv.w, s2, o2.w);
    }
    o0.x += __shfl_xor(o0.x, 1); o0.y += __shfl_xor(o0.y, 1);
    o0.z += __shfl_xor(o0.z, 1); o0.w += __shfl_xor(o0.w, 1);
    o1.x += __shfl_xor(o1.x, 1); o1.y += __shfl_xor(o1.y, 1);
    o1.z += __shfl_xor(o1.z, 1); o1.w += __shfl_xor(o1.w, 1);
    o2.x += __shfl_xor(o2.x, 1); o2.y += __shfl_xor(o2.y, 1);
    o2.z += __shfl_xor(o2.z, 1); o2.w += __shfl_xor(o2.w, 1);
    if ((tid & 1) == 0) {
      float4 ov[3] = {o0, o1, o2};
#pragma unroll
      for (int h = 0; h < 3; ++h) {
        ushort4 hi;
        hi.x = f2bf(ov[h].x);
        hi.y = f2bf(ov[h].y);
        hi.z = f2bf(ov[h].z);
        hi.w = f2bf(ov[h].w);
        *(ushort4*)&wh[h * kKP + c4] = hi;
      }
    }
  }
  if (tid < 72) {
    const int h = tid / 24, k2 = kCP + tid % 24;
    wh[h * kKP + k2] = 0;
  }
}

// ---- out-GEMM: 1-term bf16 x bf16, XCD panel swizzle -----------------------
__global__ void __launch_bounds__(256) gemm_out_kernel(
    const unsigned short* __restrict__ Ahi,
    const unsigned short* __restrict__ Bhi, float* __restrict__ C,
    const float* __restrict__ bias) {
  __shared__ unsigned short smA[128 * 32];
  __shared__ unsigned short smB[128 * 32];
  const int slot = blockIdx.z / 3, h = blockIdx.z % 3;
  const int t = blockIdx.y * 7 + blockIdx.x;
  const int xcd = t & 7, idx = t >> 3;
  const int nb = idx % 7, mb = (xcd << 2) + idx / 7;
  const int m0 = mb * 128, n0 = nb * 128;
  const unsigned short* Ah = Ahi + (size_t)slot * kWH_ELEMS;
  float* Cs = C + (size_t)slot * kQN_FLOATS;
  const int tid = threadIdx.x;
  const int lane = tid & 63, w = tid >> 6;
  const int wm = w >> 1, wn = w & 1;

  const int sr0 = w * 16 + (lane >> 2);
  const int ss = lane & 3;
  size_t aoff[2], boff[2];
  int ldsb[2];
#pragma unroll
  for (int p = 0; p < 2; ++p) {
    const int r = p * 64 + sr0;
    const int kl = (ss ^ ((r >> 1) & 3)) * 8;
    aoff[p] = (size_t)(m0 + r) * kLDA + (size_t)h * kKP + kl;
    boff[p] = ((size_t)h * kBROWS + (n0 + r)) * kKP + kl;
    ldsb[p] = (p * 64 + w * 16) * 32;
  }
  int offA[4], offB[4];
#pragma unroll
  for (int i = 0; i < 4; ++i) {
    const int ra = wm * 64 + i * 16 + (lane & 15);
    offA[i] = ra * 32 + (((lane >> 4) ^ ((ra >> 1) & 3)) << 3);
    const int rb = wn * 64 + i * 16 + (lane & 15);
    offB[i] = rb * 32 + (((lane >> 4) ^ ((rb >> 1) & 3)) << 3);
  }
  f32x4 acc[4][4];
#pragma unroll
  for (int i = 0; i < 4; ++i)
#pragma unroll
    for (int j = 0; j < 4; ++j) acc[i][j] = f32x4{0.f, 0.f, 0.f, 0.f};

  for (int k0 = 0; k0 < kKP; k0 += 32) {
#pragma unroll
    for (int p = 0; p < 2; ++p) {
      gload16(Ah + aoff[p] + k0, &smA[ldsb[p]]);
      gload16(Bhi + boff[p] + k0, &smB[ldsb[p]]);
    }
    __syncthreads();
    bf16x8 ah[4], bh[4];
#pragma unroll
    for (int i = 0; i < 4; ++i) {
      ah[i] = *(const bf16x8*)&smA[offA[i]];
      bh[i] = *(const bf16x8*)&smB[offB[i]];
    }
#pragma unroll
    for (int i = 0; i < 4; ++i)
#pragma unroll
      for (int j = 0; j < 4; ++j)
        acc[i][j] = __builtin_amdgcn_mfma_f32_16x16x32_bf16(ah[i], bh[j],
                                                            acc[i][j], 0, 0, 0);
    __syncthreads();
  }

  const int rbase = m0 + wm * 64;
  const int cbase = n0 + wn * 64;
#pragma unroll
  for (int i = 0; i < 4; ++i) {
#pragma unroll
    for (int j = 0; j < 4; ++j) {
      const int col = cbase + j * 16 + (lane & 15);
      if (col < kC) {
        const float bb = bias[h * kC + col];
#pragma unroll
        for (int r = 0; r < 4; ++r) {
          const int row = rbase + i * 16 + (lane >> 4) * 4 + r;
          Cs[(size_t)row * kQD + h * kC + col] = acc[i][j][r] + bb;
        }
      }
    }
  }
}

// ======================= tier-D f32 fallback path ==========================
__global__ void __launch_bounds__(256) build_q_f32(
    const float* __restrict__ q_xy, const float* __restrict__ q_xz,
    const float* __restrict__ q_yz, const int plane,
    const float* __restrict__ ln_g, const float* __restrict__ ln_b,
    const float* __restrict__ bk, float* __restrict__ qn,
    float* __restrict__ qbk) {
  const float* qp = (plane == 0) ? q_xy : (plane == 1) ? q_xz : q_yz;
  const float* qo0 = (plane == 0) ? q_xz : q_xy;
  const float* qo1 = (plane == 2) ? q_xz : q_yz;
  const int n = blockIdx.x, i = n >> 6, j = n & 63, tid = threadIdx.x;
  __shared__ float qf[kQD];
  __shared__ int sIdx[2][4][4];
  __shared__ float sW[2][4][4];
  __shared__ float red[16];

  if (tid < 8) {
    const int part = tid >> 2, s = tid & 3;
    const float Xi = -1.f + 2.f * i / 63.f;
    const float Xj = -1.f + 2.f * j / 63.f;
    const float Ts = -1.f + 2.f * s / 3.f;
    float a, b;
    if (plane == 0) { a = part ? Xi : Xj; b = Ts; }
    else if (plane == 1) {
      if (part == 0) { a = Xj; b = Ts; } else { a = Ts; b = Xi; }
    } else { a = Ts; b = part ? Xi : Xj; }
    const float ga = fminf(fmaxf((a * 0.5f + 0.5f) * 63.f, 0.f), 63.f);
    const float gb = fminf(fmaxf((b * 0.5f + 0.5f) * 63.f, 0.f), 63.f);
    const float ix = fminf(fmaxf((ga + 1.f) * 0.5f * 63.f, 0.f), 63.f);
    const float iy = fminf(fmaxf((gb + 1.f) * 0.5f * 63.f, 0.f), 63.f);
    const float x0 = floorf(ix), y0 = floorf(iy);
    const float wx = ix - x0, wy = iy - y0;
    const int x0i = (int)x0, y0i = (int)y0;
    const int x1i = (x0i + 1 > 63) ? 63 : x0i + 1;
    const int y1i = (y0i + 1 > 63) ? 63 : y0i + 1;
    sIdx[part][s][0] = (y0i * 64 + x0i) * kC;
    sIdx[part][s][1] = (y0i * 64 + x1i) * kC;
    sIdx[part][s][2] = (y1i * 64 + x0i) * kC;
    sIdx[part][s][3] = (y1i * 64 + x1i) * kC;
    sW[part][s][0] = (1.f - wx) * (1.f - wy);
    sW[part][s][1] = wx * (1.f - wy);
    sW[part][s][2] = (1.f - wx) * wy;
    sW[part][s][3] = wx * wy;
  }
  __syncthreads();
  for (int c = tid; c < kC; c += 256) {
    qf[c] = qp[(size_t)n * kC + c];
    float a1 = 0.f, a2 = 0.f;
#pragma unroll
    for (int s = 0; s < 4; ++s) {
      a1 += qo0[sIdx[0][s][0] + c] * sW[0][s][0]
          + qo0[sIdx[0][s][1] + c] * sW[0][s][1]
          + qo0[sIdx[0][s][2] + c] * sW[0][s][2]
          + qo0[sIdx[0][s][3] + c] * sW[0][s][3];
      a2 += qo1[sIdx[1][s][0] + c] * sW[1][s][0]
          + qo1[sIdx[1][s][1] + c] * sW[1][s][1]
          + qo1[sIdx[1][s][2] + c] * sW[1][s][2]
          + qo1[sIdx[1][s][3] + c] * sW[1][s][3];
    }
    qf[kC + c] = a1 * 0.25f;
    qf[2 * kC + c] = a2 * 0.25f;
  }
  __syncthreads();
  float sm = 0.f;
  for (int idx = tid; idx < kQD; idx += 256) sm += qf[idx];
#pragma unroll
  for (int off = 32; off; off >>= 1) sm += __shfl_down(sm, off);
  if ((tid & 63) == 0) red[tid >> 6] = sm;
  __syncthreads();
  const float mu = (red[0] + red[1] + red[2] + red[3]) * (1.f / kQD);
  __syncthreads();
  float sq = 0.f;
  for (int idx = tid; idx < kQD; idx += 256) {
    const float d = qf[idx] - mu;
    sq += d * d;
  }
#pragma unroll
  for (int off = 32; off; off >>= 1) sq += __shfl_down(sq, off);
  if ((tid & 63) == 0) red[tid >> 6] = sq;
  __syncthreads();
  const float var = (red[0] + red[1] + red[2] + red[3]) * (1.f / kQD);
  const float rstd = 1.f / sqrtf(var + 1e-5f);
  __syncthreads();
  float h0 = 0.f, h1 = 0.f, h2 = 0.f;
  for (int idx = tid; idx < kQD; idx += 256) {
    const float v = (qf[idx] - mu) * rstd * ln_g[idx] + ln_b[idx];
    qn[(size_t)n * kQD + idx] = v;
    const float pb = v * bk[idx];
    if (idx < kC) h0 += pb;
    else if (idx < 2 * kC) h1 += pb;
    else h2 += pb;
  }
#pragma unroll
  for (int off = 32; off; off >>= 1) {
    h0 += __shfl_down(h0, off);
    h1 += __shfl_down(h1, off);
    h2 += __shfl_down(h2, off);
  }
  if ((tid & 63) == 0) {
    red[(tid >> 6) * 4 + 0] = h0;
    red[(tid >> 6) * 4 + 1] = h1;
    red[(tid >> 6) * 4 + 2] = h2;
  }
  __syncthreads();
  if (tid < 3)
    qbk[n * 3 + tid] = red[tid] + red[4 + tid] + red[8 + tid] + red[12 + tid];
}

__global__ void __launch_bounds__(256) sample_attn_f32(
    const float* __restrict__ src, const float* __restrict__ w2c,
    const float* __restrict__ Kin, const float* __restrict__ qk,
    const float* __restrict__ qbk, const int plane, float* __restrict__ wctx) {
  __shared__ float ctx[kL * kC];
  __shared__ float su[kL], sv[kL], smk[kL];
  __shared__ float spart[4][48];
  __shared__ float ssc[48];
  __shared__ float swt[48];
  const int n = blockIdx.x, i = n >> 6, j = n & 63, tid = threadIdx.x;

  if (tid < kL) {
    const int s = tid >> 2, m = tid & 3;
    const float Xi = -1.f + 2.f * i / 63.f;
    const float Xj = -1.f + 2.f * j / 63.f;
    const float Ts = -1.f + 2.f * s / 3.f;
    float px, py, pz;
    if (plane == 0) { px = Xj; py = Xi; pz = Ts; }
    else if (plane == 1) { px = Xj; py = Ts; pz = Xi; }
    else { px = Ts; py = Xj; pz = Xi; }
    const float* W = w2c + m * 16;
    const float c0 = W[0] * px + W[1] * py + W[2] * pz + W[3];
    const float c1 = W[4] * px + W[5] * py + W[6] * pz + W[7];
    const float c2 = W[8] * px + W[9] * py + W[10] * pz + W[11];
    const float* Km = Kin + m * 9;
    const float un = Km[0] * c0 + Km[1] * c1 + Km[2] * c2;
    const float vn = Km[3] * c0 + Km[4] * c1 + Km[5] * c2;
    const float ds = c2 + 1e-8f;
    const float u = un / ds, v = vn / ds;
    const float mk =
        (c2 > 0.f && u >= 0.f && u < 64.f && v >= 0.f && v < 64.f) ? 1.f : 0.f;
    su[tid] = u; sv[tid] = v; smk[tid] = mk;
  }
  __syncthreads();

  for (int l = 0; l < kL; ++l) {
    const int m = l & 3;
    const float u = su[l], v = sv[l], mk = smk[l];
    float w00 = 0.f, w10 = 0.f, w01 = 0.f, w11 = 0.f;
    int i00 = 0, i10 = 0, i01 = 0, i11 = 0;
    if (mk != 0.f) {
      const float gx = 2.f * (u / 63.f) - 1.f;
      const float gy = 2.f * (v / 63.f) - 1.f;
      const float ix = (gx + 1.f) * 0.5f * 63.f;
      const float iy = (gy + 1.f) * 0.5f * 63.f;
      const float x0 = floorf(ix), y0 = floorf(iy);
      const float x1 = x0 + 1.f, y1 = y0 + 1.f;
      const float wx = ix - x0, wy = iy - y0;
      const float v00 = (x0 >= 0.f && x0 <= 63.f && y0 >= 0.f && y0 <= 63.f) ? 1.f : 0.f;
      const float v10 = (x1 >= 0.f && x1 <= 63.f && y0 >= 0.f && y0 <= 63.f) ? 1.f : 0.f;
      const float v01 = (x0 >= 0.f && x0 <= 63.f && y1 >= 0.f && y1 <= 63.f) ? 1.f : 0.f;
      const float v11 = (x1 >= 0.f && x1 <= 63.f && y1 >= 0.f && y1 <= 63.f) ? 1.f : 0.f;
      w00 = (1.f - wx) * (1.f - wy) * v00;
      w10 = wx * (1.f - wy) * v10;
      w01 = (1.f - wx) * wy * v01;
      w11 = wx * wy * v11;
      const int x0i = (int)fminf(fmaxf(x0, 0.f), 63.f);
      const int x1i = (int)fminf(fmaxf(x1, 0.f), 63.f);
      const int y0i = (int)fminf(fmaxf(y0, 0.f), 63.f);
      const int y1i = (int)fminf(fmaxf(y1, 0.f), 63.f);
      const int mb = m * kImgMStride;
      i00 = mb + (y0i * 64 + x0i);
      i10 = mb + (y0i * 64 + x1i);
      i01 = mb + (y1i * 64 + x0i);
      i11 = mb + (y1i * 64 + x1i);
    }
    for (int c = tid; c < kC; c += 256) {
      const int cs = c * (kG * kG);
      ctx[l * kC + c] = src[i00 + cs] * w00 + src[i10 + cs] * w10 +
                        src[i01 + cs] * w01 + src[i11 + cs] * w11;
    }
  }
  __syncthreads();

  float acc[48];
#pragma unroll
  for (int t = 0; t < 48; ++t) acc[t] = 0.f;
  const float* qkn = qk + (size_t)n * kQD;
  for (int c = tid; c < kC; c += 256) {
    const float q0 = qkn[c], q1 = qkn[kC + c], q2 = qkn[2 * kC + c];
#pragma unroll
    for (int l = 0; l < kL; ++l) {
      const float cv = ctx[l * kC + c];
      acc[l] = fmaf(cv, q0, acc[l]);
      acc[16 + l] = fmaf(cv, q1, acc[16 + l]);
      acc[32 + l] = fmaf(cv, q2, acc[32 + l]);
    }
  }
#pragma unroll
  for (int t = 0; t < 48; ++t) {
    float x = acc[t];
#pragma unroll
    for (int off = 32; off; off >>= 1) x += __shfl_down(x, off);
    acc[t] = x;
  }
  if ((tid & 63) == 0) {
#pragma unroll
    for (int t = 0; t < 48; ++t) spart[tid >> 6][t] = acc[t];
  }
  __syncthreads();
  if (tid < 48)
    ssc[tid] = spart[0][tid] + spart[1][tid] + spart[2][tid] + spart[3][tid] +
               qbk[n * 3 + (tid >> 4)];
  __syncthreads();
  if (tid < 3) {
    float mx = ssc[tid * 16];
#pragma unroll
    for (int l = 1; l < kL; ++l) mx = fmaxf(mx, ssc[tid * 16 + l]);
    float e[kL];
    float sum = 0.f;
#pragma unroll
    for (int l = 0; l < kL; ++l) {
      e[l] = expf(ssc[tid * 16 + l] - mx);
      sum += e[l];
    }
    const float inv = 1.f / sum;
#pragma unroll
    for (int l = 0; l < kL; ++l) swt[tid * 16 + l] = e[l] * inv;
  }
  __syncthreads();
  for (int c = tid; c < kC; c += 256) {
    float o0 = 0.f, o1 = 0.f, o2 = 0.f;
#pragma unroll
    for (int l = 0; l < kL; ++l) {
      const float cv = ctx[l * kC + c];
      o0 = fmaf(swt[l], cv, o0);
      o1 = fmaf(swt[16 + l], cv, o1);
      o2 = fmaf(swt[32 + l], cv, o2);
    }
    float* wn = wctx + (size_t)n * kQD;
    wn[c] = o0;
    wn[kC + c] = o1;
    wn[2 * kC + c] = o2;
  }
}

template <bool BT, bool BIAS>
__global__ void __launch_bounds__(256) gemm_f32(
    const float* __restrict__ A, const float* __restrict__ B,
    float* __restrict__ Cp, const float* __restrict__ bias, const int M,
    const int N, const int K, const int lda, const int ldb, const int ldc,
    const int hstride) {
  constexpr int BM = 128, BN = 64, BK = 16;
  __shared__ float As[BK][BM + 4];
  __shared__ float Bs[BK][BN + 4];
  const int hoff = blockIdx.z * hstride;
  const int m0 = blockIdx.y * BM, n0 = blockIdx.x * BN;
  const int tid = threadIdx.x;
  const int ty = tid >> 4, tx = tid & 15;
  float acc[8][4];
#pragma unroll
  for (int r = 0; r < 8; ++r)
#pragma unroll
    for (int c = 0; c < 4; ++c) acc[r][c] = 0.f;
  for (int k0 = 0; k0 < K; k0 += BK) {
#pragma unroll
    for (int p = 0; p < 8; ++p) {
      const int idx = tid + p * 256;
      const int mm = idx >> 4, kk = idx & 15;
      float v = 0.f;
      if (k0 + kk < K) v = A[(size_t)(m0 + mm) * lda + hoff + k0 + kk];
      As[kk][mm] = v;
    }
    if (BT) {
#pragma unroll
      for (int p = 0; p < 4; ++p) {
        const int idx = tid + p * 256;
        const int jj = idx >> 4, kk = idx & 15;
        float v = 0.f;
        if ((n0 + jj) < N && (k0 + kk) < K)
          v = B[(size_t)(n0 + jj) * ldb + hoff + k0 + kk];
        Bs[kk][jj] = v;
      }
    } else {
#pragma unroll
      for (int p = 0; p < 4; ++p) {
        const int idx = tid + p * 256;
        const int kk = idx >> 6, jj = idx & 63;
        float v = 0.f;
        if ((n0 + jj) < N && (k0 + kk) < K)
          v = B[(size_t)(k0 + kk) * ldb + hoff + n0 + jj];
        Bs[kk][jj] = v;
      }
    }
    __syncthreads();
#pragma unroll
    for (int kk = 0; kk < BK; ++kk) {
      float a[8], b[4];
#pragma unroll
      for (int r = 0; r < 8; ++r) a[r] = As[kk][ty * 8 + r];
#pragma unroll
      for (int c = 0; c < 4; ++c) b[c] = Bs[kk][tx * 4 + c];
#pragma unroll
      for (int r = 0; r < 8; ++r)
#pragma unroll
        for (int c = 0; c < 4; ++c) acc[r][c] = fmaf(a[r], b[c], acc[r][c]);
    }
    __syncthreads();
  }
#pragma unroll
  for (int r = 0; r < 8; ++r) {
    const int mm = m0 + ty * 8 + r;
    if (mm >= M) continue;
#pragma unroll
    for (int c = 0; c < 4; ++c) {
      const int jj = n0 + tx * 4 + c;
      if (jj < N) {
        float v = acc[r][c];
        if (BIAS) v += bias[hoff + jj];
        Cp[(size_t)mm * ldc + hoff + jj] = v;
      }
    }
  }
}

// ---------------------------------------------------------------------------
extern "C" void kernel_launch(void* const* d_in, const int* in_sizes, int n_in,
                              void* d_out, int out_size, void* d_ws,
                              size_t ws_size, hipStream_t stream) {
  const float* imgf = (const float*)d_in[0];
  const float* c2w = (const float*)d_in[2];
  const float* Kin = (const float*)d_in[3];
  const float* qpl[3] = {(const float*)d_in[5], (const float*)d_in[6],
                         (const float*)d_in[7]};
  const float* Wk = (const float*)d_in[8];
  const float* bk = (const float*)d_in[9];
  const float* Wv = (const float*)d_in[10];
  const float* bv = (const float*)d_in[11];
  const float* ln_g = (const float*)d_in[12];
  const float* ln_b = (const float*)d_in[13];
  float* out = (float*)d_out;
  char* wsb = (char*)d_ws;

  const size_t IMGT_FLOATS = (size_t)kNV * kIMS2;

  size_t off = 0;
  auto take = [&](size_t bytes) {
    size_t p = off;
    off = (off + bytes + 511) & ~(size_t)511;
    return p;
  };
  const size_t o_w2c = take(64 * 4);
  const size_t o_qbk = take((size_t)3 * kNPIX * 3 * 4);
  const size_t o_qkb = take((size_t)3 * kQKB_FLOATS * 4);
  const size_t o_wkhi = take(kW_ELEMS * 2);
  const size_t o_wklo = take(kW_ELEMS * 2);
  const size_t o_wvthi = take(kW_ELEMS * 2);
  const size_t o_a0hi = take((size_t)3 * kA0_ELEMS * 2);
  const size_t o_a0lo = take((size_t)3 * kA0_ELEMS * 2);
  const size_t o_whi = take((size_t)3 * kWH_ELEMS * 2);
  const size_t o_murs = take((size_t)3 * kNPIX * 2 * 4);
  const size_t o_u = take((size_t)3 * kCP * 4);
  const size_t o_v = take((size_t)3 * kCP * 4);
  const size_t o_tab = take(kTAB_FLOATS * 4);
  const size_t o_tshi = take((size_t)6 * 128 * kKP * 2);
  const size_t o_tslo = take((size_t)6 * 128 * kKP * 2);
  const size_t o_atab = take((size_t)6 * 128 * kCP * 4);
  const size_t o_imgt = take(IMGT_FLOATS * 4);
  const size_t need = off;

  if (ws_size >= need) {
    float* w2c = (float*)(wsb + o_w2c);
    float* qbk = (float*)(wsb + o_qbk);
    float* qkb = (float*)(wsb + o_qkb);
    unsigned short* wkhi = (unsigned short*)(wsb + o_wkhi);
    unsigned short* wklo = (unsigned short*)(wsb + o_wklo);
    unsigned short* wvthi = (unsigned short*)(wsb + o_wvthi);
    unsigned short* a0hi = (unsigned short*)(wsb + o_a0hi);
    unsigned short* a0lo = (unsigned short*)(wsb + o_a0lo);
    unsigned short* whi = (unsigned short*)(wsb + o_whi);
    float* murs = (float*)(wsb + o_murs);
    float* uvec = (float*)(wsb + o_u);
    float* vvec = (float*)(wsb + o_v);
    float* meantab = (float*)(wsb + o_tab);
    unsigned short* tshi = (unsigned short*)(wsb + o_tshi);
    unsigned short* tslo = (unsigned short*)(wsb + o_tslo);
    float* atab = (float*)(wsb + o_atab);
    float* imgt = (float*)(wsb + o_imgt);

    invert4_kernel<<<1, 64, 0, stream>>>(c2w, w2c);
    prep_wk_kernel<<<dim3(kBROWS, 3), 256, 0, stream>>>(Wk, wkhi, wklo);
    prep_wvt_kernel<<<dim3(13, 14, 3), 256, 0, stream>>>(Wv, wvthi);
    prep_meantab_kernel<<<dim3(64, 6), 256, 0, stream>>>(qpl[0], qpl[1],
                                                         qpl[2], meantab);
    prep_tabsplit_kernel<<<dim3(128, 6), 256, 0, stream>>>(meantab, ln_g,
                                                           tshi, tslo);
    prep_uv_kernel<<<dim3(kCP, 3), 256, 0, stream>>>(Wk, ln_g, ln_b, uvec,
                                                     vvec);
    transpose_img_kernel<<<dim3(64, kNV), 256, 0, stream>>>(imgf, imgt);
    gemm_tab_kernel<<<dim3(7, 6), 256, 0, stream>>>(tshi, tslo, wkhi, wklo,
                                                    atab);
    build_a0_kernel<<<dim3(kNPIX, 3), 256, 0, stream>>>(
        qpl[0], qpl[1], qpl[2], meantab, ln_g, ln_b, bk, a0hi, a0lo, murs,
        qbk);
    gemm_a0_kernel<<<dim3(7, 32, 3), 256, 0, stream>>>(
        a0hi, a0lo, wkhi, wklo, murs, uvec, vvec, qkb);
    combine_qk_kernel<<<dim3(kNPIX, 3), 256, 0, stream>>>(atab, uvec, vvec,
                                                          murs, qkb);
    sample_attn4_kernel<<<dim3(kNPIX, 3), 512, 0, stream>>>(
        imgt, w2c, Kin, qkb, qbk, whi);
    gemm_out_kernel<<<dim3(7, 32, 9), 256, 0, stream>>>(whi, wvthi, out, bv);
  } else {
    // tier-D: f32 fallback
    float* ws = (float*)d_ws;
    const size_t OFF_QBK = 64;
    const size_t OFF_BIG = OFF_QBK + (size_t)kNPIX * 3;
    float* w2c = ws;
    float* qbk = ws + OFF_QBK;
    float* qn = ws + OFF_BIG;
    float* qkb = qn + kQN_FLOATS;

    invert4_kernel<<<1, 64, 0, stream>>>(c2w, w2c);
    for (int p = 0; p < 3; ++p) {
      build_q_f32<<<kNPIX, 256, 0, stream>>>(qpl[0], qpl[1], qpl[2], p, ln_g,
                                             ln_b, bk, qn, qbk);
      gemm_f32<true, false><<<dim3(13, 32, 3), 256, 0, stream>>>(
          qn, Wk, qkb, nullptr, kNPIX, kC, kC, kQD, kQD, kQD, kC);
      sample_attn_f32<<<kNPIX, 256, 0, stream>>>(imgf, w2c, Kin, qkb, qbk, p,
                                                 qn);
      gemm_f32<false, true><<<dim3(13, 32, 3), 256, 0, stream>>>(
          qn, Wv, out + (size_t)p * kQN_FLOATS, bv, kNPIX, kC, kC, kQD, kQD,
          kQD, kC);
    }
  }
}